// Round 1
// baseline (26192.505 us; speedup 1.0000x reference)
//
#include <hip/hip_runtime.h>
#include <hip/hip_bf16.h>

// ---------------------------------------------------------------------------
// RGPNet forward, fp32 baseline.
// B=8, T=30, RANK=8, H=W=64, crops 14x14.
// Global path: (240,1,64,64) -> base -> (240,128,16,16) -> max over T -> fc_g
// Local path : ROI crops (1920,1,14,14) -> base -> fc_l -> 2x GAT -> head
// ---------------------------------------------------------------------------

constexpr int kB = 8, kT = 30, kR = 8;
constexpr int kN = kT * kR;          // 240 nodes per batch
constexpr int kRH = 14, kRW = 14;

static __device__ __forceinline__ float lrelu01(float v) {
    return v > 0.f ? v : 0.01f * v;
}

// ---------------- direct conv (+leaky_relu, optional fused 2x2 maxpool) -----
template <int K, bool POOL>
__global__ void conv_k(const float* __restrict__ in, const float* __restrict__ wgt,
                       float* __restrict__ out, int N, int Cin, int Cout,
                       int H, int W)
{
    const int Ho = POOL ? (H >> 1) : H;
    const int Wo = POOL ? (W >> 1) : W;
    const int pad = K >> 1;
    const long total = (long)N * Cout * Ho * Wo;
    long idx = (long)blockIdx.x * blockDim.x + threadIdx.x;
    if (idx >= total) return;

    int xo = (int)(idx % Wo); long t = idx / Wo;
    int yo = (int)(t % Ho);   t /= Ho;
    int co = (int)(t % Cout);
    int n  = (int)(t / Cout);

    const float* wb = wgt + (long)co * Cin * K * K;
    const float* ib = in  + (long)n * Cin * H * W;

    if (!POOL) {
        float acc = 0.f;
        for (int ci = 0; ci < Cin; ++ci) {
            const float* ic = ib + (long)ci * H * W;
            const float* wc = wb + ci * K * K;
#pragma unroll
            for (int ky = 0; ky < K; ++ky) {
                int iy = yo + ky - pad;
                if ((unsigned)iy >= (unsigned)H) continue;
#pragma unroll
                for (int kx = 0; kx < K; ++kx) {
                    int ix = xo + kx - pad;
                    if ((unsigned)ix >= (unsigned)W) continue;
                    acc = fmaf(ic[iy * W + ix], wc[ky * K + kx], acc);
                }
            }
        }
        out[idx] = lrelu01(acc);
    } else {
        float mx = -1e30f;
#pragma unroll
        for (int dy = 0; dy < 2; ++dy)
#pragma unroll
        for (int dx = 0; dx < 2; ++dx) {
            int yc = 2 * yo + dy, xc = 2 * xo + dx;
            float acc = 0.f;
            for (int ci = 0; ci < Cin; ++ci) {
                const float* ic = ib + (long)ci * H * W;
                const float* wc = wb + ci * K * K;
#pragma unroll
                for (int ky = 0; ky < K; ++ky) {
                    int iy = yc + ky - pad;
                    if ((unsigned)iy >= (unsigned)H) continue;
#pragma unroll
                    for (int kx = 0; kx < K; ++kx) {
                        int ix = xc + kx - pad;
                        if ((unsigned)ix >= (unsigned)W) continue;
                        acc = fmaf(ic[iy * W + ix], wc[ky * K + kx], acc);
                    }
                }
            }
            mx = fmaxf(mx, lrelu01(acc));
        }
        out[idx] = mx;
    }
}

// ---------------- max over T (g = max_t of (B,T,F)) -------------------------
__global__ void max_over_T(const float* __restrict__ in, float* __restrict__ out,
                           int Bn, int Tn, int F)
{
    long idx = (long)blockIdx.x * blockDim.x + threadIdx.x;
    if (idx >= (long)Bn * F) return;
    int b = (int)(idx / F), f = (int)(idx % F);
    float m = -1e30f;
    for (int t = 0; t < Tn; ++t)
        m = fmaxf(m, in[((long)(b * Tn + t)) * F + f]);
    out[idx] = m;
}

// ---------------- FC layer: wave-per-output, out[m*ldo+o] -------------------
__global__ void linear_wpo(const float* __restrict__ in, const float* __restrict__ w,
                           const float* __restrict__ bias, float* __restrict__ out,
                           int M, int Kd, int O, int ldo)
{
    long gid = (long)blockIdx.x * blockDim.x + threadIdx.x;
    long wid = gid >> 6;
    int lane = (int)(gid & 63);
    if (wid >= (long)M * O) return;
    int m = (int)(wid / O), o = (int)(wid % O);
    const float* ir = in + (long)m * Kd;
    const float* wr = w  + (long)o * Kd;
    float acc = 0.f;
    for (int k = lane; k < Kd; k += 64) acc = fmaf(ir[k], wr[k], acc);
#pragma unroll
    for (int off = 32; off > 0; off >>= 1) acc += __shfl_down(acc, off, 64);
    if (lane == 0) out[(long)m * ldo + o] = acc + bias[o];
}

// ---------------- ROI crop + bilinear resize --------------------------------
__global__ void roi_crop(const float* __restrict__ x, const float* __restrict__ px,
                         float* __restrict__ crops)
{
    int idx = blockIdx.x * blockDim.x + threadIdx.x;
    const int total = kB * kT * kR * kRH * kRW;   // 376320
    if (idx >= total) return;
    int j  = idx % kRW; int t2 = idx / kRW;
    int i  = t2 % kRH;  t2 /= kRH;
    int r  = t2 % kR;   int bt = t2 / kR;

    float cx = px[(bt * kR + r) * 2 + 0];
    float cy = px[(bt * kR + r) * 2 + 1];
    float x1 = floorf(fminf(fmaxf(cx - 7.f, 0.f), 63.f));
    float x2 = floorf(fminf(cx + 7.f, 64.f));
    float y1 = floorf(fminf(fmaxf(cy - 7.f, 0.f), 63.f));
    float y2 = floorf(fminf(cy + 7.f, 64.f));

    float sx = x1 + (j + 0.5f) * (x2 - x1) * (1.f / 14.f) - 0.5f;
    sx = fminf(fmaxf(sx, x1), x2 - 1.f);
    float sy = y1 + (i + 0.5f) * (y2 - y1) * (1.f / 14.f) - 0.5f;
    sy = fminf(fmaxf(sy, y1), y2 - 1.f);

    float ix0f = floorf(sx), iy0f = floorf(sy);
    float wx = sx - ix0f,    wy = sy - iy0f;
    int ix0 = (int)ix0f,     iy0 = (int)iy0f;
    int ix1 = (int)fminf(ix0f + 1.f, x2 - 1.f);
    int iy1 = (int)fminf(iy0f + 1.f, y2 - 1.f);

    const float* img = x + (long)bt * 64 * 64;
    float v00 = img[iy0 * 64 + ix0], v01 = img[iy0 * 64 + ix1];
    float v10 = img[iy1 * 64 + ix0], v11 = img[iy1 * 64 + ix1];
    float top = (1.f - wx) * v00 + wx * v01;
    float bot = (1.f - wx) * v10 + wx * v11;
    crops[idx] = (1.f - wy) * top + wy * bot;
}

// ---------------- tiny dense matmul: out[row,o] = in[row,:] @ w[:,o] --------
__global__ void matmul_small(const float* __restrict__ in, const float* __restrict__ w,
                             float* __restrict__ out, int rows, int Kd, int O)
{
    int idx = blockIdx.x * blockDim.x + threadIdx.x;
    if (idx >= rows * O) return;
    int row = idx / O, o = idx % O;
    float acc = 0.f;
    for (int k = 0; k < Kd; ++k) acc = fmaf(in[(long)row * Kd + k], w[k * O + o], acc);
    out[idx] = acc;
}

// ---------------- GAT attention scalars: s1 = h@a1, s2 = h@a2 ---------------
__global__ void gat_scores(const float* __restrict__ h, const float* __restrict__ a1,
                           const float* __restrict__ a2, float* __restrict__ s1,
                           float* __restrict__ s2, int total, int D)
{
    int idx = blockIdx.x * blockDim.x + threadIdx.x;
    if (idx >= total) return;
    const float* hr = h + (long)idx * D;
    float acc1 = 0.f, acc2 = 0.f;
    for (int k = 0; k < D; ++k) {
        acc1 = fmaf(hr[k], a1[k], acc1);
        acc2 = fmaf(hr[k], a2[k], acc2);
    }
    s1[idx] = acc1; s2[idx] = acc2;
}

// ---------------- GAT masked-softmax aggregate: block per (b,i) -------------
template <int D>
__global__ void gat_aggregate(const float* __restrict__ h, const float* __restrict__ s1,
                              const float* __restrict__ s2, float* __restrict__ out)
{
    int bi = blockIdx.x;                 // b*kN + i
    int b = bi / kN, i = bi % kN;
    int j = threadIdx.x;
    __shared__ float red[256];
    __shared__ float wsh[256];

    float ej = -1e30f;                   // invalid lanes
    if (j < kN) {
        int fri = i / kR, rki = i % kR;
        int frj = j / kR, rkj = j % kR;
        int df = fri - frj;
        bool adj = (fri == frj) || ((rki == rkj) && (df == 1 || df == -1));
        float v = s1[b * kN + i] + s2[b * kN + j];
        v = v > 0.f ? v : 0.2f * v;      // leaky_relu(0.2)
        ej = adj ? v : -9.0e15f;
    }
    red[j] = ej; __syncthreads();
#pragma unroll
    for (int off = 128; off > 0; off >>= 1) {
        if (j < off) red[j] = fmaxf(red[j], red[j + off]);
        __syncthreads();
    }
    float mx = red[0]; __syncthreads();

    float ex = (j < kN) ? expf(ej - mx) : 0.f;
    red[j] = ex; __syncthreads();
#pragma unroll
    for (int off = 128; off > 0; off >>= 1) {
        if (j < off) red[j] += red[j + off];
        __syncthreads();
    }
    float sum = red[0]; __syncthreads();

    wsh[j] = ex / sum; __syncthreads();

    if (j < D) {
        float acc = 0.f;
        for (int jj = 0; jj < kN; ++jj)
            acc = fmaf(wsh[jj], h[((long)b * kN + jj) * D + j], acc);
        out[((long)b * kN + i) * D + j] = acc;
    }
}

// ---------------- elu + log_softmax over last dim (16) ----------------------
__global__ void elu_logsoftmax(const float* __restrict__ in, float* __restrict__ out,
                               int rows)
{
    int r = blockIdx.x * blockDim.x + threadIdx.x;
    if (r >= rows) return;
    float v[16];
    float mx = -1e30f;
#pragma unroll
    for (int k = 0; k < 16; ++k) {
        float xv = in[(long)r * 16 + k];
        xv = xv > 0.f ? xv : expm1f(xv);
        v[k] = xv; mx = fmaxf(mx, xv);
    }
    float s = 0.f;
#pragma unroll
    for (int k = 0; k < 16; ++k) s += expf(v[k] - mx);
    float ls = logf(s) + mx;
#pragma unroll
    for (int k = 0; k < 16; ++k) out[(long)r * 16 + k] = v[k] - ls;
}

// ---------------- mean over nodes of concat(l_fc, gat_fc) -------------------
__global__ void lcat_mean(const float* __restrict__ lfc, const float* __restrict__ gatfc,
                          float* __restrict__ fcbuf)
{
    int idx = blockIdx.x * blockDim.x + threadIdx.x;
    if (idx >= kB * 272) return;
    int b = idx / 272, c = idx % 272;
    float s = 0.f;
    if (c < 256) {
        for (int n2 = 0; n2 < kN; ++n2) s += lfc[((long)b * kN + n2) * 256 + c];
    } else {
        int cc = c - 256;
        for (int n2 = 0; n2 < kN; ++n2) s += gatfc[((long)b * kN + n2) * 16 + cc];
    }
    fcbuf[b * 528 + 256 + c] = s * (1.f / kN);
}

// ---------------- final pyramid: mean+max over nb in (1,2,4,8,16) -----------
__global__ void final_feats(const float* __restrict__ fcbuf, float* __restrict__ out)
{
    int idx = blockIdx.x * blockDim.x + threadIdx.x;
    if (idx >= kB * 1023) return;
    int b = idx / 1023, m = idx % 1023;
    int nb, seg, off;
    if      (m < 528) { nb = 1;  seg = 528; off = 0;   }
    else if (m < 792) { nb = 2;  seg = 264; off = 528; }
    else if (m < 924) { nb = 4;  seg = 132; off = 792; }
    else if (m < 990) { nb = 8;  seg = 66;  off = 924; }
    else              { nb = 16; seg = 33;  off = 990; }
    int mm = m - off;
    float s = 0.f, mx = -1e30f;
    for (int k2 = 0; k2 < nb; ++k2) {
        float v = fcbuf[b * 528 + k2 * seg + mm];
        s += v; mx = fmaxf(mx, v);
    }
    out[(long)b * 1023 + m] = s / nb + mx;
}

// ---------------------------------------------------------------------------
extern "C" void kernel_launch(void* const* d_in, const int* in_sizes, int n_in,
                              void* d_out, int out_size, void* d_ws, size_t ws_size,
                              hipStream_t stream)
{
    const float* x       = (const float*)d_in[0];
    const float* px      = (const float*)d_in[1];
    const float* cw1     = (const float*)d_in[2];
    const float* cw2     = (const float*)d_in[3];
    const float* cw3     = (const float*)d_in[4];
    const float* cw4     = (const float*)d_in[5];
    const float* cw5     = (const float*)d_in[6];
    const float* cw6     = (const float*)d_in[7];
    const float* fc_g_w  = (const float*)d_in[8];
    const float* fc_g_b  = (const float*)d_in[9];
    const float* fc_l_w  = (const float*)d_in[10];
    const float* fc_l_b  = (const float*)d_in[11];
    const float* gat1_W  = (const float*)d_in[12];
    const float* gat1_a1 = (const float*)d_in[13];
    const float* gat1_a2 = (const float*)d_in[14];
    const float* gat2_W  = (const float*)d_in[15];
    const float* gat2_a1 = (const float*)d_in[16];
    const float* gat2_a2 = (const float*)d_in[17];

    float* ws    = (float*)d_ws;
    float* A     = ws;                    // 31,457,280 floats (125.8 MB)
    float* Bb    = A + 31457280;          //  7,864,320 floats ( 31.5 MB)
    float* crops = Bb + 7864320;          //    376,320
    float* gmaxb = crops + 376320;        //    262,144
    float* lfc   = gmaxb + 262144;        //    491,520
    float* h1    = lfc + 491520;          //     15,360
    float* s1    = h1 + 15360;            //      1,920
    float* s2    = s1 + 1920;             //      1,920
    float* o1    = s2 + 1920;             //     15,360
    float* h2    = o1 + 15360;            //     30,720
    float* s1b   = h2 + 30720;            //      1,920
    float* s2b   = s1b + 1920;            //      1,920
    float* o2    = s2b + 1920;            //     30,720
    float* gatfc = o2 + 30720;            //     30,720
    float* fcbuf = gatfc + 30720;         //      4,224   (total ~162 MB)

    auto cdiv = [](long a, long b) { return (int)((a + b - 1) / b); };
    const int TB = 256;

    // ---------------- global path ----------------
    conv_k<5, false><<<cdiv(240L * 32 * 64 * 64, TB), TB, 0, stream>>>(x,   cw1, A,  240, 1,   32, 64, 64);
    conv_k<3, true ><<<cdiv(240L * 32 * 32 * 32, TB), TB, 0, stream>>>(A,   cw2, Bb, 240, 32,  32, 64, 64);
    conv_k<3, false><<<cdiv(240L * 64 * 32 * 32, TB), TB, 0, stream>>>(Bb,  cw3, A,  240, 32,  64, 32, 32);
    conv_k<3, true ><<<cdiv(240L * 64 * 16 * 16, TB), TB, 0, stream>>>(A,   cw4, Bb, 240, 64,  64, 32, 32);
    conv_k<3, false><<<cdiv(240L * 128 * 16 * 16, TB), TB, 0, stream>>>(Bb, cw5, A,  240, 64, 128, 16, 16);
    conv_k<3, false><<<cdiv(240L * 128 * 16 * 16, TB), TB, 0, stream>>>(A,  cw6, Bb, 240, 128, 128, 16, 16);
    max_over_T<<<cdiv(8L * 32768, TB), TB, 0, stream>>>(Bb, gmaxb, 8, 30, 32768);
    linear_wpo<<<cdiv(8L * 256 * 64, TB), TB, 0, stream>>>(gmaxb, fc_g_w, fc_g_b, fcbuf, 8, 32768, 256, 528);

    // ---------------- local path ----------------
    roi_crop<<<cdiv(1920L * 196, TB), TB, 0, stream>>>(x, px, crops);
    conv_k<5, false><<<cdiv(1920L * 32 * 14 * 14, TB), TB, 0, stream>>>(crops, cw1, A,  1920, 1,   32, 14, 14);
    conv_k<3, true ><<<cdiv(1920L * 32 * 7 * 7,  TB), TB, 0, stream>>>(A,     cw2, Bb, 1920, 32,  32, 14, 14);
    conv_k<3, false><<<cdiv(1920L * 64 * 7 * 7,  TB), TB, 0, stream>>>(Bb,    cw3, A,  1920, 32,  64, 7, 7);
    conv_k<3, true ><<<cdiv(1920L * 64 * 3 * 3,  TB), TB, 0, stream>>>(A,     cw4, Bb, 1920, 64,  64, 7, 7);
    conv_k<3, false><<<cdiv(1920L * 128 * 3 * 3, TB), TB, 0, stream>>>(Bb,    cw5, A,  1920, 64, 128, 3, 3);
    conv_k<3, false><<<cdiv(1920L * 128 * 3 * 3, TB), TB, 0, stream>>>(A,     cw6, Bb, 1920, 128, 128, 3, 3);
    linear_wpo<<<cdiv(1920L * 256 * 64, TB), TB, 0, stream>>>(Bb, fc_l_w, fc_l_b, lfc, 1920, 1152, 256, 256);

    // ---------------- GAT ----------------
    matmul_small<<<cdiv(1920L * 8, TB), TB, 0, stream>>>(lfc, gat1_W, h1, kB * kN, 256, 8);
    gat_scores<<<cdiv(1920L, TB), TB, 0, stream>>>(h1, gat1_a1, gat1_a2, s1, s2, kB * kN, 8);
    gat_aggregate<8><<<kB * kN, TB, 0, stream>>>(h1, s1, s2, o1);
    matmul_small<<<cdiv(1920L * 16, TB), TB, 0, stream>>>(o1, gat2_W, h2, kB * kN, 8, 16);
    gat_scores<<<cdiv(1920L, TB), TB, 0, stream>>>(h2, gat2_a1, gat2_a2, s1b, s2b, kB * kN, 16);
    gat_aggregate<16><<<kB * kN, TB, 0, stream>>>(h2, s1b, s2b, o2);
    elu_logsoftmax<<<cdiv(1920L, TB), TB, 0, stream>>>(o2, gatfc, kB * kN);

    // ---------------- head ----------------
    lcat_mean<<<cdiv(8L * 272, TB), TB, 0, stream>>>(lfc, gatfc, fcbuf);
    final_feats<<<cdiv(8L * 1023, TB), TB, 0, stream>>>(fcbuf, (float*)d_out);
}

// Round 2
// 2728.842 us; speedup vs baseline: 9.5984x; 9.5984x over previous
//
#include <hip/hip_runtime.h>
#include <hip/hip_bf16.h>

// ---------------------------------------------------------------------------
// RGPNet forward. Round 2: LDS-staged compile-time-shaped conv kernels.
// ---------------------------------------------------------------------------

constexpr int kB = 8, kT = 30, kR = 8;
constexpr int kN = kT * kR;          // 240 nodes per batch
constexpr int kRH = 14, kRW = 14;

static __device__ __forceinline__ float lrelu01(float v) {
    return v > 0.f ? v : 0.01f * v;
}

// ---------------------------------------------------------------------------
// Tiled conv: block = (n, co-group, spatial tile). Input slab + weight chunk
// staged in LDS; per-thread register blocking CO_T x PT x PT.
// ---------------------------------------------------------------------------
template <int K, bool POOL, int Cin, int Cout, int H, int W,
          int TILE, int PT, int CO_T, int CIC>
__global__ __launch_bounds__(256) void conv_tile(
    const float* __restrict__ in, const float* __restrict__ wgt,
    float* __restrict__ out)
{
    constexpr int P   = K / 2;
    constexpr int NT  = (H + TILE - 1) / TILE;     // tiles per dim
    constexpr int SP  = TILE / PT;                 // patches per dim
    constexpr int SPT = SP * SP;                   // spatial threads
    constexpr int COS = 256 / SPT;                 // co sub-groups
    constexpr int COB = COS * CO_T;                // co per block
    constexpr int CG  = Cout / COB;                // co groups
    constexpr int SW  = TILE + 2 * P;              // slab valid width
    constexpr int RS  = (SW + 3) & ~3;             // slab row stride (align)
    constexpr int KK  = K * K;
    constexpr int WS  = CIC * KK + 1;              // weight per-co stride (pad)
    constexpr int Ho  = POOL ? H / 2 : H;
    constexpr int Wo  = POOL ? W / 2 : W;
    constexpr int XW  = PT + 2 * P;                // x patch width

    static_assert(256 % SPT == 0, "spt");
    static_assert(Cout % COB == 0, "cob");
    static_assert(Cin % CIC == 0, "cic");
    static_assert(TILE % PT == 0, "pt");

    __shared__ __align__(16) float slab[CIC * SW * RS];
    __shared__ __align__(16) float wl[COB * WS];

    int bid = blockIdx.x;
    const int cg = bid % CG; bid /= CG;
    const int tx = bid % NT; bid /= NT;
    const int ty = bid % NT;
    const int n  = bid / NT;
    const int x0 = tx * TILE, y0 = ty * TILE;
    const int co0 = cg * COB;

    const int tid  = threadIdx.x;
    const int sidx = tid % SPT, ssub = tid / SPT;
    const int px0  = (sidx % SP) * PT, py0 = (sidx / SP) * PT;

    float acc[CO_T][PT][PT];
#pragma unroll
    for (int c = 0; c < CO_T; ++c)
#pragma unroll
        for (int a = 0; a < PT; ++a)
#pragma unroll
            for (int b2 = 0; b2 < PT; ++b2) acc[c][a][b2] = 0.f;

    for (int cs = 0; cs < Cin; cs += CIC) {
        // ---- stage input slab (zero-padded) ----
        for (int i = tid; i < CIC * SW * SW; i += 256) {
            int ci = i / (SW * SW); int r = i % (SW * SW);
            int yy = r / SW, xx = r % SW;
            int gy = y0 + yy - P, gx = x0 + xx - P;
            float v = 0.f;
            if ((unsigned)gy < (unsigned)H && (unsigned)gx < (unsigned)W)
                v = in[(((long)n * Cin + cs + ci) * H + gy) * W + gx];
            slab[(ci * SW + yy) * RS + xx] = v;
        }
        // ---- stage weights ----
        for (int i = tid; i < COB * CIC * KK; i += 256) {
            int col = i / (CIC * KK); int r = i % (CIC * KK);
            wl[col * WS + r] = wgt[(((long)(co0 + col)) * Cin + cs) * KK + r];
        }
        __syncthreads();

        for (int ci = 0; ci < CIC; ++ci) {
            // x patch -> registers (vector LDS reads)
            float xr[XW][XW];
#pragma unroll
            for (int yy = 0; yy < XW; ++yy) {
                int xb = (ci * SW + py0 + yy) * RS + px0;
                if constexpr (PT == 4 && K == 3) {          // XW=6: f4+f2
                    float4 v4 = *(const float4*)&slab[xb];
                    float2 v2 = *(const float2*)&slab[xb + 4];
                    xr[yy][0]=v4.x; xr[yy][1]=v4.y; xr[yy][2]=v4.z; xr[yy][3]=v4.w;
                    xr[yy][4]=v2.x; xr[yy][5]=v2.y;
                } else if constexpr (PT == 4 && K == 5) {   // XW=8: 2xf4
                    float4 a4 = *(const float4*)&slab[xb];
                    float4 b4 = *(const float4*)&slab[xb + 4];
                    xr[yy][0]=a4.x; xr[yy][1]=a4.y; xr[yy][2]=a4.z; xr[yy][3]=a4.w;
                    xr[yy][4]=b4.x; xr[yy][5]=b4.y; xr[yy][6]=b4.z; xr[yy][7]=b4.w;
                } else {                                    // PT==2,K==3: XW=4
                    float2 a2 = *(const float2*)&slab[xb];
                    float2 b2 = *(const float2*)&slab[xb + 2];
                    xr[yy][0]=a2.x; xr[yy][1]=a2.y; xr[yy][2]=b2.x; xr[yy][3]=b2.y;
                }
            }
            // weights -> registers (broadcast within sub-group)
            float wr[CO_T][KK];
#pragma unroll
            for (int c = 0; c < CO_T; ++c)
#pragma unroll
                for (int k = 0; k < KK; ++k)
                    wr[c][k] = wl[(ssub * CO_T + c) * WS + ci * KK + k];
            // FMA
#pragma unroll
            for (int c = 0; c < CO_T; ++c)
#pragma unroll
                for (int oy = 0; oy < PT; ++oy)
#pragma unroll
                    for (int ox = 0; ox < PT; ++ox) {
                        float a = acc[c][oy][ox];
#pragma unroll
                        for (int ky = 0; ky < K; ++ky)
#pragma unroll
                            for (int kx = 0; kx < K; ++kx)
                                a = fmaf(xr[oy + ky][ox + kx], wr[c][ky * K + kx], a);
                        acc[c][oy][ox] = a;
                    }
        }
        __syncthreads();
    }

    // ---- write (fused leaky_relu, optional 2x2 maxpool) ----
    if constexpr (!POOL) {
#pragma unroll
        for (int c = 0; c < CO_T; ++c) {
            int co = co0 + ssub * CO_T + c;
#pragma unroll
            for (int oy = 0; oy < PT; ++oy) {
                int y = y0 + py0 + oy;
                if (y >= H) continue;
#pragma unroll
                for (int ox = 0; ox < PT; ++ox) {
                    int x = x0 + px0 + ox;
                    if (x >= W) continue;
                    out[(((long)n * Cout + co) * H + y) * W + x] = lrelu01(acc[c][oy][ox]);
                }
            }
        }
    } else {
        constexpr int Q = PT / 2;
#pragma unroll
        for (int c = 0; c < CO_T; ++c) {
            int co = co0 + ssub * CO_T + c;
#pragma unroll
            for (int i = 0; i < Q; ++i) {
                int yp = (y0 + py0) / 2 + i;
                if (yp >= Ho) continue;
#pragma unroll
                for (int j = 0; j < Q; ++j) {
                    int xp = (x0 + px0) / 2 + j;
                    if (xp >= Wo) continue;
                    float m = lrelu01(acc[c][2*i][2*j]);
                    m = fmaxf(m, lrelu01(acc[c][2*i][2*j+1]));
                    m = fmaxf(m, lrelu01(acc[c][2*i+1][2*j]));
                    m = fmaxf(m, lrelu01(acc[c][2*i+1][2*j+1]));
                    out[(((long)n * Cout + co) * Ho + yp) * Wo + xp] = m;
                }
            }
        }
    }
}

// ---------------------------------------------------------------------------
// Tiny conv for 3x3 maps (L5/L6): block = 2 images x 128 co.
// ---------------------------------------------------------------------------
template <int Cin>
__global__ __launch_bounds__(256) void conv_tiny(
    const float* __restrict__ in, const float* __restrict__ wgt,
    float* __restrict__ out)
{
    constexpr int CIC = 8;
    constexpr int WS = CIC * 9 + 1;              // 73 (bank-spread)
    __shared__ __align__(16) float slab[2 * CIC * 28];
    __shared__ __align__(16) float wl[128 * WS];

    const int tid = threadIdx.x;
    const int il = tid >> 7, co = tid & 127;
    const int n0 = blockIdx.x * 2;

    float acc[9];
#pragma unroll
    for (int s = 0; s < 9; ++s) acc[s] = 0.f;

    for (int cs = 0; cs < Cin; cs += CIC) {
        for (int i = tid; i < 2 * CIC * 25; i += 256) {
            int im = i / (CIC * 25); int r = i % (CIC * 25);
            int ci = r / 25, s = r % 25;
            int gy = s / 5 - 1, gx = s % 5 - 1;
            float v = 0.f;
            if ((unsigned)gy < 3u && (unsigned)gx < 3u)
                v = in[(((long)(n0 + im) * Cin) + cs + ci) * 9 + gy * 3 + gx];
            slab[(im * CIC + ci) * 28 + s] = v;
        }
        for (int i = tid; i < 128 * CIC * 9; i += 256) {
            int c2 = i / (CIC * 9); int r = i % (CIC * 9);
            wl[c2 * WS + r] = wgt[((long)c2 * Cin + cs) * 9 + r];
        }
        __syncthreads();

        for (int ci = 0; ci < CIC; ++ci) {
            float xr[28];
            const float4* xp = (const float4*)&slab[(il * CIC + ci) * 28];
#pragma unroll
            for (int q = 0; q < 7; ++q) {
                float4 v = xp[q];
                xr[q*4+0]=v.x; xr[q*4+1]=v.y; xr[q*4+2]=v.z; xr[q*4+3]=v.w;
            }
            float wr[9];
#pragma unroll
            for (int k = 0; k < 9; ++k) wr[k] = wl[co * WS + ci * 9 + k];
#pragma unroll
            for (int oy = 0; oy < 3; ++oy)
#pragma unroll
                for (int ox = 0; ox < 3; ++ox) {
                    float a = acc[oy * 3 + ox];
#pragma unroll
                    for (int ky = 0; ky < 3; ++ky)
#pragma unroll
                        for (int kx = 0; kx < 3; ++kx)
                            a = fmaf(xr[(oy + ky) * 5 + ox + kx], wr[ky * 3 + kx], a);
                    acc[oy * 3 + ox] = a;
                }
        }
        __syncthreads();
    }
#pragma unroll
    for (int s = 0; s < 9; ++s)
        out[((long)(n0 + il) * 128 + co) * 9 + s] = lrelu01(acc[s]);
}

// ---------------- max over T --------------------------------------------------
__global__ void max_over_T(const float* __restrict__ in, float* __restrict__ out,
                           int Bn, int Tn, int F)
{
    long idx = (long)blockIdx.x * blockDim.x + threadIdx.x;
    if (idx >= (long)Bn * F) return;
    int b = (int)(idx / F), f = (int)(idx % F);
    float m = -1e30f;
    for (int t = 0; t < Tn; ++t)
        m = fmaxf(m, in[((long)(b * Tn + t)) * F + f]);
    out[idx] = m;
}

// ---------------- FC layer: wave-per-output ----------------------------------
__global__ void linear_wpo(const float* __restrict__ in, const float* __restrict__ w,
                           const float* __restrict__ bias, float* __restrict__ out,
                           int M, int Kd, int O, int ldo)
{
    long gid = (long)blockIdx.x * blockDim.x + threadIdx.x;
    long wid = gid >> 6;
    int lane = (int)(gid & 63);
    if (wid >= (long)M * O) return;
    int m = (int)(wid / O), o = (int)(wid % O);
    const float* ir = in + (long)m * Kd;
    const float* wr = w  + (long)o * Kd;
    float acc = 0.f;
    for (int k = lane; k < Kd; k += 64) acc = fmaf(ir[k], wr[k], acc);
#pragma unroll
    for (int off = 32; off > 0; off >>= 1) acc += __shfl_down(acc, off, 64);
    if (lane == 0) out[(long)m * ldo + o] = acc + bias[o];
}

// ---------------- ROI crop + bilinear resize ----------------------------------
__global__ void roi_crop(const float* __restrict__ x, const float* __restrict__ px,
                         float* __restrict__ crops)
{
    int idx = blockIdx.x * blockDim.x + threadIdx.x;
    const int total = kB * kT * kR * kRH * kRW;
    if (idx >= total) return;
    int j  = idx % kRW; int t2 = idx / kRW;
    int i  = t2 % kRH;  t2 /= kRH;
    int r  = t2 % kR;   int bt = t2 / kR;

    float cx = px[(bt * kR + r) * 2 + 0];
    float cy = px[(bt * kR + r) * 2 + 1];
    float x1 = floorf(fminf(fmaxf(cx - 7.f, 0.f), 63.f));
    float x2 = floorf(fminf(cx + 7.f, 64.f));
    float y1 = floorf(fminf(fmaxf(cy - 7.f, 0.f), 63.f));
    float y2 = floorf(fminf(cy + 7.f, 64.f));

    float sx = x1 + (j + 0.5f) * (x2 - x1) * (1.f / 14.f) - 0.5f;
    sx = fminf(fmaxf(sx, x1), x2 - 1.f);
    float sy = y1 + (i + 0.5f) * (y2 - y1) * (1.f / 14.f) - 0.5f;
    sy = fminf(fmaxf(sy, y1), y2 - 1.f);

    float ix0f = floorf(sx), iy0f = floorf(sy);
    float wx = sx - ix0f,    wy = sy - iy0f;
    int ix0 = (int)ix0f,     iy0 = (int)iy0f;
    int ix1 = (int)fminf(ix0f + 1.f, x2 - 1.f);
    int iy1 = (int)fminf(iy0f + 1.f, y2 - 1.f);

    const float* img = x + (long)bt * 64 * 64;
    float v00 = img[iy0 * 64 + ix0], v01 = img[iy0 * 64 + ix1];
    float v10 = img[iy1 * 64 + ix0], v11 = img[iy1 * 64 + ix1];
    float top = (1.f - wx) * v00 + wx * v01;
    float bot = (1.f - wx) * v10 + wx * v11;
    crops[idx] = (1.f - wy) * top + wy * bot;
}

// ---------------- tiny dense matmul ------------------------------------------
__global__ void matmul_small(const float* __restrict__ in, const float* __restrict__ w,
                             float* __restrict__ out, int rows, int Kd, int O)
{
    int idx = blockIdx.x * blockDim.x + threadIdx.x;
    if (idx >= rows * O) return;
    int row = idx / O, o = idx % O;
    float acc = 0.f;
    for (int k = 0; k < Kd; ++k) acc = fmaf(in[(long)row * Kd + k], w[k * O + o], acc);
    out[idx] = acc;
}

// ---------------- GAT attention scalars ---------------------------------------
__global__ void gat_scores(const float* __restrict__ h, const float* __restrict__ a1,
                           const float* __restrict__ a2, float* __restrict__ s1,
                           float* __restrict__ s2, int total, int D)
{
    int idx = blockIdx.x * blockDim.x + threadIdx.x;
    if (idx >= total) return;
    const float* hr = h + (long)idx * D;
    float acc1 = 0.f, acc2 = 0.f;
    for (int k = 0; k < D; ++k) {
        acc1 = fmaf(hr[k], a1[k], acc1);
        acc2 = fmaf(hr[k], a2[k], acc2);
    }
    s1[idx] = acc1; s2[idx] = acc2;
}

// ---------------- GAT masked-softmax aggregate --------------------------------
template <int D>
__global__ void gat_aggregate(const float* __restrict__ h, const float* __restrict__ s1,
                              const float* __restrict__ s2, float* __restrict__ out)
{
    int bi = blockIdx.x;
    int b = bi / kN, i = bi % kN;
    int j = threadIdx.x;
    __shared__ float red[256];
    __shared__ float wsh[256];

    float ej = -1e30f;
    if (j < kN) {
        int fri = i / kR, rki = i % kR;
        int frj = j / kR, rkj = j % kR;
        int df = fri - frj;
        bool adj = (fri == frj) || ((rki == rkj) && (df == 1 || df == -1));
        float v = s1[b * kN + i] + s2[b * kN + j];
        v = v > 0.f ? v : 0.2f * v;
        ej = adj ? v : -9.0e15f;
    }
    red[j] = ej; __syncthreads();
#pragma unroll
    for (int off = 128; off > 0; off >>= 1) {
        if (j < off) red[j] = fmaxf(red[j], red[j + off]);
        __syncthreads();
    }
    float mx = red[0]; __syncthreads();

    float ex = (j < kN) ? expf(ej - mx) : 0.f;
    red[j] = ex; __syncthreads();
#pragma unroll
    for (int off = 128; off > 0; off >>= 1) {
        if (j < off) red[j] += red[j + off];
        __syncthreads();
    }
    float sum = red[0]; __syncthreads();

    wsh[j] = ex / sum; __syncthreads();

    if (j < D) {
        float acc = 0.f;
        for (int jj = 0; jj < kN; ++jj)
            acc = fmaf(wsh[jj], h[((long)b * kN + jj) * D + j], acc);
        out[((long)b * kN + i) * D + j] = acc;
    }
}

// ---------------- elu + log_softmax (last dim 16) -----------------------------
__global__ void elu_logsoftmax(const float* __restrict__ in, float* __restrict__ out,
                               int rows)
{
    int r = blockIdx.x * blockDim.x + threadIdx.x;
    if (r >= rows) return;
    float v[16];
    float mx = -1e30f;
#pragma unroll
    for (int k = 0; k < 16; ++k) {
        float xv = in[(long)r * 16 + k];
        xv = xv > 0.f ? xv : expm1f(xv);
        v[k] = xv; mx = fmaxf(mx, xv);
    }
    float s = 0.f;
#pragma unroll
    for (int k = 0; k < 16; ++k) s += expf(v[k] - mx);
    float ls = logf(s) + mx;
#pragma unroll
    for (int k = 0; k < 16; ++k) out[(long)r * 16 + k] = v[k] - ls;
}

// ---------------- mean over nodes of concat(l_fc, gat_fc) ---------------------
__global__ void lcat_mean(const float* __restrict__ lfc, const float* __restrict__ gatfc,
                          float* __restrict__ fcbuf)
{
    int idx = blockIdx.x * blockDim.x + threadIdx.x;
    if (idx >= kB * 272) return;
    int b = idx / 272, c = idx % 272;
    float s = 0.f;
    if (c < 256) {
        for (int n2 = 0; n2 < kN; ++n2) s += lfc[((long)b * kN + n2) * 256 + c];
    } else {
        int cc = c - 256;
        for (int n2 = 0; n2 < kN; ++n2) s += gatfc[((long)b * kN + n2) * 16 + cc];
    }
    fcbuf[b * 528 + 256 + c] = s * (1.f / kN);
}

// ---------------- final pyramid ----------------------------------------------
__global__ void final_feats(const float* __restrict__ fcbuf, float* __restrict__ out)
{
    int idx = blockIdx.x * blockDim.x + threadIdx.x;
    if (idx >= kB * 1023) return;
    int b = idx / 1023, m = idx % 1023;
    int nb, seg, off;
    if      (m < 528) { nb = 1;  seg = 528; off = 0;   }
    else if (m < 792) { nb = 2;  seg = 264; off = 528; }
    else if (m < 924) { nb = 4;  seg = 132; off = 792; }
    else if (m < 990) { nb = 8;  seg = 66;  off = 924; }
    else              { nb = 16; seg = 33;  off = 990; }
    int mm = m - off;
    float s = 0.f, mx = -1e30f;
    for (int k2 = 0; k2 < nb; ++k2) {
        float v = fcbuf[b * 528 + k2 * seg + mm];
        s += v; mx = fmaxf(mx, v);
    }
    out[(long)b * 1023 + m] = s / nb + mx;
}

// ---------------------------------------------------------------------------
extern "C" void kernel_launch(void* const* d_in, const int* in_sizes, int n_in,
                              void* d_out, int out_size, void* d_ws, size_t ws_size,
                              hipStream_t stream)
{
    const float* x       = (const float*)d_in[0];
    const float* px      = (const float*)d_in[1];
    const float* cw1     = (const float*)d_in[2];
    const float* cw2     = (const float*)d_in[3];
    const float* cw3     = (const float*)d_in[4];
    const float* cw4     = (const float*)d_in[5];
    const float* cw5     = (const float*)d_in[6];
    const float* cw6     = (const float*)d_in[7];
    const float* fc_g_w  = (const float*)d_in[8];
    const float* fc_g_b  = (const float*)d_in[9];
    const float* fc_l_w  = (const float*)d_in[10];
    const float* fc_l_b  = (const float*)d_in[11];
    const float* gat1_W  = (const float*)d_in[12];
    const float* gat1_a1 = (const float*)d_in[13];
    const float* gat1_a2 = (const float*)d_in[14];
    const float* gat2_W  = (const float*)d_in[15];
    const float* gat2_a1 = (const float*)d_in[16];
    const float* gat2_a2 = (const float*)d_in[17];

    float* ws    = (float*)d_ws;
    float* A     = ws;
    float* Bb    = A + 31457280;
    float* crops = Bb + 7864320;
    float* gmaxb = crops + 376320;
    float* lfc   = gmaxb + 262144;
    float* h1    = lfc + 491520;
    float* s1    = h1 + 15360;
    float* s2    = s1 + 1920;
    float* o1    = s2 + 1920;
    float* h2    = o1 + 15360;
    float* s1b   = h2 + 30720;
    float* s2b   = s1b + 1920;
    float* o2    = s2b + 1920;
    float* gatfc = o2 + 30720;
    float* fcbuf = gatfc + 30720;

    auto cdiv = [](long a, long b) { return (int)((a + b - 1) / b); };
    const int TB = 256;

    // ---------------- global path ----------------
    //            K  POOL  Cin Cout  H   W  TILE PT CO_T CIC      blocks = N*NT^2*CG
    conv_tile<5, false,  1,  32, 64, 64, 32, 4, 2,  1><<<3840, 256, 0, stream>>>(x,  cw1, A);
    conv_tile<3, true,  32,  32, 64, 64, 32, 4, 4,  8><<<1920, 256, 0, stream>>>(A,  cw2, Bb);
    conv_tile<3, false, 32,  64, 32, 32, 32, 4, 4,  8><<< 960, 256, 0, stream>>>(Bb, cw3, A);
    conv_tile<3, true,  64,  64, 32, 32, 32, 4, 4,  8><<< 960, 256, 0, stream>>>(A,  cw4, Bb);
    conv_tile<3, false, 64, 128, 16, 16, 16, 4, 4, 16><<< 480, 256, 0, stream>>>(Bb, cw5, A);
    conv_tile<3, false,128, 128, 16, 16, 16, 4, 4, 16><<< 480, 256, 0, stream>>>(A,  cw6, Bb);
    max_over_T<<<cdiv(8L * 32768, TB), TB, 0, stream>>>(Bb, gmaxb, 8, 30, 32768);
    linear_wpo<<<cdiv(8L * 256 * 64, TB), TB, 0, stream>>>(gmaxb, fc_g_w, fc_g_b, fcbuf, 8, 32768, 256, 528);

    // ---------------- local path ----------------
    roi_crop<<<cdiv(1920L * 196, TB), TB, 0, stream>>>(x, px, crops);
    conv_tile<5, false,  1,  32, 14, 14, 16, 4, 2,  1><<<1920, 256, 0, stream>>>(crops, cw1, A);
    conv_tile<3, true,  32,  32, 14, 14, 16, 4, 2, 16><<<1920, 256, 0, stream>>>(A,  cw2, Bb);
    conv_tile<3, false, 32,  64,  7,  7,  8, 2, 4,  8><<<1920, 256, 0, stream>>>(Bb, cw3, A);
    conv_tile<3, true,  64,  64,  7,  7,  8, 2, 4,  8><<<1920, 256, 0, stream>>>(A,  cw4, Bb);
    conv_tiny<64 ><<<960, 256, 0, stream>>>(Bb, cw5, A);
    conv_tiny<128><<<960, 256, 0, stream>>>(A,  cw6, Bb);
    linear_wpo<<<cdiv(1920L * 256 * 64, TB), TB, 0, stream>>>(Bb, fc_l_w, fc_l_b, lfc, 1920, 1152, 256, 256);

    // ---------------- GAT ----------------
    matmul_small<<<cdiv(1920L * 8, TB), TB, 0, stream>>>(lfc, gat1_W, h1, kB * kN, 256, 8);
    gat_scores<<<cdiv(1920L, TB), TB, 0, stream>>>(h1, gat1_a1, gat1_a2, s1, s2, kB * kN, 8);
    gat_aggregate<8><<<kB * kN, TB, 0, stream>>>(h1, s1, s2, o1);
    matmul_small<<<cdiv(1920L * 16, TB), TB, 0, stream>>>(o1, gat2_W, h2, kB * kN, 8, 16);
    gat_scores<<<cdiv(1920L, TB), TB, 0, stream>>>(h2, gat2_a1, gat2_a2, s1b, s2b, kB * kN, 16);
    gat_aggregate<16><<<kB * kN, TB, 0, stream>>>(h2, s1b, s2b, o2);
    elu_logsoftmax<<<cdiv(1920L, TB), TB, 0, stream>>>(o2, gatfc, kB * kN);

    // ---------------- head ----------------
    lcat_mean<<<cdiv(8L * 272, TB), TB, 0, stream>>>(lfc, gatfc, fcbuf);
    final_feats<<<cdiv(8L * 1023, TB), TB, 0, stream>>>(fcbuf, (float*)d_out);
}

// Round 3
// 1913.675 us; speedup vs baseline: 13.6870x; 1.4260x over previous
//
#include <hip/hip_runtime.h>
#include <hip/hip_bf16.h>

// ---------------------------------------------------------------------------
// RGPNet forward. Round 3: global-path convs 2..6 as bf16 MFMA implicit GEMM.
// ---------------------------------------------------------------------------

constexpr int kB = 8, kT = 30, kR = 8;
constexpr int kN = kT * kR;          // 240 nodes per batch
constexpr int kRH = 14, kRW = 14;

static __device__ __forceinline__ float lrelu01(float v) {
    return v > 0.f ? v : 0.01f * v;
}

typedef __attribute__((ext_vector_type(8))) short bf16x8;
typedef __attribute__((ext_vector_type(4))) float f32x4;

static __device__ __forceinline__ short f2bf(float v) {
    __hip_bfloat16 h = __float2bfloat16(v);
    return *reinterpret_cast<short*>(&h);
}

// ---------------------------------------------------------------------------
// Weight repack: OIHW fp32 -> per-lane B-fragment bf16 layout.
// Bp[((cs*9 + kykx)*NFTOT + nf)*64 + lane][j] = W[nf*16+(lane&15)][cs*32+(lane>>4)*8+j][ky][kx]
// ---------------------------------------------------------------------------
template <int Cin, int Cout>
__global__ void repack_w(const float* __restrict__ w, short* __restrict__ bp)
{
    constexpr int NFTOT = Cout / 16, CS = Cin / 32;
    int t = blockIdx.x * blockDim.x + threadIdx.x;
    if (t >= CS * 9 * NFTOT * 64) return;
    int lane = t & 63, rest = t >> 6;
    int nf = rest % NFTOT; rest /= NFTOT;
    int kykx = rest % 9; int cs = rest / 9;
    int co  = nf * 16 + (lane & 15);
    int cib = cs * 32 + (lane >> 4) * 8;
#pragma unroll
    for (int j = 0; j < 8; ++j) {
        float v = w[((long)co * Cin + cib + j) * 9 + kykx];
        bp[(long)t * 8 + j] = f2bf(v);
    }
}

// ---------------------------------------------------------------------------
// MFMA implicit-GEMM 3x3 conv, pad 1. Block: 16x16 spatial tile of one image,
// NF co-fragments. fp32 NCHW in/out; bf16 LDS staging; fused lrelu(+pool).
// ---------------------------------------------------------------------------
template <int Cin, int Cout, int H, int W, bool POOL, int NSPLIT>
__global__ __launch_bounds__(256) void conv_mfma(
    const float* __restrict__ in, const short* __restrict__ bp,
    float* __restrict__ out)
{
    constexpr int NFTOT = Cout / 16;
    constexpr int NF    = NFTOT / NSPLIT;
    constexpr int CS    = Cin / 32;
    constexpr int TX    = W / 16, TY = H / 16;
    constexpr int CP    = 40;                 // channel stride in shorts (16B-aligned)
    constexpr int Ho    = POOL ? H / 2 : H, Wo = POOL ? W / 2 : W;

    __shared__ short slab[18 * 18 * CP];      // 25.9 KB

    int bid = blockIdx.x;
    const int split = bid % NSPLIT; bid /= NSPLIT;
    const int txt = bid % TX; bid /= TX;
    const int tyt = bid % TY; bid /= TY;
    const int n   = bid;
    const int x0 = txt * 16, y0 = tyt * 16;
    const int nf0 = split * NF;

    const int tid = threadIdx.x;
    const int lane = tid & 63, wav = tid >> 6;
    const int mrow0 = wav * 4;                // ty rows owned by this wave
    const int lx = lane & 15, lg = lane >> 4;

    f32x4 acc[4][NF];
#pragma unroll
    for (int r = 0; r < 4; ++r)
#pragma unroll
        for (int f = 0; f < NF; ++f) acc[r][f] = (f32x4)0.f;

    for (int cs = 0; cs < CS; ++cs) {
        // ---- stage 18x18 x 32ci slab, NCHW fp32 -> [y][x][ci] bf16 ----
        for (int i = tid; i < 18 * 18 * 32; i += 256) {
            int ci = i / 324, r2 = i % 324;
            int yy = r2 / 18, xx = r2 % 18;
            int gy = y0 - 1 + yy, gx = x0 - 1 + xx;
            float v = 0.f;
            if ((unsigned)gy < (unsigned)H && (unsigned)gx < (unsigned)W)
                v = in[(((long)n * Cin + cs * 32 + ci) * H + gy) * W + gx];
            slab[(yy * 18 + xx) * CP + ci] = f2bf(v);
        }
        __syncthreads();

#pragma unroll
        for (int ky = 0; ky < 3; ++ky)
#pragma unroll
        for (int kx = 0; kx < 3; ++kx) {
            bf16x8 a[4];
#pragma unroll
            for (int r = 0; r < 4; ++r)
                a[r] = *(const bf16x8*)&slab[((mrow0 + r + ky) * 18 + lx + kx) * CP + lg * 8];
            const int kykx = ky * 3 + kx;
#pragma unroll
            for (int f = 0; f < NF; ++f) {
                bf16x8 b = *(const bf16x8*)&bp[(((long)(cs * 9 + kykx) * NFTOT + nf0 + f) * 64 + lane) * 8];
#pragma unroll
                for (int r = 0; r < 4; ++r)
                    acc[r][f] = __builtin_amdgcn_mfma_f32_16x16x32_bf16(a[r], b, acc[r][f], 0, 0, 0);
            }
        }
        __syncthreads();
    }

    // ---- epilogue: C row = M = tx = lg*4+reg, col = N = co = lx ----
    if constexpr (!POOL) {
#pragma unroll
        for (int f = 0; f < NF; ++f) {
            int co = (nf0 + f) * 16 + lx;
#pragma unroll
            for (int r = 0; r < 4; ++r) {
                int y = y0 + mrow0 + r;
                float4 v;
                v.x = lrelu01(acc[r][f][0]); v.y = lrelu01(acc[r][f][1]);
                v.z = lrelu01(acc[r][f][2]); v.w = lrelu01(acc[r][f][3]);
                *(float4*)&out[(((long)n * Cout + co) * H + y) * W + x0 + lg * 4] = v;
            }
        }
    } else {
#pragma unroll
        for (int f = 0; f < NF; ++f) {
            int co = (nf0 + f) * 16 + lx;
#pragma unroll
            for (int q = 0; q < 2; ++q) {
                int yp = (y0 >> 1) + wav * 2 + q;
                float m0 = fmaxf(fmaxf(lrelu01(acc[2*q][f][0]), lrelu01(acc[2*q][f][1])),
                                 fmaxf(lrelu01(acc[2*q+1][f][0]), lrelu01(acc[2*q+1][f][1])));
                float m1 = fmaxf(fmaxf(lrelu01(acc[2*q][f][2]), lrelu01(acc[2*q][f][3])),
                                 fmaxf(lrelu01(acc[2*q+1][f][2]), lrelu01(acc[2*q+1][f][3])));
                float2 v; v.x = m0; v.y = m1;
                *(float2*)&out[(((long)n * Cout + co) * Ho + yp) * Wo + (x0 >> 1) + lg * 2] = v;
            }
        }
    }
}

// ---------------------------------------------------------------------------
// Tiled fp32 conv (kept for conv1 + local path).
// ---------------------------------------------------------------------------
template <int K, bool POOL, int Cin, int Cout, int H, int W,
          int TILE, int PT, int CO_T, int CIC>
__global__ __launch_bounds__(256) void conv_tile(
    const float* __restrict__ in, const float* __restrict__ wgt,
    float* __restrict__ out)
{
    constexpr int P   = K / 2;
    constexpr int NT  = (H + TILE - 1) / TILE;
    constexpr int SP  = TILE / PT;
    constexpr int SPT = SP * SP;
    constexpr int COS = 256 / SPT;
    constexpr int COB = COS * CO_T;
    constexpr int CG  = Cout / COB;
    constexpr int SW  = TILE + 2 * P;
    constexpr int RS  = (SW + 3) & ~3;
    constexpr int KK  = K * K;
    constexpr int WS  = CIC * KK + 1;
    constexpr int Ho  = POOL ? H / 2 : H;
    constexpr int Wo  = POOL ? W / 2 : W;
    constexpr int XW  = PT + 2 * P;

    static_assert(256 % SPT == 0, "spt");
    static_assert(Cout % COB == 0, "cob");
    static_assert(Cin % CIC == 0, "cic");
    static_assert(TILE % PT == 0, "pt");

    __shared__ __align__(16) float slab[CIC * SW * RS];
    __shared__ __align__(16) float wl[COB * WS];

    int bid = blockIdx.x;
    const int cg = bid % CG; bid /= CG;
    const int tx = bid % NT; bid /= NT;
    const int ty = bid % NT;
    const int n  = bid / NT;
    const int x0 = tx * TILE, y0 = ty * TILE;
    const int co0 = cg * COB;

    const int tid  = threadIdx.x;
    const int sidx = tid % SPT, ssub = tid / SPT;
    const int px0  = (sidx % SP) * PT, py0 = (sidx / SP) * PT;

    float acc[CO_T][PT][PT];
#pragma unroll
    for (int c = 0; c < CO_T; ++c)
#pragma unroll
        for (int a = 0; a < PT; ++a)
#pragma unroll
            for (int b2 = 0; b2 < PT; ++b2) acc[c][a][b2] = 0.f;

    for (int cs = 0; cs < Cin; cs += CIC) {
        for (int i = tid; i < CIC * SW * SW; i += 256) {
            int ci = i / (SW * SW); int r = i % (SW * SW);
            int yy = r / SW, xx = r % SW;
            int gy = y0 + yy - P, gx = x0 + xx - P;
            float v = 0.f;
            if ((unsigned)gy < (unsigned)H && (unsigned)gx < (unsigned)W)
                v = in[(((long)n * Cin + cs + ci) * H + gy) * W + gx];
            slab[(ci * SW + yy) * RS + xx] = v;
        }
        for (int i = tid; i < COB * CIC * KK; i += 256) {
            int col = i / (CIC * KK); int r = i % (CIC * KK);
            wl[col * WS + r] = wgt[(((long)(co0 + col)) * Cin + cs) * KK + r];
        }
        __syncthreads();

        for (int ci = 0; ci < CIC; ++ci) {
            float xr[XW][XW];
#pragma unroll
            for (int yy = 0; yy < XW; ++yy) {
                int xb = (ci * SW + py0 + yy) * RS + px0;
                if constexpr (PT == 4 && K == 3) {
                    float4 v4 = *(const float4*)&slab[xb];
                    float2 v2 = *(const float2*)&slab[xb + 4];
                    xr[yy][0]=v4.x; xr[yy][1]=v4.y; xr[yy][2]=v4.z; xr[yy][3]=v4.w;
                    xr[yy][4]=v2.x; xr[yy][5]=v2.y;
                } else if constexpr (PT == 4 && K == 5) {
                    float4 a4 = *(const float4*)&slab[xb];
                    float4 b4 = *(const float4*)&slab[xb + 4];
                    xr[yy][0]=a4.x; xr[yy][1]=a4.y; xr[yy][2]=a4.z; xr[yy][3]=a4.w;
                    xr[yy][4]=b4.x; xr[yy][5]=b4.y; xr[yy][6]=b4.z; xr[yy][7]=b4.w;
                } else {
                    float2 a2 = *(const float2*)&slab[xb];
                    float2 b2 = *(const float2*)&slab[xb + 2];
                    xr[yy][0]=a2.x; xr[yy][1]=a2.y; xr[yy][2]=b2.x; xr[yy][3]=b2.y;
                }
            }
            float wr[CO_T][KK];
#pragma unroll
            for (int c = 0; c < CO_T; ++c)
#pragma unroll
                for (int k = 0; k < KK; ++k)
                    wr[c][k] = wl[(ssub * CO_T + c) * WS + ci * KK + k];
#pragma unroll
            for (int c = 0; c < CO_T; ++c)
#pragma unroll
                for (int oy = 0; oy < PT; ++oy)
#pragma unroll
                    for (int ox = 0; ox < PT; ++ox) {
                        float a = acc[c][oy][ox];
#pragma unroll
                        for (int ky = 0; ky < K; ++ky)
#pragma unroll
                            for (int kx = 0; kx < K; ++kx)
                                a = fmaf(xr[oy + ky][ox + kx], wr[c][ky * K + kx], a);
                        acc[c][oy][ox] = a;
                    }
        }
        __syncthreads();
    }

    if constexpr (!POOL) {
#pragma unroll
        for (int c = 0; c < CO_T; ++c) {
            int co = co0 + ssub * CO_T + c;
#pragma unroll
            for (int oy = 0; oy < PT; ++oy) {
                int y = y0 + py0 + oy;
                if (y >= H) continue;
#pragma unroll
                for (int ox = 0; ox < PT; ++ox) {
                    int x = x0 + px0 + ox;
                    if (x >= W) continue;
                    out[(((long)n * Cout + co) * H + y) * W + x] = lrelu01(acc[c][oy][ox]);
                }
            }
        }
    } else {
        constexpr int Q = PT / 2;
#pragma unroll
        for (int c = 0; c < CO_T; ++c) {
            int co = co0 + ssub * CO_T + c;
#pragma unroll
            for (int i = 0; i < Q; ++i) {
                int yp = (y0 + py0) / 2 + i;
                if (yp >= Ho) continue;
#pragma unroll
                for (int j = 0; j < Q; ++j) {
                    int xp = (x0 + px0) / 2 + j;
                    if (xp >= Wo) continue;
                    float m = lrelu01(acc[c][2*i][2*j]);
                    m = fmaxf(m, lrelu01(acc[c][2*i][2*j+1]));
                    m = fmaxf(m, lrelu01(acc[c][2*i+1][2*j]));
                    m = fmaxf(m, lrelu01(acc[c][2*i+1][2*j+1]));
                    out[(((long)n * Cout + co) * Ho + yp) * Wo + xp] = m;
                }
            }
        }
    }
}

// ---------------------------------------------------------------------------
// Tiny conv for 3x3 maps (local L5/L6): block = 2 images x 128 co.
// ---------------------------------------------------------------------------
template <int Cin>
__global__ __launch_bounds__(256) void conv_tiny(
    const float* __restrict__ in, const float* __restrict__ wgt,
    float* __restrict__ out)
{
    constexpr int CIC = 8;
    constexpr int WS = CIC * 9 + 1;
    __shared__ __align__(16) float slab[2 * CIC * 28];
    __shared__ __align__(16) float wl[128 * WS];

    const int tid = threadIdx.x;
    const int il = tid >> 7, co = tid & 127;
    const int n0 = blockIdx.x * 2;

    float acc[9];
#pragma unroll
    for (int s = 0; s < 9; ++s) acc[s] = 0.f;

    for (int cs = 0; cs < Cin; cs += CIC) {
        for (int i = tid; i < 2 * CIC * 25; i += 256) {
            int im = i / (CIC * 25); int r = i % (CIC * 25);
            int ci = r / 25, s = r % 25;
            int gy = s / 5 - 1, gx = s % 5 - 1;
            float v = 0.f;
            if ((unsigned)gy < 3u && (unsigned)gx < 3u)
                v = in[(((long)(n0 + im) * Cin) + cs + ci) * 9 + gy * 3 + gx];
            slab[(im * CIC + ci) * 28 + s] = v;
        }
        for (int i = tid; i < 128 * CIC * 9; i += 256) {
            int c2 = i / (CIC * 9); int r = i % (CIC * 9);
            wl[c2 * WS + r] = wgt[((long)c2 * Cin + cs) * 9 + r];
        }
        __syncthreads();

        for (int ci = 0; ci < CIC; ++ci) {
            float xr[28];
            const float4* xp = (const float4*)&slab[(il * CIC + ci) * 28];
#pragma unroll
            for (int q = 0; q < 7; ++q) {
                float4 v = xp[q];
                xr[q*4+0]=v.x; xr[q*4+1]=v.y; xr[q*4+2]=v.z; xr[q*4+3]=v.w;
            }
            float wr[9];
#pragma unroll
            for (int k = 0; k < 9; ++k) wr[k] = wl[co * WS + ci * 9 + k];
#pragma unroll
            for (int oy = 0; oy < 3; ++oy)
#pragma unroll
                for (int ox = 0; ox < 3; ++ox) {
                    float a = acc[oy * 3 + ox];
#pragma unroll
                    for (int ky = 0; ky < 3; ++ky)
#pragma unroll
                        for (int kx = 0; kx < 3; ++kx)
                            a = fmaf(xr[(oy + ky) * 5 + ox + kx], wr[ky * 3 + kx], a);
                    acc[oy * 3 + ox] = a;
                }
        }
        __syncthreads();
    }
#pragma unroll
    for (int s = 0; s < 9; ++s)
        out[((long)(n0 + il) * 128 + co) * 9 + s] = lrelu01(acc[s]);
}

// ---------------- max over T --------------------------------------------------
__global__ void max_over_T(const float* __restrict__ in, float* __restrict__ out,
                           int Bn, int Tn, int F)
{
    long idx = (long)blockIdx.x * blockDim.x + threadIdx.x;
    if (idx >= (long)Bn * F) return;
    int b = (int)(idx / F), f = (int)(idx % F);
    float m = -1e30f;
    for (int t = 0; t < Tn; ++t)
        m = fmaxf(m, in[((long)(b * Tn + t)) * F + f]);
    out[idx] = m;
}

// ---------------- FC layer: wave-per-output ----------------------------------
__global__ void linear_wpo(const float* __restrict__ in, const float* __restrict__ w,
                           const float* __restrict__ bias, float* __restrict__ out,
                           int M, int Kd, int O, int ldo)
{
    long gid = (long)blockIdx.x * blockDim.x + threadIdx.x;
    long wid = gid >> 6;
    int lane = (int)(gid & 63);
    if (wid >= (long)M * O) return;
    int m = (int)(wid / O), o = (int)(wid % O);
    const float* ir = in + (long)m * Kd;
    const float* wr = w  + (long)o * Kd;
    float acc = 0.f;
    for (int k = lane; k < Kd; k += 64) acc = fmaf(ir[k], wr[k], acc);
#pragma unroll
    for (int off = 32; off > 0; off >>= 1) acc += __shfl_down(acc, off, 64);
    if (lane == 0) out[(long)m * ldo + o] = acc + bias[o];
}

// ---------------- ROI crop + bilinear resize ----------------------------------
__global__ void roi_crop(const float* __restrict__ x, const float* __restrict__ px,
                         float* __restrict__ crops)
{
    int idx = blockIdx.x * blockDim.x + threadIdx.x;
    const int total = kB * kT * kR * kRH * kRW;
    if (idx >= total) return;
    int j  = idx % kRW; int t2 = idx / kRW;
    int i  = t2 % kRH;  t2 /= kRH;
    int r  = t2 % kR;   int bt = t2 / kR;

    float cx = px[(bt * kR + r) * 2 + 0];
    float cy = px[(bt * kR + r) * 2 + 1];
    float x1 = floorf(fminf(fmaxf(cx - 7.f, 0.f), 63.f));
    float x2 = floorf(fminf(cx + 7.f, 64.f));
    float y1 = floorf(fminf(fmaxf(cy - 7.f, 0.f), 63.f));
    float y2 = floorf(fminf(cy + 7.f, 64.f));

    float sx = x1 + (j + 0.5f) * (x2 - x1) * (1.f / 14.f) - 0.5f;
    sx = fminf(fmaxf(sx, x1), x2 - 1.f);
    float sy = y1 + (i + 0.5f) * (y2 - y1) * (1.f / 14.f) - 0.5f;
    sy = fminf(fmaxf(sy, y1), y2 - 1.f);

    float ix0f = floorf(sx), iy0f = floorf(sy);
    float wx = sx - ix0f,    wy = sy - iy0f;
    int ix0 = (int)ix0f,     iy0 = (int)iy0f;
    int ix1 = (int)fminf(ix0f + 1.f, x2 - 1.f);
    int iy1 = (int)fminf(iy0f + 1.f, y2 - 1.f);

    const float* img = x + (long)bt * 64 * 64;
    float v00 = img[iy0 * 64 + ix0], v01 = img[iy0 * 64 + ix1];
    float v10 = img[iy1 * 64 + ix0], v11 = img[iy1 * 64 + ix1];
    float top = (1.f - wx) * v00 + wx * v01;
    float bot = (1.f - wx) * v10 + wx * v11;
    crops[idx] = (1.f - wy) * top + wy * bot;
}

// ---------------- tiny dense matmul ------------------------------------------
__global__ void matmul_small(const float* __restrict__ in, const float* __restrict__ w,
                             float* __restrict__ out, int rows, int Kd, int O)
{
    int idx = blockIdx.x * blockDim.x + threadIdx.x;
    if (idx >= rows * O) return;
    int row = idx / O, o = idx % O;
    float acc = 0.f;
    for (int k = 0; k < Kd; ++k) acc = fmaf(in[(long)row * Kd + k], w[k * O + o], acc);
    out[idx] = acc;
}

// ---------------- GAT attention scalars ---------------------------------------
__global__ void gat_scores(const float* __restrict__ h, const float* __restrict__ a1,
                           const float* __restrict__ a2, float* __restrict__ s1,
                           float* __restrict__ s2, int total, int D)
{
    int idx = blockIdx.x * blockDim.x + threadIdx.x;
    if (idx >= total) return;
    const float* hr = h + (long)idx * D;
    float acc1 = 0.f, acc2 = 0.f;
    for (int k = 0; k < D; ++k) {
        acc1 = fmaf(hr[k], a1[k], acc1);
        acc2 = fmaf(hr[k], a2[k], acc2);
    }
    s1[idx] = acc1; s2[idx] = acc2;
}

// ---------------- GAT masked-softmax aggregate --------------------------------
template <int D>
__global__ void gat_aggregate(const float* __restrict__ h, const float* __restrict__ s1,
                              const float* __restrict__ s2, float* __restrict__ out)
{
    int bi = blockIdx.x;
    int b = bi / kN, i = bi % kN;
    int j = threadIdx.x;
    __shared__ float red[256];
    __shared__ float wsh[256];

    float ej = -1e30f;
    if (j < kN) {
        int fri = i / kR, rki = i % kR;
        int frj = j / kR, rkj = j % kR;
        int df = fri - frj;
        bool adj = (fri == frj) || ((rki == rkj) && (df == 1 || df == -1));
        float v = s1[b * kN + i] + s2[b * kN + j];
        v = v > 0.f ? v : 0.2f * v;
        ej = adj ? v : -9.0e15f;
    }
    red[j] = ej; __syncthreads();
#pragma unroll
    for (int off = 128; off > 0; off >>= 1) {
        if (j < off) red[j] = fmaxf(red[j], red[j + off]);
        __syncthreads();
    }
    float mx = red[0]; __syncthreads();

    float ex = (j < kN) ? expf(ej - mx) : 0.f;
    red[j] = ex; __syncthreads();
#pragma unroll
    for (int off = 128; off > 0; off >>= 1) {
        if (j < off) red[j] += red[j + off];
        __syncthreads();
    }
    float sum = red[0]; __syncthreads();

    wsh[j] = ex / sum; __syncthreads();

    if (j < D) {
        float acc = 0.f;
        for (int jj = 0; jj < kN; ++jj)
            acc = fmaf(wsh[jj], h[((long)b * kN + jj) * D + j], acc);
        out[((long)b * kN + i) * D + j] = acc;
    }
}

// ---------------- elu + log_softmax (last dim 16) -----------------------------
__global__ void elu_logsoftmax(const float* __restrict__ in, float* __restrict__ out,
                               int rows)
{
    int r = blockIdx.x * blockDim.x + threadIdx.x;
    if (r >= rows) return;
    float v[16];
    float mx = -1e30f;
#pragma unroll
    for (int k = 0; k < 16; ++k) {
        float xv = in[(long)r * 16 + k];
        xv = xv > 0.f ? xv : expm1f(xv);
        v[k] = xv; mx = fmaxf(mx, xv);
    }
    float s = 0.f;
#pragma unroll
    for (int k = 0; k < 16; ++k) s += expf(v[k] - mx);
    float ls = logf(s) + mx;
#pragma unroll
    for (int k = 0; k < 16; ++k) out[(long)r * 16 + k] = v[k] - ls;
}

// ---------------- mean over nodes of concat(l_fc, gat_fc) ---------------------
__global__ void lcat_mean(const float* __restrict__ lfc, const float* __restrict__ gatfc,
                          float* __restrict__ fcbuf)
{
    int idx = blockIdx.x * blockDim.x + threadIdx.x;
    if (idx >= kB * 272) return;
    int b = idx / 272, c = idx % 272;
    float s = 0.f;
    if (c < 256) {
        for (int n2 = 0; n2 < kN; ++n2) s += lfc[((long)b * kN + n2) * 256 + c];
    } else {
        int cc = c - 256;
        for (int n2 = 0; n2 < kN; ++n2) s += gatfc[((long)b * kN + n2) * 16 + cc];
    }
    fcbuf[b * 528 + 256 + c] = s * (1.f / kN);
}

// ---------------- final pyramid ----------------------------------------------
__global__ void final_feats(const float* __restrict__ fcbuf, float* __restrict__ out)
{
    int idx = blockIdx.x * blockDim.x + threadIdx.x;
    if (idx >= kB * 1023) return;
    int b = idx / 1023, m = idx % 1023;
    int nb, seg, off;
    if      (m < 528) { nb = 1;  seg = 528; off = 0;   }
    else if (m < 792) { nb = 2;  seg = 264; off = 528; }
    else if (m < 924) { nb = 4;  seg = 132; off = 792; }
    else if (m < 990) { nb = 8;  seg = 66;  off = 924; }
    else              { nb = 16; seg = 33;  off = 990; }
    int mm = m - off;
    float s = 0.f, mx = -1e30f;
    for (int k2 = 0; k2 < nb; ++k2) {
        float v = fcbuf[b * 528 + k2 * seg + mm];
        s += v; mx = fmaxf(mx, v);
    }
    out[(long)b * 1023 + m] = s / nb + mx;
}

// ---------------------------------------------------------------------------
extern "C" void kernel_launch(void* const* d_in, const int* in_sizes, int n_in,
                              void* d_out, int out_size, void* d_ws, size_t ws_size,
                              hipStream_t stream)
{
    const float* x       = (const float*)d_in[0];
    const float* px      = (const float*)d_in[1];
    const float* cw1     = (const float*)d_in[2];
    const float* cw2     = (const float*)d_in[3];
    const float* cw3     = (const float*)d_in[4];
    const float* cw4     = (const float*)d_in[5];
    const float* cw5     = (const float*)d_in[6];
    const float* cw6     = (const float*)d_in[7];
    const float* fc_g_w  = (const float*)d_in[8];
    const float* fc_g_b  = (const float*)d_in[9];
    const float* fc_l_w  = (const float*)d_in[10];
    const float* fc_l_b  = (const float*)d_in[11];
    const float* gat1_W  = (const float*)d_in[12];
    const float* gat1_a1 = (const float*)d_in[13];
    const float* gat1_a2 = (const float*)d_in[14];
    const float* gat2_W  = (const float*)d_in[15];
    const float* gat2_a1 = (const float*)d_in[16];
    const float* gat2_a2 = (const float*)d_in[17];

    float* ws    = (float*)d_ws;
    float* A     = ws;
    float* Bb    = A + 31457280;
    float* crops = Bb + 7864320;
    float* gmaxb = crops + 376320;
    float* lfc   = gmaxb + 262144;
    float* h1    = lfc + 491520;
    float* s1    = h1 + 15360;
    float* s2    = s1 + 1920;
    float* o1    = s2 + 1920;
    float* h2    = o1 + 15360;
    float* s1b   = h2 + 30720;
    float* s2b   = s1b + 1920;
    float* o2    = s2b + 1920;
    float* gatfc = o2 + 30720;
    float* fcbuf = gatfc + 30720;

    // packed bf16 weights alias the crops region (dead until roi_crop, which
    // runs after the global path completes). 285,696 shorts = 571 KB < 1.5 MB.
    short* bp2 = (short*)crops;
    short* bp3 = bp2 + 9216;
    short* bp4 = bp3 + 18432;
    short* bp5 = bp4 + 36864;
    short* bp6 = bp5 + 73728;

    auto cdiv = [](long a, long b) { return (int)((a + b - 1) / b); };
    const int TB = 256;

    // ---------------- weight repack (bf16 B-fragments) ----------------
    repack_w< 32,  32><<<cdiv( 9216 / 8, TB), TB, 0, stream>>>(cw2, bp2);
    repack_w< 32,  64><<<cdiv(18432 / 8, TB), TB, 0, stream>>>(cw3, bp3);
    repack_w< 64,  64><<<cdiv(36864 / 8, TB), TB, 0, stream>>>(cw4, bp4);
    repack_w< 64, 128><<<cdiv(73728 / 8, TB), TB, 0, stream>>>(cw5, bp5);
    repack_w<128, 128><<<cdiv(147456 / 8, TB), TB, 0, stream>>>(cw6, bp6);

    // ---------------- global path ----------------
    conv_tile<5, false, 1, 32, 64, 64, 32, 4, 2, 1><<<3840, 256, 0, stream>>>(x, cw1, A);
    //          Cin  Cout  H   W  POOL NSPLIT      blocks = N * (H/16)*(W/16) * NSPLIT
    conv_mfma<  32,  32, 64, 64, true,  1><<<3840, 256, 0, stream>>>(A,  bp2, Bb);
    conv_mfma<  32,  64, 32, 32, false, 1><<< 960, 256, 0, stream>>>(Bb, bp3, A);
    conv_mfma<  64,  64, 32, 32, true,  1><<< 960, 256, 0, stream>>>(A,  bp4, Bb);
    conv_mfma<  64, 128, 16, 16, false, 2><<< 480, 256, 0, stream>>>(Bb, bp5, A);
    conv_mfma< 128, 128, 16, 16, false, 2><<< 480, 256, 0, stream>>>(A,  bp6, Bb);
    max_over_T<<<cdiv(8L * 32768, TB), TB, 0, stream>>>(Bb, gmaxb, 8, 30, 32768);
    linear_wpo<<<cdiv(8L * 256 * 64, TB), TB, 0, stream>>>(gmaxb, fc_g_w, fc_g_b, fcbuf, 8, 32768, 256, 528);

    // ---------------- local path ----------------
    roi_crop<<<cdiv(1920L * 196, TB), TB, 0, stream>>>(x, px, crops);
    conv_tile<5, false,  1,  32, 14, 14, 16, 4, 2,  1><<<1920, 256, 0, stream>>>(crops, cw1, A);
    conv_tile<3, true,  32,  32, 14, 14, 16, 4, 2, 16><<<1920, 256, 0, stream>>>(A,  cw2, Bb);
    conv_tile<3, false, 32,  64,  7,  7,  8, 2, 4,  8><<<1920, 256, 0, stream>>>(Bb, cw3, A);
    conv_tile<3, true,  64,  64,  7,  7,  8, 2, 4,  8><<<1920, 256, 0, stream>>>(A,  cw4, Bb);
    conv_tiny<64 ><<<960, 256, 0, stream>>>(Bb, cw5, A);
    conv_tiny<128><<<960, 256, 0, stream>>>(A,  cw6, Bb);
    linear_wpo<<<cdiv(1920L * 256 * 64, TB), TB, 0, stream>>>(Bb, fc_l_w, fc_l_b, lfc, 1920, 1152, 256, 256);

    // ---------------- GAT ----------------
    matmul_small<<<cdiv(1920L * 8, TB), TB, 0, stream>>>(lfc, gat1_W, h1, kB * kN, 256, 8);
    gat_scores<<<cdiv(1920L, TB), TB, 0, stream>>>(h1, gat1_a1, gat1_a2, s1, s2, kB * kN, 8);
    gat_aggregate<8><<<kB * kN, TB, 0, stream>>>(h1, s1, s2, o1);
    matmul_small<<<cdiv(1920L * 16, TB), TB, 0, stream>>>(o1, gat2_W, h2, kB * kN, 8, 16);
    gat_scores<<<cdiv(1920L, TB), TB, 0, stream>>>(h2, gat2_a1, gat2_a2, s1b, s2b, kB * kN, 16);
    gat_aggregate<16><<<kB * kN, TB, 0, stream>>>(h2, s1b, s2b, o2);
    elu_logsoftmax<<<cdiv(1920L, TB), TB, 0, stream>>>(o2, gatfc, kB * kN);

    // ---------------- head ----------------
    lcat_mean<<<cdiv(8L * 272, TB), TB, 0, stream>>>(lfc, gatfc, fcbuf);
    final_feats<<<cdiv(8L * 1023, TB), TB, 0, stream>>>(fcbuf, (float*)d_out);
}

// Round 4
// 956.289 us; speedup vs baseline: 27.3897x; 2.0011x over previous
//
#include <hip/hip_runtime.h>
#include <hip/hip_bf16.h>

// ---------------------------------------------------------------------------
// RGPNet forward. Round 4: MFMA local-path convs + MFMA fc_l + split-K fc_g.
// ---------------------------------------------------------------------------

constexpr int kB = 8, kT = 30, kR = 8;
constexpr int kN = kT * kR;          // 240 nodes per batch
constexpr int kRH = 14, kRW = 14;

static __device__ __forceinline__ float lrelu01(float v) {
    return v > 0.f ? v : 0.01f * v;
}

typedef __attribute__((ext_vector_type(8))) short bf16x8;
typedef __attribute__((ext_vector_type(4))) float f32x4;

static __device__ __forceinline__ short f2bf(float v) {
    __hip_bfloat16 h = __float2bfloat16(v);
    return *reinterpret_cast<short*>(&h);
}

// ---------------------------------------------------------------------------
// Conv-weight repack: OIHW fp32 -> per-lane B-fragment bf16 layout.
// bp[(((cs*9+kykx)*NFTOT + nf)*64 + lane)*8 + j]
//   = W[nf*16+(lane&15)][cs*32+(lane>>4)*8+j][ky][kx]
// ---------------------------------------------------------------------------
template <int Cin, int Cout>
__global__ void repack_w(const float* __restrict__ w, short* __restrict__ bp)
{
    constexpr int NFTOT = Cout / 16, CS = Cin / 32;
    int t = blockIdx.x * blockDim.x + threadIdx.x;
    if (t >= CS * 9 * NFTOT * 64) return;
    int lane = t & 63, rest = t >> 6;
    int nf = rest % NFTOT; rest /= NFTOT;
    int kykx = rest % 9; int cs = rest / 9;
    int co  = nf * 16 + (lane & 15);
    int cib = cs * 32 + (lane >> 4) * 8;
#pragma unroll
    for (int j = 0; j < 8; ++j) {
        float v = w[((long)co * Cin + cib + j) * 9 + kykx];
        bp[(long)t * 8 + j] = f2bf(v);
    }
}

// Dense-weight repack for fc_l: w [O=256][KD] row-major fp32 ->
// wp[((kc*16 + nf)*64 + lane)*8 + j] = w[nf*16+(lane&15)][kc*32+(lane>>4)*8+j]
template <int KD, int O>
__global__ void repack_dense(const float* __restrict__ w, short* __restrict__ wp)
{
    constexpr int KC = KD / 32, NF = O / 16;
    int t = blockIdx.x * blockDim.x + threadIdx.x;
    if (t >= KC * NF * 64) return;
    int lane = t & 63, rest = t >> 6;
    int nf = rest % NF; int kc = rest / NF;
    int co = nf * 16 + (lane & 15);
    int k  = kc * 32 + (lane >> 4) * 8;
#pragma unroll
    for (int j = 0; j < 8; ++j)
        wp[(long)t * 8 + j] = f2bf(w[(long)co * KD + k + j]);
}

// ---------------------------------------------------------------------------
// Global-path MFMA implicit-GEMM 3x3 conv (unchanged from round 3).
// ---------------------------------------------------------------------------
template <int Cin, int Cout, int H, int W, bool POOL, int NSPLIT>
__global__ __launch_bounds__(256) void conv_mfma(
    const float* __restrict__ in, const short* __restrict__ bp,
    float* __restrict__ out)
{
    constexpr int NFTOT = Cout / 16;
    constexpr int NF    = NFTOT / NSPLIT;
    constexpr int CS    = Cin / 32;
    constexpr int TX    = W / 16, TY = H / 16;
    constexpr int CP    = 40;
    constexpr int Ho    = POOL ? H / 2 : H, Wo = POOL ? W / 2 : W;

    __shared__ short slab[18 * 18 * CP];

    int bid = blockIdx.x;
    const int split = bid % NSPLIT; bid /= NSPLIT;
    const int txt = bid % TX; bid /= TX;
    const int tyt = bid % TY; bid /= TY;
    const int n   = bid;
    const int x0 = txt * 16, y0 = tyt * 16;
    const int nf0 = split * NF;

    const int tid = threadIdx.x;
    const int lane = tid & 63, wav = tid >> 6;
    const int mrow0 = wav * 4;
    const int lx = lane & 15, lg = lane >> 4;

    f32x4 acc[4][NF];
#pragma unroll
    for (int r = 0; r < 4; ++r)
#pragma unroll
        for (int f = 0; f < NF; ++f) acc[r][f] = (f32x4)0.f;

    for (int cs = 0; cs < CS; ++cs) {
        for (int i = tid; i < 18 * 18 * 32; i += 256) {
            int ci = i / 324, r2 = i % 324;
            int yy = r2 / 18, xx = r2 % 18;
            int gy = y0 - 1 + yy, gx = x0 - 1 + xx;
            float v = 0.f;
            if ((unsigned)gy < (unsigned)H && (unsigned)gx < (unsigned)W)
                v = in[(((long)n * Cin + cs * 32 + ci) * H + gy) * W + gx];
            slab[(yy * 18 + xx) * CP + ci] = f2bf(v);
        }
        __syncthreads();

#pragma unroll
        for (int ky = 0; ky < 3; ++ky)
#pragma unroll
        for (int kx = 0; kx < 3; ++kx) {
            bf16x8 a[4];
#pragma unroll
            for (int r = 0; r < 4; ++r)
                a[r] = *(const bf16x8*)&slab[((mrow0 + r + ky) * 18 + lx + kx) * CP + lg * 8];
            const int kykx = ky * 3 + kx;
#pragma unroll
            for (int f = 0; f < NF; ++f) {
                bf16x8 b = *(const bf16x8*)&bp[(((long)(cs * 9 + kykx) * NFTOT + nf0 + f) * 64 + lane) * 8];
#pragma unroll
                for (int r = 0; r < 4; ++r)
                    acc[r][f] = __builtin_amdgcn_mfma_f32_16x16x32_bf16(a[r], b, acc[r][f], 0, 0, 0);
            }
        }
        __syncthreads();
    }

    if constexpr (!POOL) {
#pragma unroll
        for (int f = 0; f < NF; ++f) {
            int co = (nf0 + f) * 16 + lx;
#pragma unroll
            for (int r = 0; r < 4; ++r) {
                int y = y0 + mrow0 + r;
                float4 v;
                v.x = lrelu01(acc[r][f][0]); v.y = lrelu01(acc[r][f][1]);
                v.z = lrelu01(acc[r][f][2]); v.w = lrelu01(acc[r][f][3]);
                *(float4*)&out[(((long)n * Cout + co) * H + y) * W + x0 + lg * 4] = v;
            }
        }
    } else {
#pragma unroll
        for (int f = 0; f < NF; ++f) {
            int co = (nf0 + f) * 16 + lx;
#pragma unroll
            for (int q = 0; q < 2; ++q) {
                int yp = (y0 >> 1) + wav * 2 + q;
                float m0 = fmaxf(fmaxf(lrelu01(acc[2*q][f][0]), lrelu01(acc[2*q][f][1])),
                                 fmaxf(lrelu01(acc[2*q+1][f][0]), lrelu01(acc[2*q+1][f][1])));
                float m1 = fmaxf(fmaxf(lrelu01(acc[2*q][f][2]), lrelu01(acc[2*q][f][3])),
                                 fmaxf(lrelu01(acc[2*q+1][f][2]), lrelu01(acc[2*q+1][f][3])));
                float2 v; v.x = m0; v.y = m1;
                *(float2*)&out[(((long)n * Cout + co) * Ho + yp) * Wo + (x0 >> 1) + lg * 2] = v;
            }
        }
    }
}

// ---------------------------------------------------------------------------
// Local conv2: Cin=32, Cout=32, 14x14 -> pool -> 7x7. One image per block.
// M = x (16-wide, x<14 valid), y covered by wave*4+r. Slab 16x16 incl. halo.
// ---------------------------------------------------------------------------
__global__ __launch_bounds__(256) void conv2l_mfma(
    const float* __restrict__ in, const short* __restrict__ bp,
    float* __restrict__ out)
{
    constexpr int CP = 40;
    __shared__ short slab[16 * 16 * CP];
    const int n = blockIdx.x;
    const int tid = threadIdx.x;
    const int lane = tid & 63, wav = tid >> 6;
    const int lx = lane & 15, lg = lane >> 4;

    // stage: slab[yy][xx] = img[y=yy-1][x=xx-1], 32 ci
    for (int i = tid; i < 16 * 16 * 32; i += 256) {
        int ci = i >> 8, r2 = i & 255;
        int yy = r2 >> 4, xx = r2 & 15;
        int gy = yy - 1, gx = xx - 1;
        float v = 0.f;
        if ((unsigned)gy < 14u && (unsigned)gx < 14u)
            v = in[(((long)n * 32 + ci) * 14 + gy) * 14 + gx];
        slab[(yy * 16 + xx) * CP + ci] = f2bf(v);
    }
    __syncthreads();

    f32x4 acc[4][2];
#pragma unroll
    for (int r = 0; r < 4; ++r)
#pragma unroll
        for (int f = 0; f < 2; ++f) acc[r][f] = (f32x4)0.f;

#pragma unroll
    for (int ky = 0; ky < 3; ++ky)
#pragma unroll
    for (int kx = 0; kx < 3; ++kx) {
        bf16x8 a[4];
        int xcl = min(lx + kx, 15);
#pragma unroll
        for (int r = 0; r < 4; ++r) {
            int ycl = min(wav * 4 + r + ky, 15);
            a[r] = *(const bf16x8*)&slab[(ycl * 16 + xcl) * CP + lg * 8];
        }
        const int kykx = ky * 3 + kx;
#pragma unroll
        for (int f = 0; f < 2; ++f) {
            bf16x8 b = *(const bf16x8*)&bp[(((long)kykx * 2 + f) * 64 + lane) * 8];
#pragma unroll
            for (int r = 0; r < 4; ++r)
                acc[r][f] = __builtin_amdgcn_mfma_f32_16x16x32_bf16(a[r], b, acc[r][f], 0, 0, 0);
        }
    }

    // pool epilogue: x = lg*4+reg, y = wav*4+r
#pragma unroll
    for (int f = 0; f < 2; ++f) {
        int co = f * 16 + lx;
#pragma unroll
        for (int q = 0; q < 2; ++q) {
            int yp = wav * 2 + q;
            if (yp >= 7) continue;
            float m0 = fmaxf(fmaxf(lrelu01(acc[2*q][f][0]), lrelu01(acc[2*q][f][1])),
                             fmaxf(lrelu01(acc[2*q+1][f][0]), lrelu01(acc[2*q+1][f][1])));
            float m1 = fmaxf(fmaxf(lrelu01(acc[2*q][f][2]), lrelu01(acc[2*q][f][3])),
                             fmaxf(lrelu01(acc[2*q+1][f][2]), lrelu01(acc[2*q+1][f][3])));
            int xp0 = lg * 2;
            out[(((long)n * 32 + co) * 7 + yp) * 7 + xp0] = m0;
            if (xp0 + 1 < 7)
                out[(((long)n * 32 + co) * 7 + yp) * 7 + xp0 + 1] = m1;
        }
    }
}

// ---------------------------------------------------------------------------
// Local conv3: Cin=32, Cout=64, 7x7, no pool. Flat-M over G=4 images (M=196).
// ---------------------------------------------------------------------------
__global__ __launch_bounds__(256) void conv3l_mfma(
    const float* __restrict__ in, const short* __restrict__ bp,
    float* __restrict__ out)
{
    constexpr int CP = 40;
    __shared__ short slab[4 * 81 * CP];   // 25.9 KB
    const int n0 = blockIdx.x * 4;
    const int tid = threadIdx.x;
    const int lane = tid & 63, wav = tid >> 6;
    const int lx = lane & 15, lg = lane >> 4;

    for (int i = tid; i < 4 * 81 * 32; i += 256) {
        int g = i / 2592, r2 = i % 2592;
        int ci = r2 / 81, s = r2 % 81;
        int gy = s / 9 - 1, gx = s % 9 - 1;
        float v = 0.f;
        if ((unsigned)gy < 7u && (unsigned)gx < 7u)
            v = in[(((long)(n0 + g) * 32 + ci) * 7 + gy) * 7 + gx];
        slab[((g * 81) + s) * CP + ci] = f2bf(v);
    }
    __syncthreads();

    // per-lane A base per tile
    int abase[4];
#pragma unroll
    for (int i = 0; i < 4; ++i) {
        int mt = wav + i * 4;
        int m = min(mt * 16 + lx, 195);
        int g = m / 49, s = m % 49;
        int y = s / 7, x = s % 7;
        abase[i] = (g * 81 + y * 9 + x) * CP + lg * 8;
    }

    f32x4 acc[4][4];
#pragma unroll
    for (int i = 0; i < 4; ++i)
#pragma unroll
        for (int f = 0; f < 4; ++f) acc[i][f] = (f32x4)0.f;

#pragma unroll
    for (int ky = 0; ky < 3; ++ky)
#pragma unroll
    for (int kx = 0; kx < 3; ++kx) {
        const int koff = (ky * 9 + kx) * CP;
        bf16x8 a[4];
#pragma unroll
        for (int i = 0; i < 4; ++i)
            a[i] = *(const bf16x8*)&slab[abase[i] + koff];
        const int kykx = ky * 3 + kx;
#pragma unroll
        for (int f = 0; f < 4; ++f) {
            bf16x8 b = *(const bf16x8*)&bp[(((long)kykx * 4 + f) * 64 + lane) * 8];
#pragma unroll
            for (int i = 0; i < 4; ++i)
                acc[i][f] = __builtin_amdgcn_mfma_f32_16x16x32_bf16(a[i], b, acc[i][f], 0, 0, 0);
        }
    }

#pragma unroll
    for (int i = 0; i < 4; ++i) {
        int mt = wav + i * 4;
        if (mt >= 13) continue;
#pragma unroll
        for (int f = 0; f < 4; ++f) {
            int co = f * 16 + lx;
#pragma unroll
            for (int reg = 0; reg < 4; ++reg) {
                int m = mt * 16 + lg * 4 + reg;
                if (m >= 196) continue;
                int g = m / 49, s = m % 49;
                out[((long)(n0 + g) * 64 + co) * 49 + s] = lrelu01(acc[i][f][reg]);
            }
        }
    }
}

// ---------------------------------------------------------------------------
// Local conv4: Cin=64, Cout=64, 7x7 -> pool -> 3x3. Two images packed in M
// (lanes 0-7 img0, 8-15 img1). Waves: (wav&1)=y-half, (wav>>1)=nf-half.
// ---------------------------------------------------------------------------
__global__ __launch_bounds__(256) void conv4l_mfma(
    const float* __restrict__ in, const short* __restrict__ bp,
    float* __restrict__ out)
{
    constexpr int CP = 40;
    __shared__ short slab[2 * 81 * CP];   // 13 KB
    const int n0 = blockIdx.x * 2;
    const int tid = threadIdx.x;
    const int lane = tid & 63, wav = tid >> 6;
    const int lx = lane & 15, lg = lane >> 4;
    const int yh = wav & 1, nf0 = (wav >> 1) * 2;

    f32x4 acc[4][2];
#pragma unroll
    for (int r = 0; r < 4; ++r)
#pragma unroll
        for (int f = 0; f < 2; ++f) acc[r][f] = (f32x4)0.f;

    const int imgA = lx >> 3, xlA = lx & 7;

    for (int cs = 0; cs < 2; ++cs) {
        for (int i = tid; i < 2 * 81 * 32; i += 256) {
            int g = i / 2592, r2 = i % 2592;
            int ci = r2 / 81, s = r2 % 81;
            int gy = s / 9 - 1, gx = s % 9 - 1;
            float v = 0.f;
            if ((unsigned)gy < 7u && (unsigned)gx < 7u)
                v = in[(((long)(n0 + g) * 64 + cs * 32 + ci) * 7 + gy) * 7 + gx];
            slab[((g * 81) + s) * CP + ci] = f2bf(v);
        }
        __syncthreads();

#pragma unroll
        for (int ky = 0; ky < 3; ++ky)
#pragma unroll
        for (int kx = 0; kx < 3; ++kx) {
            int xcl = min(xlA + kx, 8);
            bf16x8 a[4];
#pragma unroll
            for (int r = 0; r < 4; ++r) {
                int ycl = min(yh * 4 + r + ky, 8);
                a[r] = *(const bf16x8*)&slab[(imgA * 81 + ycl * 9 + xcl) * CP + lg * 8];
            }
            const int kykx = ky * 3 + kx;
#pragma unroll
            for (int f = 0; f < 2; ++f) {
                bf16x8 b = *(const bf16x8*)&bp[(((long)(cs * 9 + kykx) * 4 + nf0 + f) * 64 + lane) * 8];
#pragma unroll
                for (int r = 0; r < 4; ++r)
                    acc[r][f] = __builtin_amdgcn_mfma_f32_16x16x32_bf16(a[r], b, acc[r][f], 0, 0, 0);
            }
        }
        __syncthreads();
    }

    // pool epilogue: M row = lg*4+reg -> img = row>>3, xl = row&7
    const int imgC = (lg * 4) >> 3;            // rows within a lane share img
#pragma unroll
    for (int f = 0; f < 2; ++f) {
        int co = (nf0 + f) * 16 + lx;
#pragma unroll
        for (int qy = 0; qy < 2; ++qy) {
            int yp = yh * 2 + qy;
            if (yp >= 3) continue;
#pragma unroll
            for (int q = 0; q < 2; ++q) {
                int xp = (lg & 1) * 2 + q;
                if (xp >= 3) continue;
                float m = fmaxf(fmaxf(lrelu01(acc[2*qy][f][2*q]),   lrelu01(acc[2*qy][f][2*q+1])),
                                fmaxf(lrelu01(acc[2*qy+1][f][2*q]), lrelu01(acc[2*qy+1][f][2*q+1])));
                out[((long)(n0 + imgC) * 64 + co) * 9 + yp * 3 + xp] = m;
            }
        }
    }
}

// ---------------------------------------------------------------------------
// Local conv5/6: Cin={64,128}, Cout=128, 3x3, no pool. Flat-M over G=16
// images (M=144 exact, 9 tiles). NSPLIT=2 over co.
// ---------------------------------------------------------------------------
template <int Cin>
__global__ __launch_bounds__(256) void conv56l_mfma(
    const float* __restrict__ in, const short* __restrict__ bp,
    float* __restrict__ out)
{
    constexpr int CP = 40, CS = Cin / 32;
    __shared__ short slab[16 * 25 * CP];   // 32 KB
    int bid = blockIdx.x;
    const int split = bid & 1;
    const int n0 = (bid >> 1) * 16;
    const int nf0 = split * 4;
    const int tid = threadIdx.x;
    const int lane = tid & 63, wav = tid >> 6;
    const int lx = lane & 15, lg = lane >> 4;

    int abase[3];
#pragma unroll
    for (int i = 0; i < 3; ++i) {
        int mt = wav + i * 4;
        int m = min(mt, 8) * 16 + lx;
        int g = m / 9, s = m % 9;
        int y = s / 3, x = s % 3;
        abase[i] = (g * 25 + y * 5 + x) * CP + lg * 8;
    }

    f32x4 acc[3][4];
#pragma unroll
    for (int i = 0; i < 3; ++i)
#pragma unroll
        for (int f = 0; f < 4; ++f) acc[i][f] = (f32x4)0.f;

    for (int cs = 0; cs < CS; ++cs) {
        for (int i = tid; i < 16 * 25 * 32; i += 256) {
            int g = i / 800, r2 = i % 800;
            int ci = r2 / 25, s = r2 % 25;
            int gy = s / 5 - 1, gx = s % 5 - 1;
            float v = 0.f;
            if ((unsigned)gy < 3u && (unsigned)gx < 3u)
                v = in[(((long)(n0 + g) * Cin + cs * 32 + ci) * 3 + gy) * 3 + gx];
            slab[(g * 25 + s) * CP + ci] = f2bf(v);
        }
        __syncthreads();

#pragma unroll
        for (int ky = 0; ky < 3; ++ky)
#pragma unroll
        for (int kx = 0; kx < 3; ++kx) {
            const int koff = (ky * 5 + kx) * CP;
            bf16x8 a[3];
#pragma unroll
            for (int i = 0; i < 3; ++i)
                a[i] = *(const bf16x8*)&slab[abase[i] + koff];
            const int kykx = ky * 3 + kx;
#pragma unroll
            for (int f = 0; f < 4; ++f) {
                bf16x8 b = *(const bf16x8*)&bp[(((long)(cs * 9 + kykx) * 8 + nf0 + f) * 64 + lane) * 8];
#pragma unroll
                for (int i = 0; i < 3; ++i)
                    acc[i][f] = __builtin_amdgcn_mfma_f32_16x16x32_bf16(a[i], b, acc[i][f], 0, 0, 0);
            }
        }
        __syncthreads();
    }

#pragma unroll
    for (int i = 0; i < 3; ++i) {
        int mt = wav + i * 4;
        if (mt >= 9) continue;
#pragma unroll
        for (int f = 0; f < 4; ++f) {
            int co = (nf0 + f) * 16 + lx;
#pragma unroll
            for (int reg = 0; reg < 4; ++reg) {
                int m = mt * 16 + lg * 4 + reg;
                int g = m / 9, s = m % 9;
                out[((long)(n0 + g) * 128 + co) * 9 + s] = lrelu01(acc[i][f][reg]);
            }
        }
    }
}

// ---------------------------------------------------------------------------
// fc_l as MFMA GEMM: C[1920][256] = A[1920][1152] @ W^T + b. Block = 16 rows.
// ---------------------------------------------------------------------------
__global__ __launch_bounds__(256) void linear_l_mfma(
    const float* __restrict__ in, const short* __restrict__ wp,
    const float* __restrict__ bias, float* __restrict__ out)
{
    constexpr int KD = 1152, LDK = KD + 8;   // short stride, 16B-aligned
    __shared__ short slab[16 * LDK];         // 37.1 KB
    const int m0 = blockIdx.x * 16;
    const int tid = threadIdx.x;
    const int lane = tid & 63, wav = tid >> 6;
    const int lx = lane & 15, lg = lane >> 4;

    for (int i = tid; i < 16 * (KD / 4); i += 256) {
        int r = i / (KD / 4), c4 = i % (KD / 4);
        float4 v = *(const float4*)&in[(long)(m0 + r) * KD + c4 * 4];
        short4 s4;
        s4.x = f2bf(v.x); s4.y = f2bf(v.y); s4.z = f2bf(v.z); s4.w = f2bf(v.w);
        *(short4*)&slab[r * LDK + c4 * 4] = s4;
    }
    __syncthreads();

    f32x4 acc[4];
#pragma unroll
    for (int f = 0; f < 4; ++f) acc[f] = (f32x4)0.f;

    for (int kc = 0; kc < KD / 32; ++kc) {
        bf16x8 a = *(const bf16x8*)&slab[lx * LDK + kc * 32 + lg * 8];
#pragma unroll
        for (int f = 0; f < 4; ++f) {
            int nf = wav * 4 + f;
            bf16x8 b = *(const bf16x8*)&wp[(((long)kc * 16 + nf) * 64 + lane) * 8];
            acc[f] = __builtin_amdgcn_mfma_f32_16x16x32_bf16(a, b, acc[f], 0, 0, 0);
        }
    }

#pragma unroll
    for (int f = 0; f < 4; ++f) {
        int co = (wav * 4 + f) * 16 + lx;
        float bv = bias[co];
#pragma unroll
        for (int reg = 0; reg < 4; ++reg) {
            int m = m0 + lg * 4 + reg;
            out[(long)m * 256 + co] = acc[f][reg] + bv;
        }
    }
}

// ---------------------------------------------------------------------------
// fc_g: split-K, weights read once, all 8 batch rows per wave, atomicAdd.
// ---------------------------------------------------------------------------
__global__ void init_fcg(const float* __restrict__ bias, float* __restrict__ fcbuf)
{
    int idx = blockIdx.x * blockDim.x + threadIdx.x;
    if (idx >= 8 * 256) return;
    fcbuf[(idx >> 8) * 528 + (idx & 255)] = bias[idx & 255];
}

__global__ __launch_bounds__(256) void fcg_partial(
    const float* __restrict__ in, const float* __restrict__ w,
    float* __restrict__ fcbuf)
{
    const int gid = blockIdx.x * 256 + threadIdx.x;
    const int wid = gid >> 6, lane = gid & 63;
    const int o = wid >> 4, kc = wid & 15;        // 256 outputs x 16 k-chunks
    const int k0 = kc * 2048;

    float acc[8];
#pragma unroll
    for (int m = 0; m < 8; ++m) acc[m] = 0.f;

    for (int it = 0; it < 8; ++it) {
        int k = k0 + it * 256 + lane * 4;
        float4 wv = *(const float4*)&w[(long)o * 32768 + k];
#pragma unroll
        for (int m = 0; m < 8; ++m) {
            float4 xv = *(const float4*)&in[(long)m * 32768 + k];
            acc[m] = fmaf(xv.x, wv.x, acc[m]);
            acc[m] = fmaf(xv.y, wv.y, acc[m]);
            acc[m] = fmaf(xv.z, wv.z, acc[m]);
            acc[m] = fmaf(xv.w, wv.w, acc[m]);
        }
    }
#pragma unroll
    for (int off = 32; off > 0; off >>= 1)
#pragma unroll
        for (int m = 0; m < 8; ++m)
            acc[m] += __shfl_down(acc[m], off, 64);
    if (lane == 0) {
#pragma unroll
        for (int m = 0; m < 8; ++m)
            atomicAdd(&fcbuf[m * 528 + o], acc[m]);
    }
}

// ---------------------------------------------------------------------------
// Tiled fp32 conv (conv1 global + local: Cin=1, K=5).
// ---------------------------------------------------------------------------
template <int K, bool POOL, int Cin, int Cout, int H, int W,
          int TILE, int PT, int CO_T, int CIC>
__global__ __launch_bounds__(256) void conv_tile(
    const float* __restrict__ in, const float* __restrict__ wgt,
    float* __restrict__ out)
{
    constexpr int P   = K / 2;
    constexpr int NT  = (H + TILE - 1) / TILE;
    constexpr int SP  = TILE / PT;
    constexpr int SPT = SP * SP;
    constexpr int COS = 256 / SPT;
    constexpr int COB = COS * CO_T;
    constexpr int CG  = Cout / COB;
    constexpr int SW  = TILE + 2 * P;
    constexpr int RS  = (SW + 3) & ~3;
    constexpr int KK  = K * K;
    constexpr int WS  = CIC * KK + 1;
    constexpr int XW  = PT + 2 * P;

    __shared__ __align__(16) float slab[CIC * SW * RS];
    __shared__ __align__(16) float wl[COB * WS];

    int bid = blockIdx.x;
    const int cg = bid % CG; bid /= CG;
    const int tx = bid % NT; bid /= NT;
    const int ty = bid % NT;
    const int n  = bid / NT;
    const int x0 = tx * TILE, y0 = ty * TILE;
    const int co0 = cg * COB;

    const int tid  = threadIdx.x;
    const int sidx = tid % SPT, ssub = tid / SPT;
    const int px0  = (sidx % SP) * PT, py0 = (sidx / SP) * PT;

    float acc[CO_T][PT][PT];
#pragma unroll
    for (int c = 0; c < CO_T; ++c)
#pragma unroll
        for (int a = 0; a < PT; ++a)
#pragma unroll
            for (int b2 = 0; b2 < PT; ++b2) acc[c][a][b2] = 0.f;

    for (int cs = 0; cs < Cin; cs += CIC) {
        for (int i = tid; i < CIC * SW * SW; i += 256) {
            int ci = i / (SW * SW); int r = i % (SW * SW);
            int yy = r / SW, xx = r % SW;
            int gy = y0 + yy - P, gx = x0 + xx - P;
            float v = 0.f;
            if ((unsigned)gy < (unsigned)H && (unsigned)gx < (unsigned)W)
                v = in[(((long)n * Cin + cs + ci) * H + gy) * W + gx];
            slab[(ci * SW + yy) * RS + xx] = v;
        }
        for (int i = tid; i < COB * CIC * KK; i += 256) {
            int col = i / (CIC * KK); int r = i % (CIC * KK);
            wl[col * WS + r] = wgt[(((long)(co0 + col)) * Cin + cs) * KK + r];
        }
        __syncthreads();

        for (int ci = 0; ci < CIC; ++ci) {
            float xr[XW][XW];
#pragma unroll
            for (int yy = 0; yy < XW; ++yy) {
                int xb = (ci * SW + py0 + yy) * RS + px0;
                if constexpr (PT == 4 && K == 5) {
                    float4 a4 = *(const float4*)&slab[xb];
                    float4 b4 = *(const float4*)&slab[xb + 4];
                    xr[yy][0]=a4.x; xr[yy][1]=a4.y; xr[yy][2]=a4.z; xr[yy][3]=a4.w;
                    xr[yy][4]=b4.x; xr[yy][5]=b4.y; xr[yy][6]=b4.z; xr[yy][7]=b4.w;
                } else {
#pragma unroll
                    for (int xx = 0; xx < XW; ++xx) xr[yy][xx] = slab[xb + xx];
                }
            }
            float wr[CO_T][KK];
#pragma unroll
            for (int c = 0; c < CO_T; ++c)
#pragma unroll
                for (int k = 0; k < KK; ++k)
                    wr[c][k] = wl[(ssub * CO_T + c) * WS + ci * KK + k];
#pragma unroll
            for (int c = 0; c < CO_T; ++c)
#pragma unroll
                for (int oy = 0; oy < PT; ++oy)
#pragma unroll
                    for (int ox = 0; ox < PT; ++ox) {
                        float a = acc[c][oy][ox];
#pragma unroll
                        for (int ky = 0; ky < K; ++ky)
#pragma unroll
                            for (int kx = 0; kx < K; ++kx)
                                a = fmaf(xr[oy + ky][ox + kx], wr[c][ky * K + kx], a);
                        acc[c][oy][ox] = a;
                    }
        }
        __syncthreads();
    }

#pragma unroll
    for (int c = 0; c < CO_T; ++c) {
        int co = co0 + ssub * CO_T + c;
#pragma unroll
        for (int oy = 0; oy < PT; ++oy) {
            int y = y0 + py0 + oy;
            if (y >= H) continue;
#pragma unroll
            for (int ox = 0; ox < PT; ++ox) {
                int x = x0 + px0 + ox;
                if (x >= W) continue;
                out[(((long)n * Cout + co) * H + y) * W + x] = lrelu01(acc[c][oy][ox]);
            }
        }
    }
}

// ---------------- max over T --------------------------------------------------
__global__ void max_over_T(const float* __restrict__ in, float* __restrict__ out,
                           int Bn, int Tn, int F)
{
    long idx = (long)blockIdx.x * blockDim.x + threadIdx.x;
    if (idx >= (long)Bn * F) return;
    int b = (int)(idx / F), f = (int)(idx % F);
    float m = -1e30f;
    for (int t = 0; t < Tn; ++t)
        m = fmaxf(m, in[((long)(b * Tn + t)) * F + f]);
    out[idx] = m;
}

// ---------------- ROI crop + bilinear resize ----------------------------------
__global__ void roi_crop(const float* __restrict__ x, const float* __restrict__ px,
                         float* __restrict__ crops)
{
    int idx = blockIdx.x * blockDim.x + threadIdx.x;
    const int total = kB * kT * kR * kRH * kRW;
    if (idx >= total) return;
    int j  = idx % kRW; int t2 = idx / kRW;
    int i  = t2 % kRH;  t2 /= kRH;
    int r  = t2 % kR;   int bt = t2 / kR;

    float cx = px[(bt * kR + r) * 2 + 0];
    float cy = px[(bt * kR + r) * 2 + 1];
    float x1 = floorf(fminf(fmaxf(cx - 7.f, 0.f), 63.f));
    float x2 = floorf(fminf(cx + 7.f, 64.f));
    float y1 = floorf(fminf(fmaxf(cy - 7.f, 0.f), 63.f));
    float y2 = floorf(fminf(cy + 7.f, 64.f));

    float sx = x1 + (j + 0.5f) * (x2 - x1) * (1.f / 14.f) - 0.5f;
    sx = fminf(fmaxf(sx, x1), x2 - 1.f);
    float sy = y1 + (i + 0.5f) * (y2 - y1) * (1.f / 14.f) - 0.5f;
    sy = fminf(fmaxf(sy, y1), y2 - 1.f);

    float ix0f = floorf(sx), iy0f = floorf(sy);
    float wx = sx - ix0f,    wy = sy - iy0f;
    int ix0 = (int)ix0f,     iy0 = (int)iy0f;
    int ix1 = (int)fminf(ix0f + 1.f, x2 - 1.f);
    int iy1 = (int)fminf(iy0f + 1.f, y2 - 1.f);

    const float* img = x + (long)bt * 64 * 64;
    float v00 = img[iy0 * 64 + ix0], v01 = img[iy0 * 64 + ix1];
    float v10 = img[iy1 * 64 + ix0], v11 = img[iy1 * 64 + ix1];
    float top = (1.f - wx) * v00 + wx * v01;
    float bot = (1.f - wx) * v10 + wx * v11;
    crops[idx] = (1.f - wy) * top + wy * bot;
}

// ---------------- tiny dense matmul ------------------------------------------
__global__ void matmul_small(const float* __restrict__ in, const float* __restrict__ w,
                             float* __restrict__ out, int rows, int Kd, int O)
{
    int idx = blockIdx.x * blockDim.x + threadIdx.x;
    if (idx >= rows * O) return;
    int row = idx / O, o = idx % O;
    float acc = 0.f;
    for (int k = 0; k < Kd; ++k) acc = fmaf(in[(long)row * Kd + k], w[k * O + o], acc);
    out[idx] = acc;
}

// ---------------- GAT attention scalars ---------------------------------------
__global__ void gat_scores(const float* __restrict__ h, const float* __restrict__ a1,
                           const float* __restrict__ a2, float* __restrict__ s1,
                           float* __restrict__ s2, int total, int D)
{
    int idx = blockIdx.x * blockDim.x + threadIdx.x;
    if (idx >= total) return;
    const float* hr = h + (long)idx * D;
    float acc1 = 0.f, acc2 = 0.f;
    for (int k = 0; k < D; ++k) {
        acc1 = fmaf(hr[k], a1[k], acc1);
        acc2 = fmaf(hr[k], a2[k], acc2);
    }
    s1[idx] = acc1; s2[idx] = acc2;
}

// ---------------- GAT masked-softmax aggregate --------------------------------
template <int D>
__global__ void gat_aggregate(const float* __restrict__ h, const float* __restrict__ s1,
                              const float* __restrict__ s2, float* __restrict__ out)
{
    int bi = blockIdx.x;
    int b = bi / kN, i = bi % kN;
    int j = threadIdx.x;
    __shared__ float red[256];
    __shared__ float wsh[256];

    float ej = -1e30f;
    if (j < kN) {
        int fri = i / kR, rki = i % kR;
        int frj = j / kR, rkj = j % kR;
        int df = fri - frj;
        bool adj = (fri == frj) || ((rki == rkj) && (df == 1 || df == -1));
        float v = s1[b * kN + i] + s2[b * kN + j];
        v = v > 0.f ? v : 0.2f * v;
        ej = adj ? v : -9.0e15f;
    }
    red[j] = ej; __syncthreads();
#pragma unroll
    for (int off = 128; off > 0; off >>= 1) {
        if (j < off) red[j] = fmaxf(red[j], red[j + off]);
        __syncthreads();
    }
    float mx = red[0]; __syncthreads();

    float ex = (j < kN) ? expf(ej - mx) : 0.f;
    red[j] = ex; __syncthreads();
#pragma unroll
    for (int off = 128; off > 0; off >>= 1) {
        if (j < off) red[j] += red[j + off];
        __syncthreads();
    }
    float sum = red[0]; __syncthreads();

    wsh[j] = ex / sum; __syncthreads();

    if (j < D) {
        float acc = 0.f;
        for (int jj = 0; jj < kN; ++jj)
            acc = fmaf(wsh[jj], h[((long)b * kN + jj) * D + j], acc);
        out[((long)b * kN + i) * D + j] = acc;
    }
}

// ---------------- elu + log_softmax (last dim 16) -----------------------------
__global__ void elu_logsoftmax(const float* __restrict__ in, float* __restrict__ out,
                               int rows)
{
    int r = blockIdx.x * blockDim.x + threadIdx.x;
    if (r >= rows) return;
    float v[16];
    float mx = -1e30f;
#pragma unroll
    for (int k = 0; k < 16; ++k) {
        float xv = in[(long)r * 16 + k];
        xv = xv > 0.f ? xv : expm1f(xv);
        v[k] = xv; mx = fmaxf(mx, xv);
    }
    float s = 0.f;
#pragma unroll
    for (int k = 0; k < 16; ++k) s += expf(v[k] - mx);
    float ls = logf(s) + mx;
#pragma unroll
    for (int k = 0; k < 16; ++k) out[(long)r * 16 + k] = v[k] - ls;
}

// ---------------- mean over nodes of concat(l_fc, gat_fc) ---------------------
__global__ void lcat_mean(const float* __restrict__ lfc, const float* __restrict__ gatfc,
                          float* __restrict__ fcbuf)
{
    int idx = blockIdx.x * blockDim.x + threadIdx.x;
    if (idx >= kB * 272) return;
    int b = idx / 272, c = idx % 272;
    float s = 0.f;
    if (c < 256) {
        for (int n2 = 0; n2 < kN; ++n2) s += lfc[((long)b * kN + n2) * 256 + c];
    } else {
        int cc = c - 256;
        for (int n2 = 0; n2 < kN; ++n2) s += gatfc[((long)b * kN + n2) * 16 + cc];
    }
    fcbuf[b * 528 + 256 + c] = s * (1.f / kN);
}

// ---------------- final pyramid ----------------------------------------------
__global__ void final_feats(const float* __restrict__ fcbuf, float* __restrict__ out)
{
    int idx = blockIdx.x * blockDim.x + threadIdx.x;
    if (idx >= kB * 1023) return;
    int b = idx / 1023, m = idx % 1023;
    int nb, seg, off;
    if      (m < 528) { nb = 1;  seg = 528; off = 0;   }
    else if (m < 792) { nb = 2;  seg = 264; off = 528; }
    else if (m < 924) { nb = 4;  seg = 132; off = 792; }
    else if (m < 990) { nb = 8;  seg = 66;  off = 924; }
    else              { nb = 16; seg = 33;  off = 990; }
    int mm = m - off;
    float s = 0.f, mx = -1e30f;
    for (int k2 = 0; k2 < nb; ++k2) {
        float v = fcbuf[b * 528 + k2 * seg + mm];
        s += v; mx = fmaxf(mx, v);
    }
    out[(long)b * 1023 + m] = s / nb + mx;
}

// ---------------------------------------------------------------------------
extern "C" void kernel_launch(void* const* d_in, const int* in_sizes, int n_in,
                              void* d_out, int out_size, void* d_ws, size_t ws_size,
                              hipStream_t stream)
{
    const float* x       = (const float*)d_in[0];
    const float* px      = (const float*)d_in[1];
    const float* cw1     = (const float*)d_in[2];
    const float* cw2     = (const float*)d_in[3];
    const float* cw3     = (const float*)d_in[4];
    const float* cw4     = (const float*)d_in[5];
    const float* cw5     = (const float*)d_in[6];
    const float* cw6     = (const float*)d_in[7];
    const float* fc_g_w  = (const float*)d_in[8];
    const float* fc_g_b  = (const float*)d_in[9];
    const float* fc_l_w  = (const float*)d_in[10];
    const float* fc_l_b  = (const float*)d_in[11];
    const float* gat1_W  = (const float*)d_in[12];
    const float* gat1_a1 = (const float*)d_in[13];
    const float* gat1_a2 = (const float*)d_in[14];
    const float* gat2_W  = (const float*)d_in[15];
    const float* gat2_a1 = (const float*)d_in[16];
    const float* gat2_a2 = (const float*)d_in[17];

    float* ws    = (float*)d_ws;
    float* A     = ws;                      // 31,457,280 floats
    float* Bb    = A + 31457280;            //  7,864,320
    float* crops = Bb + 7864320;            //    376,320
    float* gmaxb = crops + 376320;          //    262,144
    float* lfc   = gmaxb + 262144;          //    491,520
    float* h1    = lfc + 491520;
    float* s1    = h1 + 15360;
    float* s2    = s1 + 1920;
    float* o1    = s2 + 1920;
    float* h2    = o1 + 15360;
    float* s1b   = h2 + 30720;
    float* s2b   = s1b + 1920;
    float* o2    = s2b + 1920;
    float* gatfc = o2 + 30720;
    float* fcbuf = gatfc + 30720;           // 4,224

    // dedicated packed-weight regions (bf16)
    short* bp2 = (short*)(fcbuf + 4224);    // 9,216 shorts
    short* bp3 = bp2 + 9216;                // 18,432
    short* bp4 = bp3 + 18432;               // 36,864
    short* bp5 = bp4 + 36864;               // 73,728
    short* bp6 = bp5 + 73728;               // 147,456
    short* wpl = bp6 + 147456;              // 294,912 (fc_l packed)

    auto cdiv = [](long a, long b) { return (int)((a + b - 1) / b); };
    const int TB = 256;

    // ---------------- weight repack ----------------
    repack_w< 32,  32><<<cdiv(  9216 / 8, TB), TB, 0, stream>>>(cw2, bp2);
    repack_w< 32,  64><<<cdiv( 18432 / 8, TB), TB, 0, stream>>>(cw3, bp3);
    repack_w< 64,  64><<<cdiv( 36864 / 8, TB), TB, 0, stream>>>(cw4, bp4);
    repack_w< 64, 128><<<cdiv( 73728 / 8, TB), TB, 0, stream>>>(cw5, bp5);
    repack_w<128, 128><<<cdiv(147456 / 8, TB), TB, 0, stream>>>(cw6, bp6);
    repack_dense<1152, 256><<<cdiv(294912 / 8, TB), TB, 0, stream>>>(fc_l_w, wpl);

    // ---------------- global path ----------------
    conv_tile<5, false, 1, 32, 64, 64, 32, 4, 2, 1><<<3840, 256, 0, stream>>>(x, cw1, A);
    conv_mfma<  32,  32, 64, 64, true,  1><<<3840, 256, 0, stream>>>(A,  bp2, Bb);
    conv_mfma<  32,  64, 32, 32, false, 1><<< 960, 256, 0, stream>>>(Bb, bp3, A);
    conv_mfma<  64,  64, 32, 32, true,  1><<< 960, 256, 0, stream>>>(A,  bp4, Bb);
    conv_mfma<  64, 128, 16, 16, false, 2><<< 480, 256, 0, stream>>>(Bb, bp5, A);
    conv_mfma< 128, 128, 16, 16, false, 2><<< 480, 256, 0, stream>>>(A,  bp6, Bb);
    max_over_T<<<cdiv(8L * 32768, TB), TB, 0, stream>>>(Bb, gmaxb, 8, 30, 32768);
    init_fcg<<<cdiv(2048L, TB), TB, 0, stream>>>(fc_g_b, fcbuf);
    fcg_partial<<<1024, 256, 0, stream>>>(gmaxb, fc_g_w, fcbuf);

    // ---------------- local path ----------------
    roi_crop<<<cdiv(1920L * 196, TB), TB, 0, stream>>>(x, px, crops);
    conv_tile<5, false, 1, 32, 14, 14, 16, 4, 2, 1><<<1920, 256, 0, stream>>>(crops, cw1, A);
    conv2l_mfma<<<1920, 256, 0, stream>>>(A,  bp2, Bb);
    conv3l_mfma<<< 480, 256, 0, stream>>>(Bb, bp3, A);
    conv4l_mfma<<< 960, 256, 0, stream>>>(A,  bp4, Bb);
    conv56l_mfma< 64><<<240, 256, 0, stream>>>(Bb, bp5, A);
    conv56l_mfma<128><<<240, 256, 0, stream>>>(A,  bp6, Bb);
    linear_l_mfma<<<120, 256, 0, stream>>>(Bb, wpl, fc_l_b, lfc);

    // ---------------- GAT ----------------
    matmul_small<<<cdiv(1920L * 8, TB), TB, 0, stream>>>(lfc, gat1_W, h1, kB * kN, 256, 8);
    gat_scores<<<cdiv(1920L, TB), TB, 0, stream>>>(h1, gat1_a1, gat1_a2, s1, s2, kB * kN, 8);
    gat_aggregate<8><<<kB * kN, TB, 0, stream>>>(h1, s1, s2, o1);
    matmul_small<<<cdiv(1920L * 16, TB), TB, 0, stream>>>(o1, gat2_W, h2, kB * kN, 8, 16);
    gat_scores<<<cdiv(1920L, TB), TB, 0, stream>>>(h2, gat2_a1, gat2_a2, s1b, s2b, kB * kN, 16);
    gat_aggregate<16><<<kB * kN, TB, 0, stream>>>(h2, s1b, s2b, o2);
    elu_logsoftmax<<<cdiv(1920L, TB), TB, 0, stream>>>(o2, gatfc, kB * kN);

    // ---------------- head ----------------
    lcat_mean<<<cdiv(8L * 272, TB), TB, 0, stream>>>(lfc, gatfc, fcbuf);
    final_feats<<<cdiv(8L * 1023, TB), TB, 0, stream>>>(fcbuf, (float*)d_out);
}

// Round 5
// 808.923 us; speedup vs baseline: 32.3795x; 1.1822x over previous
//
#include <hip/hip_runtime.h>
#include <hip/hip_bf16.h>

// ---------------------------------------------------------------------------
// RGPNet forward. Round 5: channel-last bf16 local path, unified convl_cl,
// merged repack, wave-per-node GAT aggregate.
// ---------------------------------------------------------------------------

constexpr int kB = 8, kT = 30, kR = 8;
constexpr int kN = kT * kR;          // 240 nodes per batch
constexpr int kRH = 14, kRW = 14;

static __device__ __forceinline__ float lrelu01(float v) {
    return v > 0.f ? v : 0.01f * v;
}

typedef __attribute__((ext_vector_type(8))) short bf16x8;
typedef __attribute__((ext_vector_type(4))) float f32x4;

static __device__ __forceinline__ short f2bf(float v) {
    __hip_bfloat16 h = __float2bfloat16(v);
    return *reinterpret_cast<short*>(&h);
}
static __device__ __forceinline__ float bf2f(short s) {
    unsigned u = ((unsigned)(unsigned short)s) << 16;
    return __uint_as_float(u);
}

// ---------------------------------------------------------------------------
// Repack bodies (device): conv OIHW fp32 -> per-lane B-fragment bf16.
// bp[(((cs*9+kykx)*NFTOT + nf)*64 + lane)*8 + j]
//   = W[nf*16+(lane&15)][cs*32+(lane>>4)*8+j][ky][kx]
// ---------------------------------------------------------------------------
template <int Cin, int Cout>
static __device__ void repack_w_body(const float* __restrict__ w,
                                     short* __restrict__ bp, int t)
{
    constexpr int NFTOT = Cout / 16;
    int lane = t & 63, rest = t >> 6;
    int nf = rest % NFTOT; rest /= NFTOT;
    int kykx = rest % 9; int cs = rest / 9;
    int co  = nf * 16 + (lane & 15);
    int cib = cs * 32 + (lane >> 4) * 8;
#pragma unroll
    for (int j = 0; j < 8; ++j) {
        float v = w[((long)co * Cin + cib + j) * 9 + kykx];
        bp[(long)t * 8 + j] = f2bf(v);
    }
}

// fc_l repack with K-permutation for channel-last input: k = s*128 + c,
// original column = c*9 + s.
static __device__ void repack_dense_body(const float* __restrict__ w,
                                         short* __restrict__ wp, int t)
{
    constexpr int KD = 1152;
    int lane = t & 63, rest = t >> 6;
    int nf = rest % 16; int kc = rest / 16;
    int co = nf * 16 + (lane & 15);
    int k0 = kc * 32 + (lane >> 4) * 8;
#pragma unroll
    for (int j = 0; j < 8; ++j) {
        int k = k0 + j;
        int korig = (k & 127) * 9 + (k >> 7);
        wp[(long)t * 8 + j] = f2bf(w[(long)co * KD + korig]);
    }
}

__global__ __launch_bounds__(256) void repack_all(
    const float* cw2, const float* cw3, const float* cw4,
    const float* cw5, const float* cw6, const float* fclw,
    short* bp2, short* bp3, short* bp4, short* bp5, short* bp6, short* wpl)
{
    int t = blockIdx.x * 256 + threadIdx.x;
    if      (t < 1152)                repack_w_body< 32,  32>(cw2, bp2, t);
    else if (t < 1152 + 2304)         repack_w_body< 32,  64>(cw3, bp3, t - 1152);
    else if (t < 3456 + 4608)         repack_w_body< 64,  64>(cw4, bp4, t - 3456);
    else if (t < 8064 + 9216)         repack_w_body< 64, 128>(cw5, bp5, t - 8064);
    else if (t < 17280 + 18432)       repack_w_body<128, 128>(cw6, bp6, t - 17280);
    else if (t < 35712 + 36864)       repack_dense_body(fclw, wpl, t - 35712);
}

// ---------------------------------------------------------------------------
// Global-path MFMA implicit-GEMM 3x3 conv (unchanged).
// ---------------------------------------------------------------------------
template <int Cin, int Cout, int H, int W, bool POOL, int NSPLIT>
__global__ __launch_bounds__(256) void conv_mfma(
    const float* __restrict__ in, const short* __restrict__ bp,
    float* __restrict__ out)
{
    constexpr int NFTOT = Cout / 16;
    constexpr int NF    = NFTOT / NSPLIT;
    constexpr int CS    = Cin / 32;
    constexpr int TX    = W / 16, TY = H / 16;
    constexpr int CP    = 40;
    constexpr int Ho    = POOL ? H / 2 : H, Wo = POOL ? W / 2 : W;

    __shared__ short slab[18 * 18 * CP];

    int bid = blockIdx.x;
    const int split = bid % NSPLIT; bid /= NSPLIT;
    const int txt = bid % TX; bid /= TX;
    const int tyt = bid % TY; bid /= TY;
    const int n   = bid;
    const int x0 = txt * 16, y0 = tyt * 16;
    const int nf0 = split * NF;

    const int tid = threadIdx.x;
    const int lane = tid & 63, wav = tid >> 6;
    const int mrow0 = wav * 4;
    const int lx = lane & 15, lg = lane >> 4;

    f32x4 acc[4][NF];
#pragma unroll
    for (int r = 0; r < 4; ++r)
#pragma unroll
        for (int f = 0; f < NF; ++f) acc[r][f] = (f32x4)0.f;

    for (int cs = 0; cs < CS; ++cs) {
        for (int i = tid; i < 18 * 18 * 32; i += 256) {
            int ci = i / 324, r2 = i % 324;
            int yy = r2 / 18, xx = r2 % 18;
            int gy = y0 - 1 + yy, gx = x0 - 1 + xx;
            float v = 0.f;
            if ((unsigned)gy < (unsigned)H && (unsigned)gx < (unsigned)W)
                v = in[(((long)n * Cin + cs * 32 + ci) * H + gy) * W + gx];
            slab[(yy * 18 + xx) * CP + ci] = f2bf(v);
        }
        __syncthreads();

#pragma unroll
        for (int ky = 0; ky < 3; ++ky)
#pragma unroll
        for (int kx = 0; kx < 3; ++kx) {
            bf16x8 a[4];
#pragma unroll
            for (int r = 0; r < 4; ++r)
                a[r] = *(const bf16x8*)&slab[((mrow0 + r + ky) * 18 + lx + kx) * CP + lg * 8];
            const int kykx = ky * 3 + kx;
#pragma unroll
            for (int f = 0; f < NF; ++f) {
                bf16x8 b = *(const bf16x8*)&bp[(((long)(cs * 9 + kykx) * NFTOT + nf0 + f) * 64 + lane) * 8];
#pragma unroll
                for (int r = 0; r < 4; ++r)
                    acc[r][f] = __builtin_amdgcn_mfma_f32_16x16x32_bf16(a[r], b, acc[r][f], 0, 0, 0);
            }
        }
        __syncthreads();
    }

    if constexpr (!POOL) {
#pragma unroll
        for (int f = 0; f < NF; ++f) {
            int co = (nf0 + f) * 16 + lx;
#pragma unroll
            for (int r = 0; r < 4; ++r) {
                int y = y0 + mrow0 + r;
                float4 v;
                v.x = lrelu01(acc[r][f][0]); v.y = lrelu01(acc[r][f][1]);
                v.z = lrelu01(acc[r][f][2]); v.w = lrelu01(acc[r][f][3]);
                *(float4*)&out[(((long)n * Cout + co) * H + y) * W + x0 + lg * 4] = v;
            }
        }
    } else {
#pragma unroll
        for (int f = 0; f < NF; ++f) {
            int co = (nf0 + f) * 16 + lx;
#pragma unroll
            for (int q = 0; q < 2; ++q) {
                int yp = (y0 >> 1) + wav * 2 + q;
                float m0 = fmaxf(fmaxf(lrelu01(acc[2*q][f][0]), lrelu01(acc[2*q][f][1])),
                                 fmaxf(lrelu01(acc[2*q+1][f][0]), lrelu01(acc[2*q+1][f][1])));
                float m1 = fmaxf(fmaxf(lrelu01(acc[2*q][f][2]), lrelu01(acc[2*q][f][3])),
                                 fmaxf(lrelu01(acc[2*q+1][f][2]), lrelu01(acc[2*q+1][f][3])));
                float2 v; v.x = m0; v.y = m1;
                *(float2*)&out[(((long)n * Cout + co) * Ho + yp) * Wo + (x0 >> 1) + lg * 2] = v;
            }
        }
    }
}

// ---------------------------------------------------------------------------
// Local conv2: fp32 NCHW 32x14x14 input -> pool -> bf16 channel-last [49][32].
// One image per block; M = x; y = wav*4+r.
// ---------------------------------------------------------------------------
__global__ __launch_bounds__(256) void conv2l_mfma(
    const float* __restrict__ in, const short* __restrict__ bp,
    short* __restrict__ out)
{
    constexpr int CP = 40;
    __shared__ short slab[16 * 16 * CP];
    const int n = blockIdx.x;
    const int tid = threadIdx.x;
    const int lane = tid & 63, wav = tid >> 6;
    const int lx = lane & 15, lg = lane >> 4;

    for (int i = tid; i < 16 * 16 * 32; i += 256) {
        int ci = i >> 8, r2 = i & 255;
        int yy = r2 >> 4, xx = r2 & 15;
        int gy = yy - 1, gx = xx - 1;
        float v = 0.f;
        if ((unsigned)gy < 14u && (unsigned)gx < 14u)
            v = in[(((long)n * 32 + ci) * 14 + gy) * 14 + gx];
        slab[(yy * 16 + xx) * CP + ci] = f2bf(v);
    }
    __syncthreads();

    f32x4 acc[4][2];
#pragma unroll
    for (int r = 0; r < 4; ++r)
#pragma unroll
        for (int f = 0; f < 2; ++f) acc[r][f] = (f32x4)0.f;

#pragma unroll
    for (int ky = 0; ky < 3; ++ky)
#pragma unroll
    for (int kx = 0; kx < 3; ++kx) {
        bf16x8 a[4];
        int xcl = min(lx + kx, 15);
#pragma unroll
        for (int r = 0; r < 4; ++r) {
            int ycl = min(wav * 4 + r + ky, 15);
            a[r] = *(const bf16x8*)&slab[(ycl * 16 + xcl) * CP + lg * 8];
        }
        const int kykx = ky * 3 + kx;
#pragma unroll
        for (int f = 0; f < 2; ++f) {
            bf16x8 b = *(const bf16x8*)&bp[(((long)kykx * 2 + f) * 64 + lane) * 8];
#pragma unroll
            for (int r = 0; r < 4; ++r)
                acc[r][f] = __builtin_amdgcn_mfma_f32_16x16x32_bf16(a[r], b, acc[r][f], 0, 0, 0);
        }
    }

    // pool epilogue; write channel-last bf16: out[(n*49 + yp*7+xp)*32 + co]
#pragma unroll
    for (int f = 0; f < 2; ++f) {
        int co = f * 16 + lx;
#pragma unroll
        for (int q = 0; q < 2; ++q) {
            int yp = wav * 2 + q;
            if (yp >= 7) continue;
            float m0 = fmaxf(fmaxf(lrelu01(acc[2*q][f][0]), lrelu01(acc[2*q][f][1])),
                             fmaxf(lrelu01(acc[2*q+1][f][0]), lrelu01(acc[2*q+1][f][1])));
            float m1 = fmaxf(fmaxf(lrelu01(acc[2*q][f][2]), lrelu01(acc[2*q][f][3])),
                             fmaxf(lrelu01(acc[2*q+1][f][2]), lrelu01(acc[2*q+1][f][3])));
            int xp0 = lg * 2;
            out[((long)n * 49 + yp * 7 + xp0) * 32 + co] = f2bf(m0);
            if (xp0 + 1 < 7)
                out[((long)n * 49 + yp * 7 + xp0 + 1) * 32 + co] = f2bf(m1);
        }
    }
}

// ---------------------------------------------------------------------------
// Unified channel-last local conv (conv3l..conv6l). Input/output bf16
// [n][S*S][C]. Zero-slot LDS layout, vectorized staging, MFMA compute.
// ---------------------------------------------------------------------------
template <int Cin, int Cout, int S, bool POOL, int G, int NSPLIT>
__global__ __launch_bounds__(256) void convl_cl(
    const short* __restrict__ in, const short* __restrict__ bp,
    short* __restrict__ out)
{
    constexpr int SS    = S * S;
    constexpr int M     = G * SS;
    constexpr int MT    = (M + 15) / 16;
    constexpr int TPW   = (MT + 3) / 4;
    constexpr int CPAD  = Cin + 8;
    constexpr int NFTOT = Cout / 16;
    constexpr int NF    = NFTOT / NSPLIT;
    constexpr int CS    = Cin / 32;
    constexpr int So    = S / 2;

    __shared__ __align__(16) short slab[(1 + M) * CPAD];

    const int bid   = blockIdx.x;
    const int split = bid % NSPLIT;
    const int n0    = (bid / NSPLIT) * G;
    const int nf0   = split * NF;
    const int tid   = threadIdx.x;
    const int lane  = tid & 63, wav = tid >> 6;
    const int lx    = lane & 15, lg = lane >> 4;

    // zero slot 0 + vectorized stage (input contiguous for images n0..n0+G-1)
    for (int i = tid; i < CPAD / 8; i += 256)
        *(bf16x8*)&slab[i * 8] = (bf16x8)(short)0;
    const short* src = in + (long)n0 * SS * Cin;
    for (int i = tid; i < M * (Cin / 8); i += 256) {
        int gs = i / (Cin / 8), c8 = i % (Cin / 8);
        *(bf16x8*)&slab[(1 + gs) * CPAD + c8 * 8] = *(const bf16x8*)&src[(long)i * 8];
    }
    __syncthreads();

    // per-lane A slot offsets
    int aoff[TPW][9];
#pragma unroll
    for (int i = 0; i < TPW; ++i) {
        int mt = wav + i * 4;
        int m = mt * 16 + lx;
        if (mt >= MT || m > M - 1) m = M - 1;
        int g = m / SS, s = m % SS, y = s / S, x = s % S;
#pragma unroll
        for (int ky = 0; ky < 3; ++ky)
#pragma unroll
        for (int kx = 0; kx < 3; ++kx) {
            int iy = y + ky - 1, ix = x + kx - 1;
            bool ok = (unsigned)iy < (unsigned)S && (unsigned)ix < (unsigned)S;
            aoff[i][ky * 3 + kx] = (ok ? (1 + g * SS + iy * S + ix) : 0) * CPAD + lg * 8;
        }
    }

    f32x4 acc[TPW][NF];
#pragma unroll
    for (int i = 0; i < TPW; ++i)
#pragma unroll
        for (int f = 0; f < NF; ++f) acc[i][f] = (f32x4)0.f;

    for (int cs = 0; cs < CS; ++cs) {
#pragma unroll
        for (int kk = 0; kk < 9; ++kk) {
            bf16x8 a[TPW];
#pragma unroll
            for (int i = 0; i < TPW; ++i)
                a[i] = *(const bf16x8*)&slab[aoff[i][kk] + cs * 32];
#pragma unroll
            for (int f = 0; f < NF; ++f) {
                bf16x8 b = *(const bf16x8*)&bp[(((long)(cs * 9 + kk) * NFTOT + nf0 + f) * 64 + lane) * 8];
#pragma unroll
                for (int i = 0; i < TPW; ++i)
                    acc[i][f] = __builtin_amdgcn_mfma_f32_16x16x32_bf16(a[i], b, acc[i][f], 0, 0, 0);
            }
        }
    }

    if constexpr (!POOL) {
#pragma unroll
        for (int i = 0; i < TPW; ++i) {
            int mt = wav + i * 4;
            if (mt >= MT) continue;
#pragma unroll
            for (int f = 0; f < NF; ++f) {
                int co = (nf0 + f) * 16 + lx;
#pragma unroll
                for (int r = 0; r < 4; ++r) {
                    int m = mt * 16 + lg * 4 + r;
                    if (m >= M) continue;
                    int g = m / SS, s = m % SS;
                    out[((long)(n0 + g) * SS + s) * Cout + co] = f2bf(lrelu01(acc[i][f][r]));
                }
            }
        }
    } else {
        // pool 2x2 via LDS round-trip (bf16 max is exact on bf16 values)
        constexpr int CPO = Cout + 8;
        static_assert((long)M * CPO <= (long)(1 + M) * CPAD, "pool lds");
        __syncthreads();
#pragma unroll
        for (int i = 0; i < TPW; ++i) {
            int mt = wav + i * 4;
            if (mt >= MT) continue;
#pragma unroll
            for (int f = 0; f < NF; ++f) {
                int co = (nf0 + f) * 16 + lx;
#pragma unroll
                for (int r = 0; r < 4; ++r) {
                    int m = mt * 16 + lg * 4 + r;
                    if (m >= M) continue;
                    slab[m * CPO + co] = f2bf(lrelu01(acc[i][f][r]));
                }
            }
        }
        __syncthreads();
        for (int o = tid; o < G * So * So * Cout; o += 256) {
            int c = o % Cout; int rest = o / Cout;
            int xp = rest % So; rest /= So;
            int yp = rest % So; int g = rest / So;
            int base = (g * SS + 2 * yp * S + 2 * xp) * CPO + c;
            float v0 = bf2f(slab[base]);
            float v1 = bf2f(slab[base + CPO]);
            float v2 = bf2f(slab[base + S * CPO]);
            float v3 = bf2f(slab[base + (S + 1) * CPO]);
            float mv = fmaxf(fmaxf(v0, v1), fmaxf(v2, v3));
            out[((long)(n0 + g) * So * So + yp * So + xp) * Cout + c] = f2bf(mv);
        }
    }
}

// ---------------------------------------------------------------------------
// fc_l as MFMA GEMM, bf16 channel-last input [1920][1152].
// ---------------------------------------------------------------------------
__global__ __launch_bounds__(256) void linear_l_mfma(
    const short* __restrict__ in, const short* __restrict__ wp,
    const float* __restrict__ bias, float* __restrict__ out)
{
    constexpr int KD = 1152, LDK = KD + 8;
    __shared__ __align__(16) short slab[16 * LDK];
    const int m0 = blockIdx.x * 16;
    const int tid = threadIdx.x;
    const int lane = tid & 63, wav = tid >> 6;
    const int lx = lane & 15, lg = lane >> 4;

    for (int i = tid; i < 16 * (KD / 8); i += 256) {
        int r = i / (KD / 8), c8 = i % (KD / 8);
        *(bf16x8*)&slab[r * LDK + c8 * 8] = *(const bf16x8*)&in[(long)(m0 + r) * KD + c8 * 8];
    }
    __syncthreads();

    f32x4 acc[4];
#pragma unroll
    for (int f = 0; f < 4; ++f) acc[f] = (f32x4)0.f;

    for (int kc = 0; kc < KD / 32; ++kc) {
        bf16x8 a = *(const bf16x8*)&slab[lx * LDK + kc * 32 + lg * 8];
#pragma unroll
        for (int f = 0; f < 4; ++f) {
            int nf = wav * 4 + f;
            bf16x8 b = *(const bf16x8*)&wp[(((long)kc * 16 + nf) * 64 + lane) * 8];
            acc[f] = __builtin_amdgcn_mfma_f32_16x16x32_bf16(a, b, acc[f], 0, 0, 0);
        }
    }

#pragma unroll
    for (int f = 0; f < 4; ++f) {
        int co = (wav * 4 + f) * 16 + lx;
        float bv = bias[co];
#pragma unroll
        for (int reg = 0; reg < 4; ++reg) {
            int m = m0 + lg * 4 + reg;
            out[(long)m * 256 + co] = acc[f][reg] + bv;
        }
    }
}

// ---------------------------------------------------------------------------
// fc_g: split-K, weights read once, all 8 batch rows per wave, atomicAdd.
// ---------------------------------------------------------------------------
__global__ void init_fcg(const float* __restrict__ bias, float* __restrict__ fcbuf)
{
    int idx = blockIdx.x * blockDim.x + threadIdx.x;
    if (idx >= 8 * 256) return;
    fcbuf[(idx >> 8) * 528 + (idx & 255)] = bias[idx & 255];
}

__global__ __launch_bounds__(256) void fcg_partial(
    const float* __restrict__ in, const float* __restrict__ w,
    float* __restrict__ fcbuf)
{
    const int gid = blockIdx.x * 256 + threadIdx.x;
    const int wid = gid >> 6, lane = gid & 63;
    const int o = wid >> 4, kc = wid & 15;
    const int k0 = kc * 2048;

    float acc[8];
#pragma unroll
    for (int m = 0; m < 8; ++m) acc[m] = 0.f;

    for (int it = 0; it < 8; ++it) {
        int k = k0 + it * 256 + lane * 4;
        float4 wv = *(const float4*)&w[(long)o * 32768 + k];
#pragma unroll
        for (int m = 0; m < 8; ++m) {
            float4 xv = *(const float4*)&in[(long)m * 32768 + k];
            acc[m] = fmaf(xv.x, wv.x, acc[m]);
            acc[m] = fmaf(xv.y, wv.y, acc[m]);
            acc[m] = fmaf(xv.z, wv.z, acc[m]);
            acc[m] = fmaf(xv.w, wv.w, acc[m]);
        }
    }
#pragma unroll
    for (int off = 32; off > 0; off >>= 1)
#pragma unroll
        for (int m = 0; m < 8; ++m)
            acc[m] += __shfl_down(acc[m], off, 64);
    if (lane == 0) {
#pragma unroll
        for (int m = 0; m < 8; ++m)
            atomicAdd(&fcbuf[m * 528 + o], acc[m]);
    }
}

// ---------------------------------------------------------------------------
// Tiled fp32 conv (conv1 global + conv1 local: Cin=1, K=5).
// ---------------------------------------------------------------------------
template <int K, int Cin, int Cout, int H, int W,
          int TILE, int PT, int CO_T, int CIC>
__global__ __launch_bounds__(256) void conv_tile(
    const float* __restrict__ in, const float* __restrict__ wgt,
    float* __restrict__ out)
{
    constexpr int P   = K / 2;
    constexpr int NT  = (H + TILE - 1) / TILE;
    constexpr int SP  = TILE / PT;
    constexpr int SPT = SP * SP;
    constexpr int COS = 256 / SPT;
    constexpr int COB = COS * CO_T;
    constexpr int CG  = Cout / COB;
    constexpr int SW  = TILE + 2 * P;
    constexpr int RS  = (SW + 3) & ~3;
    constexpr int KK  = K * K;
    constexpr int WS  = CIC * KK + 1;
    constexpr int XW  = PT + 2 * P;

    __shared__ __align__(16) float slab[CIC * SW * RS];
    __shared__ __align__(16) float wl[COB * WS];

    int bid = blockIdx.x;
    const int cg = bid % CG; bid /= CG;
    const int tx = bid % NT; bid /= NT;
    const int ty = bid % NT;
    const int n  = bid / NT;
    const int x0 = tx * TILE, y0 = ty * TILE;
    const int co0 = cg * COB;

    const int tid  = threadIdx.x;
    const int sidx = tid % SPT, ssub = tid / SPT;
    const int px0  = (sidx % SP) * PT, py0 = (sidx / SP) * PT;

    float acc[CO_T][PT][PT];
#pragma unroll
    for (int c = 0; c < CO_T; ++c)
#pragma unroll
        for (int a = 0; a < PT; ++a)
#pragma unroll
            for (int b2 = 0; b2 < PT; ++b2) acc[c][a][b2] = 0.f;

    for (int cs = 0; cs < Cin; cs += CIC) {
        for (int i = tid; i < CIC * SW * SW; i += 256) {
            int ci = i / (SW * SW); int r = i % (SW * SW);
            int yy = r / SW, xx = r % SW;
            int gy = y0 + yy - P, gx = x0 + xx - P;
            float v = 0.f;
            if ((unsigned)gy < (unsigned)H && (unsigned)gx < (unsigned)W)
                v = in[(((long)n * Cin + cs + ci) * H + gy) * W + gx];
            slab[(ci * SW + yy) * RS + xx] = v;
        }
        for (int i = tid; i < COB * CIC * KK; i += 256) {
            int col = i / (CIC * KK); int r = i % (CIC * KK);
            wl[col * WS + r] = wgt[(((long)(co0 + col)) * Cin + cs) * KK + r];
        }
        __syncthreads();

        for (int ci = 0; ci < CIC; ++ci) {
            float xr[XW][XW];
#pragma unroll
            for (int yy = 0; yy < XW; ++yy) {
                int xb = (ci * SW + py0 + yy) * RS + px0;
                if constexpr (PT == 4 && K == 5) {
                    float4 a4 = *(const float4*)&slab[xb];
                    float4 b4 = *(const float4*)&slab[xb + 4];
                    xr[yy][0]=a4.x; xr[yy][1]=a4.y; xr[yy][2]=a4.z; xr[yy][3]=a4.w;
                    xr[yy][4]=b4.x; xr[yy][5]=b4.y; xr[yy][6]=b4.z; xr[yy][7]=b4.w;
                } else {
#pragma unroll
                    for (int xx = 0; xx < XW; ++xx) xr[yy][xx] = slab[xb + xx];
                }
            }
            float wr[CO_T][KK];
#pragma unroll
            for (int c = 0; c < CO_T; ++c)
#pragma unroll
                for (int k = 0; k < KK; ++k)
                    wr[c][k] = wl[(ssub * CO_T + c) * WS + ci * KK + k];
#pragma unroll
            for (int c = 0; c < CO_T; ++c)
#pragma unroll
                for (int oy = 0; oy < PT; ++oy)
#pragma unroll
                    for (int ox = 0; ox < PT; ++ox) {
                        float a = acc[c][oy][ox];
#pragma unroll
                        for (int ky = 0; ky < K; ++ky)
#pragma unroll
                            for (int kx = 0; kx < K; ++kx)
                                a = fmaf(xr[oy + ky][ox + kx], wr[c][ky * K + kx], a);
                        acc[c][oy][ox] = a;
                    }
        }
        __syncthreads();
    }

#pragma unroll
    for (int c = 0; c < CO_T; ++c) {
        int co = co0 + ssub * CO_T + c;
#pragma unroll
        for (int oy = 0; oy < PT; ++oy) {
            int y = y0 + py0 + oy;
            if (y >= H) continue;
#pragma unroll
            for (int ox = 0; ox < PT; ++ox) {
                int x = x0 + px0 + ox;
                if (x >= W) continue;
                out[(((long)n * Cout + co) * H + y) * W + x] = lrelu01(acc[c][oy][ox]);
            }
        }
    }
}

// ---------------- max over T --------------------------------------------------
__global__ void max_over_T(const float* __restrict__ in, float* __restrict__ out,
                           int Bn, int Tn, int F)
{
    long idx = (long)blockIdx.x * blockDim.x + threadIdx.x;
    if (idx >= (long)Bn * F) return;
    int b = (int)(idx / F), f = (int)(idx % F);
    float m = -1e30f;
    for (int t = 0; t < Tn; ++t)
        m = fmaxf(m, in[((long)(b * Tn + t)) * F + f]);
    out[idx] = m;
}

// ---------------- ROI crop + bilinear resize ----------------------------------
__global__ void roi_crop(const float* __restrict__ x, const float* __restrict__ px,
                         float* __restrict__ crops)
{
    int idx = blockIdx.x * blockDim.x + threadIdx.x;
    const int total = kB * kT * kR * kRH * kRW;
    if (idx >= total) return;
    int j  = idx % kRW; int t2 = idx / kRW;
    int i  = t2 % kRH;  t2 /= kRH;
    int r  = t2 % kR;   int bt = t2 / kR;

    float cx = px[(bt * kR + r) * 2 + 0];
    float cy = px[(bt * kR + r) * 2 + 1];
    float x1 = floorf(fminf(fmaxf(cx - 7.f, 0.f), 63.f));
    float x2 = floorf(fminf(cx + 7.f, 64.f));
    float y1 = floorf(fminf(fmaxf(cy - 7.f, 0.f), 63.f));
    float y2 = floorf(fminf(cy + 7.f, 64.f));

    float sx = x1 + (j + 0.5f) * (x2 - x1) * (1.f / 14.f) - 0.5f;
    sx = fminf(fmaxf(sx, x1), x2 - 1.f);
    float sy = y1 + (i + 0.5f) * (y2 - y1) * (1.f / 14.f) - 0.5f;
    sy = fminf(fmaxf(sy, y1), y2 - 1.f);

    float ix0f = floorf(sx), iy0f = floorf(sy);
    float wx = sx - ix0f,    wy = sy - iy0f;
    int ix0 = (int)ix0f,     iy0 = (int)iy0f;
    int ix1 = (int)fminf(ix0f + 1.f, x2 - 1.f);
    int iy1 = (int)fminf(iy0f + 1.f, y2 - 1.f);

    const float* img = x + (long)bt * 64 * 64;
    float v00 = img[iy0 * 64 + ix0], v01 = img[iy0 * 64 + ix1];
    float v10 = img[iy1 * 64 + ix0], v11 = img[iy1 * 64 + ix1];
    float top = (1.f - wx) * v00 + wx * v01;
    float bot = (1.f - wx) * v10 + wx * v11;
    crops[idx] = (1.f - wy) * top + wy * bot;
}

// ---------------- tiny dense matmul ------------------------------------------
__global__ void matmul_small(const float* __restrict__ in, const float* __restrict__ w,
                             float* __restrict__ out, int rows, int Kd, int O)
{
    int idx = blockIdx.x * blockDim.x + threadIdx.x;
    if (idx >= rows * O) return;
    int row = idx / O, o = idx % O;
    float acc = 0.f;
    for (int k = 0; k < Kd; ++k) acc = fmaf(in[(long)row * Kd + k], w[k * O + o], acc);
    out[idx] = acc;
}

// ---------------- GAT attention scalars ---------------------------------------
__global__ void gat_scores(const float* __restrict__ h, const float* __restrict__ a1,
                           const float* __restrict__ a2, float* __restrict__ s1,
                           float* __restrict__ s2, int total, int D)
{
    int idx = blockIdx.x * blockDim.x + threadIdx.x;
    if (idx >= total) return;
    const float* hr = h + (long)idx * D;
    float acc1 = 0.f, acc2 = 0.f;
    for (int k = 0; k < D; ++k) {
        acc1 = fmaf(hr[k], a1[k], acc1);
        acc2 = fmaf(hr[k], a2[k], acc2);
    }
    s1[idx] = acc1; s2[idx] = acc2;
}

// ---------------- GAT masked-softmax aggregate: wave per (b,i) ----------------
template <int D>
__global__ __launch_bounds__(256) void gat_agg2(
    const float* __restrict__ h, const float* __restrict__ s1,
    const float* __restrict__ s2, float* __restrict__ out)
{
    const int wid = (blockIdx.x * 256 + threadIdx.x) >> 6;
    const int lane = threadIdx.x & 63;
    const int b = wid / kN, i = wid % kN;
    const int fri = i / kR, rki = i % kR;
    const float s1i = s1[b * kN + i];

    float ej[4];
    float mx = -1e30f;
#pragma unroll
    for (int t = 0; t < 4; ++t) {
        int j = lane + t * 64;
        if (j < kN) {
            int frj = j / kR, rkj = j % kR;
            int df = fri - frj;
            bool adj = (fri == frj) || ((rki == rkj) && (df == 1 || df == -1));
            float v = s1i + s2[b * kN + j];
            v = v > 0.f ? v : 0.2f * v;
            ej[t] = adj ? v : -9.0e15f;
        } else ej[t] = -1e30f;
        mx = fmaxf(mx, ej[t]);
    }
#pragma unroll
    for (int off = 1; off < 64; off <<= 1)
        mx = fmaxf(mx, __shfl_xor(mx, off, 64));

    float ex[4]; float sum = 0.f;
#pragma unroll
    for (int t = 0; t < 4; ++t) { ex[t] = expf(ej[t] - mx); sum += ex[t]; }
#pragma unroll
    for (int off = 1; off < 64; off <<= 1)
        sum += __shfl_xor(sum, off, 64);

    float part[D];
#pragma unroll
    for (int d = 0; d < D; ++d) part[d] = 0.f;
#pragma unroll
    for (int t = 0; t < 4; ++t) {
        int j = lane + t * 64;
        int jc = j < kN ? j : kN - 1;
        float w = j < kN ? ex[t] : 0.f;
        const float* hr = h + ((long)b * kN + jc) * D;
#pragma unroll
        for (int d = 0; d < D; ++d) part[d] = fmaf(w, hr[d], part[d]);
    }
#pragma unroll
    for (int d = 0; d < D; ++d)
#pragma unroll
        for (int off = 1; off < 64; off <<= 1)
            part[d] += __shfl_xor(part[d], off, 64);

    if (lane < D) {
        float v = part[0];
#pragma unroll
        for (int d = 1; d < D; ++d) v = (lane == d) ? part[d] : v;
        out[((long)b * kN + i) * D + lane] = v / sum;
    }
}

// ---------------- elu + log_softmax (last dim 16) -----------------------------
__global__ void elu_logsoftmax(const float* __restrict__ in, float* __restrict__ out,
                               int rows)
{
    int r = blockIdx.x * blockDim.x + threadIdx.x;
    if (r >= rows) return;
    float v[16];
    float mx = -1e30f;
#pragma unroll
    for (int k = 0; k < 16; ++k) {
        float xv = in[(long)r * 16 + k];
        xv = xv > 0.f ? xv : expm1f(xv);
        v[k] = xv; mx = fmaxf(mx, xv);
    }
    float s = 0.f;
#pragma unroll
    for (int k = 0; k < 16; ++k) s += expf(v[k] - mx);
    float ls = logf(s) + mx;
#pragma unroll
    for (int k = 0; k < 16; ++k) out[(long)r * 16 + k] = v[k] - ls;
}

// ---------------- mean over nodes of concat(l_fc, gat_fc) ---------------------
__global__ void lcat_mean(const float* __restrict__ lfc, const float* __restrict__ gatfc,
                          float* __restrict__ fcbuf)
{
    int idx = blockIdx.x * blockDim.x + threadIdx.x;
    if (idx >= kB * 272) return;
    int b = idx / 272, c = idx % 272;
    float s = 0.f;
    if (c < 256) {
        for (int n2 = 0; n2 < kN; ++n2) s += lfc[((long)b * kN + n2) * 256 + c];
    } else {
        int cc = c - 256;
        for (int n2 = 0; n2 < kN; ++n2) s += gatfc[((long)b * kN + n2) * 16 + cc];
    }
    fcbuf[b * 528 + 256 + c] = s * (1.f / kN);
}

// ---------------- final pyramid ----------------------------------------------
__global__ void final_feats(const float* __restrict__ fcbuf, float* __restrict__ out)
{
    int idx = blockIdx.x * blockDim.x + threadIdx.x;
    if (idx >= kB * 1023) return;
    int b = idx / 1023, m = idx % 1023;
    int nb, seg, off;
    if      (m < 528) { nb = 1;  seg = 528; off = 0;   }
    else if (m < 792) { nb = 2;  seg = 264; off = 528; }
    else if (m < 924) { nb = 4;  seg = 132; off = 792; }
    else if (m < 990) { nb = 8;  seg = 66;  off = 924; }
    else              { nb = 16; seg = 33;  off = 990; }
    int mm = m - off;
    float s = 0.f, mx = -1e30f;
    for (int k2 = 0; k2 < nb; ++k2) {
        float v = fcbuf[b * 528 + k2 * seg + mm];
        s += v; mx = fmaxf(mx, v);
    }
    out[(long)b * 1023 + m] = s / nb + mx;
}

// ---------------------------------------------------------------------------
extern "C" void kernel_launch(void* const* d_in, const int* in_sizes, int n_in,
                              void* d_out, int out_size, void* d_ws, size_t ws_size,
                              hipStream_t stream)
{
    const float* x       = (const float*)d_in[0];
    const float* px      = (const float*)d_in[1];
    const float* cw1     = (const float*)d_in[2];
    const float* cw2     = (const float*)d_in[3];
    const float* cw3     = (const float*)d_in[4];
    const float* cw4     = (const float*)d_in[5];
    const float* cw5     = (const float*)d_in[6];
    const float* cw6     = (const float*)d_in[7];
    const float* fc_g_w  = (const float*)d_in[8];
    const float* fc_g_b  = (const float*)d_in[9];
    const float* fc_l_w  = (const float*)d_in[10];
    const float* fc_l_b  = (const float*)d_in[11];
    const float* gat1_W  = (const float*)d_in[12];
    const float* gat1_a1 = (const float*)d_in[13];
    const float* gat1_a2 = (const float*)d_in[14];
    const float* gat2_W  = (const float*)d_in[15];
    const float* gat2_a1 = (const float*)d_in[16];
    const float* gat2_a2 = (const float*)d_in[17];

    float* ws    = (float*)d_ws;
    float* A     = ws;                      // 31,457,280 floats
    float* Bb    = A + 31457280;            //  7,864,320
    float* crops = Bb + 7864320;            //    376,320
    float* gmaxb = crops + 376320;          //    262,144
    float* lfc   = gmaxb + 262144;          //    491,520
    float* h1    = lfc + 491520;
    float* s1    = h1 + 15360;
    float* s2    = s1 + 1920;
    float* o1    = s2 + 1920;
    float* h2    = o1 + 15360;
    float* s1b   = h2 + 30720;
    float* s2b   = s1b + 1920;
    float* o2    = s2b + 1920;
    float* gatfc = o2 + 30720;
    float* fcbuf = gatfc + 30720;           // 4,224

    short* bp2 = (short*)(fcbuf + 4224);    // 9,216 shorts
    short* bp3 = bp2 + 9216;                // 18,432
    short* bp4 = bp3 + 18432;               // 36,864
    short* bp5 = bp4 + 36864;               // 73,728
    short* bp6 = bp5 + 73728;               // 147,456
    short* wpl = bp6 + 147456;              // 294,912 (fc_l packed, K-permuted)

    auto cdiv = [](long a, long b) { return (int)((a + b - 1) / b); };
    const int TB = 256;

    // ---------------- all weight repacks in one launch ----------------
    repack_all<<<284, 256, 0, stream>>>(cw2, cw3, cw4, cw5, cw6, fc_l_w,
                                        bp2, bp3, bp4, bp5, bp6, wpl);

    // ---------------- global path ----------------
    conv_tile<5, 1, 32, 64, 64, 32, 4, 2, 1><<<3840, 256, 0, stream>>>(x, cw1, A);
    conv_mfma<  32,  32, 64, 64, true,  1><<<3840, 256, 0, stream>>>(A,  bp2, Bb);
    conv_mfma<  32,  64, 32, 32, false, 1><<< 960, 256, 0, stream>>>(Bb, bp3, A);
    conv_mfma<  64,  64, 32, 32, true,  1><<< 960, 256, 0, stream>>>(A,  bp4, Bb);
    conv_mfma<  64, 128, 16, 16, false, 2><<< 480, 256, 0, stream>>>(Bb, bp5, A);
    conv_mfma< 128, 128, 16, 16, false, 2><<< 480, 256, 0, stream>>>(A,  bp6, Bb);
    max_over_T<<<cdiv(8L * 32768, TB), TB, 0, stream>>>(Bb, gmaxb, 8, 30, 32768);
    init_fcg<<<cdiv(2048L, TB), TB, 0, stream>>>(fc_g_b, fcbuf);
    fcg_partial<<<1024, 256, 0, stream>>>(gmaxb, fc_g_w, fcbuf);

    // ---------------- local path (channel-last bf16 chain) ----------------
    roi_crop<<<cdiv(1920L * 196, TB), TB, 0, stream>>>(x, px, crops);
    conv_tile<5, 1, 32, 14, 14, 16, 4, 2, 1><<<1920, 256, 0, stream>>>(crops, cw1, A);
    conv2l_mfma<<<1920, 256, 0, stream>>>(A, bp2, (short*)Bb);
    //        Cin Cout  S  POOL  G NSPLIT          blocks = (1920/G)*NSPLIT
    convl_cl< 32,  64,  7, false, 2, 1><<< 960, 256, 0, stream>>>((short*)Bb, bp3, (short*)A);
    convl_cl< 64,  64,  7, true,  2, 1><<< 960, 256, 0, stream>>>((short*)A,  bp4, (short*)Bb);
    convl_cl< 64, 128,  3, false, 8, 2><<< 480, 256, 0, stream>>>((short*)Bb, bp5, (short*)A);
    convl_cl<128, 128,  3, false, 8, 2><<< 480, 256, 0, stream>>>((short*)A,  bp6, (short*)Bb);
    linear_l_mfma<<<120, 256, 0, stream>>>((short*)Bb, wpl, fc_l_b, lfc);

    // ---------------- GAT ----------------
    matmul_small<<<cdiv(1920L * 8, TB), TB, 0, stream>>>(lfc, gat1_W, h1, kB * kN, 256, 8);
    gat_scores<<<cdiv(1920L, TB), TB, 0, stream>>>(h1, gat1_a1, gat1_a2, s1, s2, kB * kN, 8);
    gat_agg2<8><<<480, 256, 0, stream>>>(h1, s1, s2, o1);
    matmul_small<<<cdiv(1920L * 16, TB), TB, 0, stream>>>(o1, gat2_W, h2, kB * kN, 8, 16);
    gat_scores<<<cdiv(1920L, TB), TB, 0, stream>>>(h2, gat2_a1, gat2_a2, s1b, s2b, kB * kN, 16);
    gat_agg2<16><<<480, 256, 0, stream>>>(h2, s1b, s2b, o2);
    elu_logsoftmax<<<cdiv(1920L, TB), TB, 0, stream>>>(o2, gatfc, kB * kN);

    // ---------------- head ----------------
    lcat_mean<<<cdiv(8L * 272, TB), TB, 0, stream>>>(lfc, gatfc, fcbuf);
    final_feats<<<cdiv(8L * 1023, TB), TB, 0, stream>>>(fcbuf, (float*)d_out);
}

// Round 6
// 717.391 us; speedup vs baseline: 36.5108x; 1.1276x over previous
//
#include <hip/hip_runtime.h>
#include <hip/hip_bf16.h>

// ---------------------------------------------------------------------------
// RGPNet forward. Round 6: channel-last bf16 everywhere (global + local),
// vector-staged MFMA convs, permuting max_over_T.
// ---------------------------------------------------------------------------

constexpr int kB = 8, kT = 30, kR = 8;
constexpr int kN = kT * kR;          // 240 nodes per batch
constexpr int kRH = 14, kRW = 14;

static __device__ __forceinline__ float lrelu01(float v) {
    return v > 0.f ? v : 0.01f * v;
}

typedef __attribute__((ext_vector_type(8))) short bf16x8;
typedef __attribute__((ext_vector_type(4))) float f32x4;

static __device__ __forceinline__ short f2bf(float v) {
    __hip_bfloat16 h = __float2bfloat16(v);
    return *reinterpret_cast<short*>(&h);
}
static __device__ __forceinline__ float bf2f(short s) {
    unsigned u = ((unsigned)(unsigned short)s) << 16;
    return __uint_as_float(u);
}

// ---------------------------------------------------------------------------
// Repack bodies: conv OIHW fp32 -> per-lane B-fragment bf16.
// bp[(((cs*9+kykx)*NFTOT + nf)*64 + lane)*8 + j]
//   = W[nf*16+(lane&15)][cs*32+(lane>>4)*8+j][ky][kx]
// ---------------------------------------------------------------------------
template <int Cin, int Cout>
static __device__ void repack_w_body(const float* __restrict__ w,
                                     short* __restrict__ bp, int t)
{
    constexpr int NFTOT = Cout / 16;
    int lane = t & 63, rest = t >> 6;
    int nf = rest % NFTOT; rest /= NFTOT;
    int kykx = rest % 9; int cs = rest / 9;
    int co  = nf * 16 + (lane & 15);
    int cib = cs * 32 + (lane >> 4) * 8;
#pragma unroll
    for (int j = 0; j < 8; ++j) {
        float v = w[((long)co * Cin + cib + j) * 9 + kykx];
        bp[(long)t * 8 + j] = f2bf(v);
    }
}

// fc_l repack with K-permutation for channel-last input: k = s*128 + c,
// original column = c*9 + s.
static __device__ void repack_dense_body(const float* __restrict__ w,
                                         short* __restrict__ wp, int t)
{
    constexpr int KD = 1152;
    int lane = t & 63, rest = t >> 6;
    int nf = rest % 16; int kc = rest / 16;
    int co = nf * 16 + (lane & 15);
    int k0 = kc * 32 + (lane >> 4) * 8;
#pragma unroll
    for (int j = 0; j < 8; ++j) {
        int k = k0 + j;
        int korig = (k & 127) * 9 + (k >> 7);
        wp[(long)t * 8 + j] = f2bf(w[(long)co * KD + korig]);
    }
}

__global__ __launch_bounds__(256) void repack_all(
    const float* cw2, const float* cw3, const float* cw4,
    const float* cw5, const float* cw6, const float* fclw,
    short* bp2, short* bp3, short* bp4, short* bp5, short* bp6, short* wpl)
{
    int t = blockIdx.x * 256 + threadIdx.x;
    if      (t < 1152)                repack_w_body< 32,  32>(cw2, bp2, t);
    else if (t < 1152 + 2304)         repack_w_body< 32,  64>(cw3, bp3, t - 1152);
    else if (t < 3456 + 4608)         repack_w_body< 64,  64>(cw4, bp4, t - 3456);
    else if (t < 8064 + 9216)         repack_w_body< 64, 128>(cw5, bp5, t - 8064);
    else if (t < 17280 + 18432)       repack_w_body<128, 128>(cw6, bp6, t - 17280);
    else if (t < 35712 + 36864)       repack_dense_body(fclw, wpl, t - 35712);
}

// ---------------------------------------------------------------------------
// Global-path MFMA conv, channel-last bf16 in/out. Block = 16x16 spatial tile
// of one image (x NSPLIT co-splits). Vector-staged 18x18 halo slab.
// ---------------------------------------------------------------------------
template <int Cin, int Cout, int H, int W, bool POOL, int NSPLIT>
__global__ __launch_bounds__(256) void convg_cl(
    const short* __restrict__ in, const short* __restrict__ bp,
    short* __restrict__ out)
{
    constexpr int NFTOT = Cout / 16;
    constexpr int NF    = NFTOT / NSPLIT;
    constexpr int CS    = Cin / 32;
    constexpr int TX    = W / 16, TY = H / 16;
    constexpr int CP    = 40;
    constexpr int Ho    = POOL ? H / 2 : H, Wo = POOL ? W / 2 : W;

    __shared__ __align__(16) short slab[18 * 18 * CP];   // 25.9 KB

    int bid = blockIdx.x;
    const int split = bid % NSPLIT; bid /= NSPLIT;
    const int txt = bid % TX; bid /= TX;
    const int tyt = bid % TY; bid /= TY;
    const int n   = bid;
    const int x0 = txt * 16, y0 = tyt * 16;
    const int nf0 = split * NF;

    const int tid = threadIdx.x;
    const int lane = tid & 63, wav = tid >> 6;
    const int mrow0 = wav * 4;
    const int lx = lane & 15, lg = lane >> 4;

    f32x4 acc[4][NF];
#pragma unroll
    for (int r = 0; r < 4; ++r)
#pragma unroll
        for (int f = 0; f < NF; ++f) acc[r][f] = (f32x4)0.f;

    for (int cs = 0; cs < CS; ++cs) {
        // ---- vector stage: [y][x][ci] bf16, conditional zero for halo ----
        for (int i = tid; i < 324 * 4; i += 256) {
            int pos = i >> 2, c8 = i & 3;
            int yy = pos / 18, xx = pos % 18;
            int gy = y0 - 1 + yy, gx = x0 - 1 + xx;
            bf16x8 v = (bf16x8)(short)0;
            if ((unsigned)gy < (unsigned)H && (unsigned)gx < (unsigned)W)
                v = *(const bf16x8*)&in[(((long)n * H + gy) * W + gx) * Cin + cs * 32 + c8 * 8];
            *(bf16x8*)&slab[pos * CP + c8 * 8] = v;
        }
        __syncthreads();

#pragma unroll
        for (int ky = 0; ky < 3; ++ky)
#pragma unroll
        for (int kx = 0; kx < 3; ++kx) {
            bf16x8 a[4];
#pragma unroll
            for (int r = 0; r < 4; ++r)
                a[r] = *(const bf16x8*)&slab[((mrow0 + r + ky) * 18 + lx + kx) * CP + lg * 8];
            const int kykx = ky * 3 + kx;
#pragma unroll
            for (int f = 0; f < NF; ++f) {
                bf16x8 b = *(const bf16x8*)&bp[(((long)(cs * 9 + kykx) * NFTOT + nf0 + f) * 64 + lane) * 8];
#pragma unroll
                for (int r = 0; r < 4; ++r)
                    acc[r][f] = __builtin_amdgcn_mfma_f32_16x16x32_bf16(a[r], b, acc[r][f], 0, 0, 0);
            }
        }
        __syncthreads();
    }

    // ---- epilogue: row M = tx-in-tile = lg*4+reg, col N = co ----
    if constexpr (!POOL) {
#pragma unroll
        for (int f = 0; f < NF; ++f) {
            int co = (nf0 + f) * 16 + lx;
#pragma unroll
            for (int r = 0; r < 4; ++r) {
                int y = y0 + mrow0 + r;
#pragma unroll
                for (int reg = 0; reg < 4; ++reg) {
                    int x = x0 + lg * 4 + reg;
                    out[((long)n * H * W + y * W + x) * Cout + co] = f2bf(lrelu01(acc[r][f][reg]));
                }
            }
        }
    } else {
#pragma unroll
        for (int f = 0; f < NF; ++f) {
            int co = (nf0 + f) * 16 + lx;
#pragma unroll
            for (int q = 0; q < 2; ++q) {
                int yp = (y0 >> 1) + wav * 2 + q;
                float m0 = fmaxf(fmaxf(lrelu01(acc[2*q][f][0]), lrelu01(acc[2*q][f][1])),
                                 fmaxf(lrelu01(acc[2*q+1][f][0]), lrelu01(acc[2*q+1][f][1])));
                float m1 = fmaxf(fmaxf(lrelu01(acc[2*q][f][2]), lrelu01(acc[2*q][f][3])),
                                 fmaxf(lrelu01(acc[2*q+1][f][2]), lrelu01(acc[2*q+1][f][3])));
                int xp0 = (x0 >> 1) + lg * 2;
                long base = (long)n * Ho * Wo + yp * Wo;
                out[(base + xp0) * Cout + co]     = f2bf(m0);
                out[(base + xp0 + 1) * Cout + co] = f2bf(m1);
            }
        }
    }
}

// ---------------------------------------------------------------------------
// Local conv2: channel-last bf16 [n][196][32] input -> pool -> [n][49][32].
// One image per block; M = x; y = wav*4+r. Slab 16x16 incl. halo.
// ---------------------------------------------------------------------------
__global__ __launch_bounds__(256) void conv2l_mfma(
    const short* __restrict__ in, const short* __restrict__ bp,
    short* __restrict__ out)
{
    constexpr int CP = 40;
    __shared__ __align__(16) short slab[16 * 16 * CP];
    const int n = blockIdx.x;
    const int tid = threadIdx.x;
    const int lane = tid & 63, wav = tid >> 6;
    const int lx = lane & 15, lg = lane >> 4;

    for (int i = tid; i < 256 * 4; i += 256) {
        int pos = i >> 2, c8 = i & 3;
        int yy = pos >> 4, xx = pos & 15;
        int gy = yy - 1, gx = xx - 1;
        bf16x8 v = (bf16x8)(short)0;
        if ((unsigned)gy < 14u && (unsigned)gx < 14u)
            v = *(const bf16x8*)&in[((long)n * 196 + gy * 14 + gx) * 32 + c8 * 8];
        *(bf16x8*)&slab[pos * CP + c8 * 8] = v;
    }
    __syncthreads();

    f32x4 acc[4][2];
#pragma unroll
    for (int r = 0; r < 4; ++r)
#pragma unroll
        for (int f = 0; f < 2; ++f) acc[r][f] = (f32x4)0.f;

#pragma unroll
    for (int ky = 0; ky < 3; ++ky)
#pragma unroll
    for (int kx = 0; kx < 3; ++kx) {
        bf16x8 a[4];
        int xcl = min(lx + kx, 15);
#pragma unroll
        for (int r = 0; r < 4; ++r) {
            int ycl = min(wav * 4 + r + ky, 15);
            a[r] = *(const bf16x8*)&slab[(ycl * 16 + xcl) * CP + lg * 8];
        }
        const int kykx = ky * 3 + kx;
#pragma unroll
        for (int f = 0; f < 2; ++f) {
            bf16x8 b = *(const bf16x8*)&bp[(((long)kykx * 2 + f) * 64 + lane) * 8];
#pragma unroll
            for (int r = 0; r < 4; ++r)
                acc[r][f] = __builtin_amdgcn_mfma_f32_16x16x32_bf16(a[r], b, acc[r][f], 0, 0, 0);
        }
    }

#pragma unroll
    for (int f = 0; f < 2; ++f) {
        int co = f * 16 + lx;
#pragma unroll
        for (int q = 0; q < 2; ++q) {
            int yp = wav * 2 + q;
            if (yp >= 7) continue;
            float m0 = fmaxf(fmaxf(lrelu01(acc[2*q][f][0]), lrelu01(acc[2*q][f][1])),
                             fmaxf(lrelu01(acc[2*q+1][f][0]), lrelu01(acc[2*q+1][f][1])));
            float m1 = fmaxf(fmaxf(lrelu01(acc[2*q][f][2]), lrelu01(acc[2*q][f][3])),
                             fmaxf(lrelu01(acc[2*q+1][f][2]), lrelu01(acc[2*q+1][f][3])));
            int xp0 = lg * 2;
            out[((long)n * 49 + yp * 7 + xp0) * 32 + co] = f2bf(m0);
            if (xp0 + 1 < 7)
                out[((long)n * 49 + yp * 7 + xp0 + 1) * 32 + co] = f2bf(m1);
        }
    }
}

// ---------------------------------------------------------------------------
// Unified channel-last local conv (conv3l..conv6l), unchanged from round 5.
// ---------------------------------------------------------------------------
template <int Cin, int Cout, int S, bool POOL, int G, int NSPLIT>
__global__ __launch_bounds__(256) void convl_cl(
    const short* __restrict__ in, const short* __restrict__ bp,
    short* __restrict__ out)
{
    constexpr int SS    = S * S;
    constexpr int M     = G * SS;
    constexpr int MT    = (M + 15) / 16;
    constexpr int TPW   = (MT + 3) / 4;
    constexpr int CPAD  = Cin + 8;
    constexpr int NFTOT = Cout / 16;
    constexpr int NF    = NFTOT / NSPLIT;
    constexpr int CS    = Cin / 32;
    constexpr int So    = S / 2;

    __shared__ __align__(16) short slab[(1 + M) * CPAD];

    const int bid   = blockIdx.x;
    const int split = bid % NSPLIT;
    const int n0    = (bid / NSPLIT) * G;
    const int nf0   = split * NF;
    const int tid   = threadIdx.x;
    const int lane  = tid & 63, wav = tid >> 6;
    const int lx    = lane & 15, lg = lane >> 4;

    for (int i = tid; i < CPAD / 8; i += 256)
        *(bf16x8*)&slab[i * 8] = (bf16x8)(short)0;
    const short* src = in + (long)n0 * SS * Cin;
    for (int i = tid; i < M * (Cin / 8); i += 256) {
        int gs = i / (Cin / 8), c8 = i % (Cin / 8);
        *(bf16x8*)&slab[(1 + gs) * CPAD + c8 * 8] = *(const bf16x8*)&src[(long)i * 8];
    }
    __syncthreads();

    int aoff[TPW][9];
#pragma unroll
    for (int i = 0; i < TPW; ++i) {
        int mt = wav + i * 4;
        int m = mt * 16 + lx;
        if (mt >= MT || m > M - 1) m = M - 1;
        int g = m / SS, s = m % SS, y = s / S, x = s % S;
#pragma unroll
        for (int ky = 0; ky < 3; ++ky)
#pragma unroll
        for (int kx = 0; kx < 3; ++kx) {
            int iy = y + ky - 1, ix = x + kx - 1;
            bool ok = (unsigned)iy < (unsigned)S && (unsigned)ix < (unsigned)S;
            aoff[i][ky * 3 + kx] = (ok ? (1 + g * SS + iy * S + ix) : 0) * CPAD + lg * 8;
        }
    }

    f32x4 acc[TPW][NF];
#pragma unroll
    for (int i = 0; i < TPW; ++i)
#pragma unroll
        for (int f = 0; f < NF; ++f) acc[i][f] = (f32x4)0.f;

    for (int cs = 0; cs < CS; ++cs) {
#pragma unroll
        for (int kk = 0; kk < 9; ++kk) {
            bf16x8 a[TPW];
#pragma unroll
            for (int i = 0; i < TPW; ++i)
                a[i] = *(const bf16x8*)&slab[aoff[i][kk] + cs * 32];
#pragma unroll
            for (int f = 0; f < NF; ++f) {
                bf16x8 b = *(const bf16x8*)&bp[(((long)(cs * 9 + kk) * NFTOT + nf0 + f) * 64 + lane) * 8];
#pragma unroll
                for (int i = 0; i < TPW; ++i)
                    acc[i][f] = __builtin_amdgcn_mfma_f32_16x16x32_bf16(a[i], b, acc[i][f], 0, 0, 0);
            }
        }
    }

    if constexpr (!POOL) {
#pragma unroll
        for (int i = 0; i < TPW; ++i) {
            int mt = wav + i * 4;
            if (mt >= MT) continue;
#pragma unroll
            for (int f = 0; f < NF; ++f) {
                int co = (nf0 + f) * 16 + lx;
#pragma unroll
                for (int r = 0; r < 4; ++r) {
                    int m = mt * 16 + lg * 4 + r;
                    if (m >= M) continue;
                    int g = m / SS, s = m % SS;
                    out[((long)(n0 + g) * SS + s) * Cout + co] = f2bf(lrelu01(acc[i][f][r]));
                }
            }
        }
    } else {
        constexpr int CPO = Cout + 8;
        static_assert((long)M * CPO <= (long)(1 + M) * CPAD, "pool lds");
        __syncthreads();
#pragma unroll
        for (int i = 0; i < TPW; ++i) {
            int mt = wav + i * 4;
            if (mt >= MT) continue;
#pragma unroll
            for (int f = 0; f < NF; ++f) {
                int co = (nf0 + f) * 16 + lx;
#pragma unroll
                for (int r = 0; r < 4; ++r) {
                    int m = mt * 16 + lg * 4 + r;
                    if (m >= M) continue;
                    slab[m * CPO + co] = f2bf(lrelu01(acc[i][f][r]));
                }
            }
        }
        __syncthreads();
        for (int o = tid; o < G * So * So * Cout; o += 256) {
            int c = o % Cout; int rest = o / Cout;
            int xp = rest % So; rest /= So;
            int yp = rest % So; int g = rest / So;
            int base = (g * SS + 2 * yp * S + 2 * xp) * CPO + c;
            float v0 = bf2f(slab[base]);
            float v1 = bf2f(slab[base + CPO]);
            float v2 = bf2f(slab[base + S * CPO]);
            float v3 = bf2f(slab[base + (S + 1) * CPO]);
            float mv = fmaxf(fmaxf(v0, v1), fmaxf(v2, v3));
            out[((long)(n0 + g) * So * So + yp * So + xp) * Cout + c] = f2bf(mv);
        }
    }
}

// ---------------------------------------------------------------------------
// fc_l as MFMA GEMM, bf16 channel-last input [1920][1152].
// ---------------------------------------------------------------------------
__global__ __launch_bounds__(256) void linear_l_mfma(
    const short* __restrict__ in, const short* __restrict__ wp,
    const float* __restrict__ bias, float* __restrict__ out)
{
    constexpr int KD = 1152, LDK = KD + 8;
    __shared__ __align__(16) short slab[16 * LDK];
    const int m0 = blockIdx.x * 16;
    const int tid = threadIdx.x;
    const int lane = tid & 63, wav = tid >> 6;
    const int lx = lane & 15, lg = lane >> 4;

    for (int i = tid; i < 16 * (KD / 8); i += 256) {
        int r = i / (KD / 8), c8 = i % (KD / 8);
        *(bf16x8*)&slab[r * LDK + c8 * 8] = *(const bf16x8*)&in[(long)(m0 + r) * KD + c8 * 8];
    }
    __syncthreads();

    f32x4 acc[4];
#pragma unroll
    for (int f = 0; f < 4; ++f) acc[f] = (f32x4)0.f;

    for (int kc = 0; kc < KD / 32; ++kc) {
        bf16x8 a = *(const bf16x8*)&slab[lx * LDK + kc * 32 + lg * 8];
#pragma unroll
        for (int f = 0; f < 4; ++f) {
            int nf = wav * 4 + f;
            bf16x8 b = *(const bf16x8*)&wp[(((long)kc * 16 + nf) * 64 + lane) * 8];
            acc[f] = __builtin_amdgcn_mfma_f32_16x16x32_bf16(a, b, acc[f], 0, 0, 0);
        }
    }

#pragma unroll
    for (int f = 0; f < 4; ++f) {
        int co = (wav * 4 + f) * 16 + lx;
        float bv = bias[co];
#pragma unroll
        for (int reg = 0; reg < 4; ++reg) {
            int m = m0 + lg * 4 + reg;
            out[(long)m * 256 + co] = acc[f][reg] + bv;
        }
    }
}

// ---------------------------------------------------------------------------
// max over T, channel-last bf16 input -> fp32 output in ORIGINAL NCHW order.
// ---------------------------------------------------------------------------
__global__ void max_over_T_cl(const short* __restrict__ in, float* __restrict__ out)
{
    int idx = blockIdx.x * blockDim.x + threadIdx.x;
    if (idx >= 8 * 4096) return;
    int b = idx >> 12, k8 = idx & 4095;
    float m[8];
#pragma unroll
    for (int j = 0; j < 8; ++j) m[j] = -1e30f;
    for (int t = 0; t < 30; ++t) {
        bf16x8 v = *(const bf16x8*)&in[(((long)(b * 30 + t)) << 15) + k8 * 8];
#pragma unroll
        for (int j = 0; j < 8; ++j) m[j] = fmaxf(m[j], bf2f(v[j]));
    }
    int kcl0 = k8 * 8;
    int s = kcl0 >> 7, c0 = kcl0 & 127;
#pragma unroll
    for (int j = 0; j < 8; ++j)
        out[b * 32768 + (c0 + j) * 256 + s] = m[j];
}

// ---------------------------------------------------------------------------
// fc_g: split-K, weights read once, all 8 batch rows per wave, atomicAdd.
// ---------------------------------------------------------------------------
__global__ void init_fcg(const float* __restrict__ bias, float* __restrict__ fcbuf)
{
    int idx = blockIdx.x * blockDim.x + threadIdx.x;
    if (idx >= 8 * 256) return;
    fcbuf[(idx >> 8) * 528 + (idx & 255)] = bias[idx & 255];
}

__global__ __launch_bounds__(256) void fcg_partial(
    const float* __restrict__ in, const float* __restrict__ w,
    float* __restrict__ fcbuf)
{
    const int gid = blockIdx.x * 256 + threadIdx.x;
    const int wid = gid >> 6, lane = gid & 63;
    const int o = wid >> 4, kc = wid & 15;
    const int k0 = kc * 2048;

    float acc[8];
#pragma unroll
    for (int m = 0; m < 8; ++m) acc[m] = 0.f;

    for (int it = 0; it < 8; ++it) {
        int k = k0 + it * 256 + lane * 4;
        float4 wv = *(const float4*)&w[(long)o * 32768 + k];
#pragma unroll
        for (int m = 0; m < 8; ++m) {
            float4 xv = *(const float4*)&in[(long)m * 32768 + k];
            acc[m] = fmaf(xv.x, wv.x, acc[m]);
            acc[m] = fmaf(xv.y, wv.y, acc[m]);
            acc[m] = fmaf(xv.z, wv.z, acc[m]);
            acc[m] = fmaf(xv.w, wv.w, acc[m]);
        }
    }
#pragma unroll
    for (int off = 32; off > 0; off >>= 1)
#pragma unroll
        for (int m = 0; m < 8; ++m)
            acc[m] += __shfl_down(acc[m], off, 64);
    if (lane == 0) {
#pragma unroll
        for (int m = 0; m < 8; ++m)
            atomicAdd(&fcbuf[m * 528 + o], acc[m]);
    }
}

// ---------------------------------------------------------------------------
// Tiled fp32 conv1 (Cin=1, K=5), fp32 NCHW in -> channel-last bf16 out.
// ---------------------------------------------------------------------------
template <int K, int Cin, int Cout, int H, int W,
          int TILE, int PT, int CO_T, int CIC>
__global__ __launch_bounds__(256) void conv_tile(
    const float* __restrict__ in, const float* __restrict__ wgt,
    short* __restrict__ out)
{
    constexpr int P   = K / 2;
    constexpr int NT  = (H + TILE - 1) / TILE;
    constexpr int SP  = TILE / PT;
    constexpr int SPT = SP * SP;
    constexpr int COS = 256 / SPT;
    constexpr int COB = COS * CO_T;
    constexpr int CG  = Cout / COB;
    constexpr int SW  = TILE + 2 * P;
    constexpr int RS  = (SW + 3) & ~3;
    constexpr int KK  = K * K;
    constexpr int WS  = CIC * KK + 1;
    constexpr int XW  = PT + 2 * P;

    __shared__ __align__(16) float slab[CIC * SW * RS];
    __shared__ __align__(16) float wl[COB * WS];

    int bid = blockIdx.x;
    const int cg = bid % CG; bid /= CG;
    const int tx = bid % NT; bid /= NT;
    const int ty = bid % NT;
    const int n  = bid / NT;
    const int x0 = tx * TILE, y0 = ty * TILE;
    const int co0 = cg * COB;

    const int tid  = threadIdx.x;
    const int sidx = tid % SPT, ssub = tid / SPT;
    const int px0  = (sidx % SP) * PT, py0 = (sidx / SP) * PT;

    float acc[CO_T][PT][PT];
#pragma unroll
    for (int c = 0; c < CO_T; ++c)
#pragma unroll
        for (int a = 0; a < PT; ++a)
#pragma unroll
            for (int b2 = 0; b2 < PT; ++b2) acc[c][a][b2] = 0.f;

    for (int cs = 0; cs < Cin; cs += CIC) {
        for (int i = tid; i < CIC * SW * SW; i += 256) {
            int ci = i / (SW * SW); int r = i % (SW * SW);
            int yy = r / SW, xx = r % SW;
            int gy = y0 + yy - P, gx = x0 + xx - P;
            float v = 0.f;
            if ((unsigned)gy < (unsigned)H && (unsigned)gx < (unsigned)W)
                v = in[(((long)n * Cin + cs + ci) * H + gy) * W + gx];
            slab[(ci * SW + yy) * RS + xx] = v;
        }
        for (int i = tid; i < COB * CIC * KK; i += 256) {
            int col = i / (CIC * KK); int r = i % (CIC * KK);
            wl[col * WS + r] = wgt[(((long)(co0 + col)) * Cin + cs) * KK + r];
        }
        __syncthreads();

        for (int ci = 0; ci < CIC; ++ci) {
            float xr[XW][XW];
#pragma unroll
            for (int yy = 0; yy < XW; ++yy) {
                int xb = (ci * SW + py0 + yy) * RS + px0;
                if constexpr (PT == 4 && K == 5) {
                    float4 a4 = *(const float4*)&slab[xb];
                    float4 b4 = *(const float4*)&slab[xb + 4];
                    xr[yy][0]=a4.x; xr[yy][1]=a4.y; xr[yy][2]=a4.z; xr[yy][3]=a4.w;
                    xr[yy][4]=b4.x; xr[yy][5]=b4.y; xr[yy][6]=b4.z; xr[yy][7]=b4.w;
                } else {
#pragma unroll
                    for (int xx = 0; xx < XW; ++xx) xr[yy][xx] = slab[xb + xx];
                }
            }
            float wr[CO_T][KK];
#pragma unroll
            for (int c = 0; c < CO_T; ++c)
#pragma unroll
                for (int k = 0; k < KK; ++k)
                    wr[c][k] = wl[(ssub * CO_T + c) * WS + ci * KK + k];
#pragma unroll
            for (int c = 0; c < CO_T; ++c)
#pragma unroll
                for (int oy = 0; oy < PT; ++oy)
#pragma unroll
                    for (int ox = 0; ox < PT; ++ox) {
                        float a = acc[c][oy][ox];
#pragma unroll
                        for (int ky = 0; ky < K; ++ky)
#pragma unroll
                            for (int kx = 0; kx < K; ++kx)
                                a = fmaf(xr[oy + ky][ox + kx], wr[c][ky * K + kx], a);
                        acc[c][oy][ox] = a;
                    }
        }
        __syncthreads();
    }

#pragma unroll
    for (int c = 0; c < CO_T; ++c) {
        int co = co0 + ssub * CO_T + c;
#pragma unroll
        for (int oy = 0; oy < PT; ++oy) {
            int y = y0 + py0 + oy;
            if (y >= H) continue;
#pragma unroll
            for (int ox = 0; ox < PT; ++ox) {
                int x = x0 + px0 + ox;
                if (x >= W) continue;
                out[((long)n * H * W + y * W + x) * Cout + co] = f2bf(lrelu01(acc[c][oy][ox]));
            }
        }
    }
}

// ---------------- ROI crop + bilinear resize ----------------------------------
__global__ void roi_crop(const float* __restrict__ x, const float* __restrict__ px,
                         float* __restrict__ crops)
{
    int idx = blockIdx.x * blockDim.x + threadIdx.x;
    const int total = kB * kT * kR * kRH * kRW;
    if (idx >= total) return;
    int j  = idx % kRW; int t2 = idx / kRW;
    int i  = t2 % kRH;  t2 /= kRH;
    int r  = t2 % kR;   int bt = t2 / kR;

    float cx = px[(bt * kR + r) * 2 + 0];
    float cy = px[(bt * kR + r) * 2 + 1];
    float x1 = floorf(fminf(fmaxf(cx - 7.f, 0.f), 63.f));
    float x2 = floorf(fminf(cx + 7.f, 64.f));
    float y1 = floorf(fminf(fmaxf(cy - 7.f, 0.f), 63.f));
    float y2 = floorf(fminf(cy + 7.f, 64.f));

    float sx = x1 + (j + 0.5f) * (x2 - x1) * (1.f / 14.f) - 0.5f;
    sx = fminf(fmaxf(sx, x1), x2 - 1.f);
    float sy = y1 + (i + 0.5f) * (y2 - y1) * (1.f / 14.f) - 0.5f;
    sy = fminf(fmaxf(sy, y1), y2 - 1.f);

    float ix0f = floorf(sx), iy0f = floorf(sy);
    float wx = sx - ix0f,    wy = sy - iy0f;
    int ix0 = (int)ix0f,     iy0 = (int)iy0f;
    int ix1 = (int)fminf(ix0f + 1.f, x2 - 1.f);
    int iy1 = (int)fminf(iy0f + 1.f, y2 - 1.f);

    const float* img = x + (long)bt * 64 * 64;
    float v00 = img[iy0 * 64 + ix0], v01 = img[iy0 * 64 + ix1];
    float v10 = img[iy1 * 64 + ix0], v11 = img[iy1 * 64 + ix1];
    float top = (1.f - wx) * v00 + wx * v01;
    float bot = (1.f - wx) * v10 + wx * v11;
    crops[idx] = (1.f - wy) * top + wy * bot;
}

// ---------------- tiny dense matmul ------------------------------------------
__global__ void matmul_small(const float* __restrict__ in, const float* __restrict__ w,
                             float* __restrict__ out, int rows, int Kd, int O)
{
    int idx = blockIdx.x * blockDim.x + threadIdx.x;
    if (idx >= rows * O) return;
    int row = idx / O, o = idx % O;
    float acc = 0.f;
    for (int k = 0; k < Kd; ++k) acc = fmaf(in[(long)row * Kd + k], w[k * O + o], acc);
    out[idx] = acc;
}

// ---------------- GAT attention scalars ---------------------------------------
__global__ void gat_scores(const float* __restrict__ h, const float* __restrict__ a1,
                           const float* __restrict__ a2, float* __restrict__ s1,
                           float* __restrict__ s2, int total, int D)
{
    int idx = blockIdx.x * blockDim.x + threadIdx.x;
    if (idx >= total) return;
    const float* hr = h + (long)idx * D;
    float acc1 = 0.f, acc2 = 0.f;
    for (int k = 0; k < D; ++k) {
        acc1 = fmaf(hr[k], a1[k], acc1);
        acc2 = fmaf(hr[k], a2[k], acc2);
    }
    s1[idx] = acc1; s2[idx] = acc2;
}

// ---------------- GAT masked-softmax aggregate: wave per (b,i) ----------------
template <int D>
__global__ __launch_bounds__(256) void gat_agg2(
    const float* __restrict__ h, const float* __restrict__ s1,
    const float* __restrict__ s2, float* __restrict__ out)
{
    const int wid = (blockIdx.x * 256 + threadIdx.x) >> 6;
    const int lane = threadIdx.x & 63;
    const int b = wid / kN, i = wid % kN;
    const int fri = i / kR, rki = i % kR;
    const float s1i = s1[b * kN + i];

    float ej[4];
    float mx = -1e30f;
#pragma unroll
    for (int t = 0; t < 4; ++t) {
        int j = lane + t * 64;
        if (j < kN) {
            int frj = j / kR, rkj = j % kR;
            int df = fri - frj;
            bool adj = (fri == frj) || ((rki == rkj) && (df == 1 || df == -1));
            float v = s1i + s2[b * kN + j];
            v = v > 0.f ? v : 0.2f * v;
            ej[t] = adj ? v : -9.0e15f;
        } else ej[t] = -1e30f;
        mx = fmaxf(mx, ej[t]);
    }
#pragma unroll
    for (int off = 1; off < 64; off <<= 1)
        mx = fmaxf(mx, __shfl_xor(mx, off, 64));

    float ex[4]; float sum = 0.f;
#pragma unroll
    for (int t = 0; t < 4; ++t) { ex[t] = expf(ej[t] - mx); sum += ex[t]; }
#pragma unroll
    for (int off = 1; off < 64; off <<= 1)
        sum += __shfl_xor(sum, off, 64);

    float part[D];
#pragma unroll
    for (int d = 0; d < D; ++d) part[d] = 0.f;
#pragma unroll
    for (int t = 0; t < 4; ++t) {
        int j = lane + t * 64;
        int jc = j < kN ? j : kN - 1;
        float w = j < kN ? ex[t] : 0.f;
        const float* hr = h + ((long)b * kN + jc) * D;
#pragma unroll
        for (int d = 0; d < D; ++d) part[d] = fmaf(w, hr[d], part[d]);
    }
#pragma unroll
    for (int d = 0; d < D; ++d)
#pragma unroll
        for (int off = 1; off < 64; off <<= 1)
            part[d] += __shfl_xor(part[d], off, 64);

    if (lane < D) {
        float v = part[0];
#pragma unroll
        for (int d = 1; d < D; ++d) v = (lane == d) ? part[d] : v;
        out[((long)b * kN + i) * D + lane] = v / sum;
    }
}

// ---------------- elu + log_softmax (last dim 16) -----------------------------
__global__ void elu_logsoftmax(const float* __restrict__ in, float* __restrict__ out,
                               int rows)
{
    int r = blockIdx.x * blockDim.x + threadIdx.x;
    if (r >= rows) return;
    float v[16];
    float mx = -1e30f;
#pragma unroll
    for (int k = 0; k < 16; ++k) {
        float xv = in[(long)r * 16 + k];
        xv = xv > 0.f ? xv : expm1f(xv);
        v[k] = xv; mx = fmaxf(mx, xv);
    }
    float s = 0.f;
#pragma unroll
    for (int k = 0; k < 16; ++k) s += expf(v[k] - mx);
    float ls = logf(s) + mx;
#pragma unroll
    for (int k = 0; k < 16; ++k) out[(long)r * 16 + k] = v[k] - ls;
}

// ---------------- mean over nodes of concat(l_fc, gat_fc) ---------------------
__global__ void lcat_mean(const float* __restrict__ lfc, const float* __restrict__ gatfc,
                          float* __restrict__ fcbuf)
{
    int idx = blockIdx.x * blockDim.x + threadIdx.x;
    if (idx >= kB * 272) return;
    int b = idx / 272, c = idx % 272;
    float s = 0.f;
    if (c < 256) {
        for (int n2 = 0; n2 < kN; ++n2) s += lfc[((long)b * kN + n2) * 256 + c];
    } else {
        int cc = c - 256;
        for (int n2 = 0; n2 < kN; ++n2) s += gatfc[((long)b * kN + n2) * 16 + cc];
    }
    fcbuf[b * 528 + 256 + c] = s * (1.f / kN);
}

// ---------------- final pyramid ----------------------------------------------
__global__ void final_feats(const float* __restrict__ fcbuf, float* __restrict__ out)
{
    int idx = blockIdx.x * blockDim.x + threadIdx.x;
    if (idx >= kB * 1023) return;
    int b = idx / 1023, m = idx % 1023;
    int nb, seg, off;
    if      (m < 528) { nb = 1;  seg = 528; off = 0;   }
    else if (m < 792) { nb = 2;  seg = 264; off = 528; }
    else if (m < 924) { nb = 4;  seg = 132; off = 792; }
    else if (m < 990) { nb = 8;  seg = 66;  off = 924; }
    else              { nb = 16; seg = 33;  off = 990; }
    int mm = m - off;
    float s = 0.f, mx = -1e30f;
    for (int k2 = 0; k2 < nb; ++k2) {
        float v = fcbuf[b * 528 + k2 * seg + mm];
        s += v; mx = fmaxf(mx, v);
    }
    out[(long)b * 1023 + m] = s / nb + mx;
}

// ---------------------------------------------------------------------------
extern "C" void kernel_launch(void* const* d_in, const int* in_sizes, int n_in,
                              void* d_out, int out_size, void* d_ws, size_t ws_size,
                              hipStream_t stream)
{
    const float* x       = (const float*)d_in[0];
    const float* px      = (const float*)d_in[1];
    const float* cw1     = (const float*)d_in[2];
    const float* cw2     = (const float*)d_in[3];
    const float* cw3     = (const float*)d_in[4];
    const float* cw4     = (const float*)d_in[5];
    const float* cw5     = (const float*)d_in[6];
    const float* cw6     = (const float*)d_in[7];
    const float* fc_g_w  = (const float*)d_in[8];
    const float* fc_g_b  = (const float*)d_in[9];
    const float* fc_l_w  = (const float*)d_in[10];
    const float* fc_l_b  = (const float*)d_in[11];
    const float* gat1_W  = (const float*)d_in[12];
    const float* gat1_a1 = (const float*)d_in[13];
    const float* gat1_a2 = (const float*)d_in[14];
    const float* gat2_W  = (const float*)d_in[15];
    const float* gat2_a1 = (const float*)d_in[16];
    const float* gat2_a2 = (const float*)d_in[17];

    float* ws    = (float*)d_ws;
    float* A     = ws;                      // 31,457,280 floats
    float* Bb    = A + 31457280;            //  7,864,320
    float* crops = Bb + 7864320;            //    376,320
    float* gmaxb = crops + 376320;          //    262,144
    float* lfc   = gmaxb + 262144;          //    491,520
    float* h1    = lfc + 491520;
    float* s1    = h1 + 15360;
    float* s2    = s1 + 1920;
    float* o1    = s2 + 1920;
    float* h2    = o1 + 15360;
    float* s1b   = h2 + 30720;
    float* s2b   = s1b + 1920;
    float* o2    = s2b + 1920;
    float* gatfc = o2 + 30720;
    float* fcbuf = gatfc + 30720;           // 4,224

    short* bp2 = (short*)(fcbuf + 4224);    // 9,216 shorts
    short* bp3 = bp2 + 9216;                // 18,432
    short* bp4 = bp3 + 18432;               // 36,864
    short* bp5 = bp4 + 36864;               // 73,728
    short* bp6 = bp5 + 73728;               // 147,456
    short* wpl = bp6 + 147456;              // 294,912 (fc_l packed, K-permuted)

    auto cdiv = [](long a, long b) { return (int)((a + b - 1) / b); };
    const int TB = 256;

    // ---------------- all weight repacks in one launch ----------------
    repack_all<<<284, 256, 0, stream>>>(cw2, cw3, cw4, cw5, cw6, fc_l_w,
                                        bp2, bp3, bp4, bp5, bp6, wpl);

    // ---------------- global path (channel-last bf16 chain) ----------------
    conv_tile<5, 1, 32, 64, 64, 32, 4, 2, 1><<<3840, 256, 0, stream>>>(x, cw1, (short*)A);
    //        Cin Cout  H   W  POOL NSPLIT        blocks = N*(H/16)*(W/16)*NSPLIT
    convg_cl< 32,  32, 64, 64, true,  1><<<3840, 256, 0, stream>>>((short*)A,  bp2, (short*)Bb);
    convg_cl< 32,  64, 32, 32, false, 1><<< 960, 256, 0, stream>>>((short*)Bb, bp3, (short*)A);
    convg_cl< 64,  64, 32, 32, true,  1><<< 960, 256, 0, stream>>>((short*)A,  bp4, (short*)Bb);
    convg_cl< 64, 128, 16, 16, false, 2><<< 480, 256, 0, stream>>>((short*)Bb, bp5, (short*)A);
    convg_cl<128, 128, 16, 16, false, 2><<< 480, 256, 0, stream>>>((short*)A,  bp6, (short*)Bb);
    max_over_T_cl<<<128, 256, 0, stream>>>((short*)Bb, gmaxb);
    init_fcg<<<cdiv(2048L, TB), TB, 0, stream>>>(fc_g_b, fcbuf);
    fcg_partial<<<1024, 256, 0, stream>>>(gmaxb, fc_g_w, fcbuf);

    // ---------------- local path (channel-last bf16 chain) ----------------
    roi_crop<<<cdiv(1920L * 196, TB), TB, 0, stream>>>(x, px, crops);
    conv_tile<5, 1, 32, 14, 14, 16, 4, 2, 1><<<1920, 256, 0, stream>>>(crops, cw1, (short*)A);
    conv2l_mfma<<<1920, 256, 0, stream>>>((short*)A, bp2, (short*)Bb);
    //        Cin Cout  S  POOL  G NSPLIT          blocks = (1920/G)*NSPLIT
    convl_cl< 32,  64,  7, false, 2, 1><<< 960, 256, 0, stream>>>((short*)Bb, bp3, (short*)A);
    convl_cl< 64,  64,  7, true,  2, 1><<< 960, 256, 0, stream>>>((short*)A,  bp4, (short*)Bb);
    convl_cl< 64, 128,  3, false, 8, 2><<< 480, 256, 0, stream>>>((short*)Bb, bp5, (short*)A);
    convl_cl<128, 128,  3, false, 8, 2><<< 480, 256, 0, stream>>>((short*)A,  bp6, (short*)Bb);
    linear_l_mfma<<<120, 256, 0, stream>>>((short*)Bb, wpl, fc_l_b, lfc);

    // ---------------- GAT ----------------
    matmul_small<<<cdiv(1920L * 8, TB), TB, 0, stream>>>(lfc, gat1_W, h1, kB * kN, 256, 8);
    gat_scores<<<cdiv(1920L, TB), TB, 0, stream>>>(h1, gat1_a1, gat1_a2, s1, s2, kB * kN, 8);
    gat_agg2<8><<<480, 256, 0, stream>>>(h1, s1, s2, o1);
    matmul_small<<<cdiv(1920L * 16, TB), TB, 0, stream>>>(o1, gat2_W, h2, kB * kN, 8, 16);
    gat_scores<<<cdiv(1920L, TB), TB, 0, stream>>>(h2, gat2_a1, gat2_a2, s1b, s2b, kB * kN, 16);
    gat_agg2<16><<<480, 256, 0, stream>>>(h2, s1b, s2b, o2);
    elu_logsoftmax<<<cdiv(1920L, TB), TB, 0, stream>>>(o2, gatfc, kB * kN);

    // ---------------- head ----------------
    lcat_mean<<<cdiv(8L * 272, TB), TB, 0, stream>>>(lfc, gatfc, fcbuf);
    final_feats<<<cdiv(8L * 1023, TB), TB, 0, stream>>>(fcbuf, (float*)d_out);
}

// Round 7
// 614.495 us; speedup vs baseline: 42.6244x; 1.1674x over previous
//
#include <hip/hip_runtime.h>
#include <hip/hip_bf16.h>

// ---------------------------------------------------------------------------
// RGPNet forward. Round 7: conv1 (both paths) as MFMA im2col with fused ROI
// crop + coalesced channel-last epilogues. Everything else channel-last bf16.
// ---------------------------------------------------------------------------

constexpr int kB = 8, kT = 30, kR = 8;
constexpr int kN = kT * kR;          // 240 nodes per batch
constexpr int kRH = 14, kRW = 14;

static __device__ __forceinline__ float lrelu01(float v) {
    return v > 0.f ? v : 0.01f * v;
}

typedef __attribute__((ext_vector_type(8))) short bf16x8;
typedef __attribute__((ext_vector_type(4))) float f32x4;

static __device__ __forceinline__ short f2bf(float v) {
    __hip_bfloat16 h = __float2bfloat16(v);
    return *reinterpret_cast<short*>(&h);
}
static __device__ __forceinline__ float bf2f(short s) {
    unsigned u = ((unsigned)(unsigned short)s) << 16;
    return __uint_as_float(u);
}

// ---------------------------------------------------------------------------
// Repack bodies: conv OIHW fp32 -> per-lane B-fragment bf16.
// bp[(((cs*9+kykx)*NFTOT + nf)*64 + lane)*8 + j]
//   = W[nf*16+(lane&15)][cs*32+(lane>>4)*8+j][ky][kx]
// ---------------------------------------------------------------------------
template <int Cin, int Cout>
static __device__ void repack_w_body(const float* __restrict__ w,
                                     short* __restrict__ bp, int t)
{
    constexpr int NFTOT = Cout / 16;
    int lane = t & 63, rest = t >> 6;
    int nf = rest % NFTOT; rest /= NFTOT;
    int kykx = rest % 9; int cs = rest / 9;
    int co  = nf * 16 + (lane & 15);
    int cib = cs * 32 + (lane >> 4) * 8;
#pragma unroll
    for (int j = 0; j < 8; ++j) {
        float v = w[((long)co * Cin + cib + j) * 9 + kykx];
        bp[(long)t * 8 + j] = f2bf(v);
    }
}

// fc_l repack with K-permutation for channel-last input: k = s*128 + c,
// original column = c*9 + s.
static __device__ void repack_dense_body(const float* __restrict__ w,
                                         short* __restrict__ wp, int t)
{
    constexpr int KD = 1152;
    int lane = t & 63, rest = t >> 6;
    int nf = rest % 16; int kc = rest / 16;
    int co = nf * 16 + (lane & 15);
    int k0 = kc * 32 + (lane >> 4) * 8;
#pragma unroll
    for (int j = 0; j < 8; ++j) {
        int k = k0 + j;
        int korig = (k & 127) * 9 + (k >> 7);
        wp[(long)t * 8 + j] = f2bf(w[(long)co * KD + korig]);
    }
}

// conv1 (Cin=1, 5x5): K = ky*5+kx in [0,25), zero-padded to 32.
static __device__ void repack_w1_body(const float* __restrict__ w,
                                      short* __restrict__ bp, int t)
{
    int lane = t & 63, f = t >> 6;          // t < 128, NFTOT = 2
    int co = f * 16 + (lane & 15);
    int k0 = (lane >> 4) * 8;
#pragma unroll
    for (int j = 0; j < 8; ++j) {
        int k = k0 + j;
        bp[(long)t * 8 + j] = (k < 25) ? f2bf(w[co * 25 + k]) : (short)0;
    }
}

__global__ __launch_bounds__(256) void repack_all(
    const float* cw1, const float* cw2, const float* cw3, const float* cw4,
    const float* cw5, const float* cw6, const float* fclw,
    short* bp1, short* bp2, short* bp3, short* bp4, short* bp5, short* bp6,
    short* wpl)
{
    int t = blockIdx.x * 256 + threadIdx.x;
    if      (t < 1152)                repack_w_body< 32,  32>(cw2, bp2, t);
    else if (t < 1152 + 2304)         repack_w_body< 32,  64>(cw3, bp3, t - 1152);
    else if (t < 3456 + 4608)         repack_w_body< 64,  64>(cw4, bp4, t - 3456);
    else if (t < 8064 + 9216)         repack_w_body< 64, 128>(cw5, bp5, t - 8064);
    else if (t < 17280 + 18432)       repack_w_body<128, 128>(cw6, bp6, t - 17280);
    else if (t < 35712 + 36864)       repack_dense_body(fclw, wpl, t - 35712);
    else if (t < 72576 + 128)         repack_w1_body(cw1, bp1, t - 72576);
}

// ---------------------------------------------------------------------------
// conv1 global: fp32 NCHW (Cin=1) 64x64 -> MFMA im2col -> bf16 CL [n][4096][32].
// Block = one 16x16 tile. K=25 padded to 32 (B zero-padded).
// ---------------------------------------------------------------------------
__global__ __launch_bounds__(256) void conv1g_mfma(
    const float* __restrict__ x, const short* __restrict__ bp1,
    short* __restrict__ out)
{
    constexpr int RS = 23;
    __shared__ short slab[20 * RS];
    __shared__ __align__(16) short cslab[256 * 40];

    int bid = blockIdx.x;
    const int t16 = bid & 15;
    const int n = bid >> 4;
    const int y0 = (t16 >> 2) * 16, x0 = (t16 & 3) * 16;
    const int tid = threadIdx.x;
    const int lane = tid & 63, wav = tid >> 6;
    const int lx = lane & 15, lg = lane >> 4;

    for (int i = tid; i < 400; i += 256) {
        int yy = i / 20, xx = i % 20;
        int gy = y0 - 2 + yy, gx = x0 - 2 + xx;
        float v = 0.f;
        if ((unsigned)gy < 64u && (unsigned)gx < 64u)
            v = x[(long)n * 4096 + gy * 64 + gx];
        slab[yy * RS + xx] = f2bf(v);
    }

    bf16x8 bfr[2];
    bfr[0] = *(const bf16x8*)&bp1[(long)lane * 8];
    bfr[1] = *(const bf16x8*)&bp1[(long)(64 + lane) * 8];

    int aoff[8];
#pragma unroll
    for (int j = 0; j < 8; ++j) {
        int k = lg * 8 + j;
        int ky = k / 5, kx = k - ky * 5;
        aoff[j] = (k < 25) ? (ky * RS + kx) : 0;
    }
    __syncthreads();

    f32x4 acc[4][2];
#pragma unroll
    for (int i = 0; i < 4; ++i)
#pragma unroll
        for (int f = 0; f < 2; ++f) acc[i][f] = (f32x4)0.f;

#pragma unroll
    for (int i = 0; i < 4; ++i) {
        int mt = wav * 4 + i;               // tile row = py
        int base = mt * RS + lx;
        bf16x8 av;
#pragma unroll
        for (int j = 0; j < 8; ++j) av[j] = slab[base + aoff[j]];
        acc[i][0] = __builtin_amdgcn_mfma_f32_16x16x32_bf16(av, bfr[0], acc[i][0], 0, 0, 0);
        acc[i][1] = __builtin_amdgcn_mfma_f32_16x16x32_bf16(av, bfr[1], acc[i][1], 0, 0, 0);
    }

    // epilogue via LDS -> coalesced bf16x8 stores
#pragma unroll
    for (int i = 0; i < 4; ++i) {
        int mt = wav * 4 + i;
#pragma unroll
        for (int f = 0; f < 2; ++f) {
            int co = f * 16 + lx;
#pragma unroll
            for (int r = 0; r < 4; ++r) {
                int pix = mt * 16 + lg * 4 + r;
                cslab[pix * 40 + co] = f2bf(lrelu01(acc[i][f][r]));
            }
        }
    }
    __syncthreads();
    for (int i = tid; i < 1024; i += 256) {
        int pix = i >> 2, c8 = i & 3;
        int py = pix >> 4, px = pix & 15;
        *(bf16x8*)&out[((long)n * 4096 + (y0 + py) * 64 + x0 + px) * 32 + c8 * 8]
            = *(const bf16x8*)&cslab[pix * 40 + c8 * 8];
    }
}

// ---------------------------------------------------------------------------
// conv1 local, ROI-crop fused: block = one crop (1920). Bilinear crop staged
// directly into the halo slab; MFMA im2col; bf16 CL out [n][196][32].
// ---------------------------------------------------------------------------
__global__ __launch_bounds__(256) void conv1l_fused(
    const float* __restrict__ x, const float* __restrict__ px,
    const short* __restrict__ bp1, short* __restrict__ out)
{
    constexpr int RS = 19;
    __shared__ short slab[18 * RS];
    __shared__ __align__(16) short cslab[196 * 40];

    const int n = blockIdx.x;               // bt = n>>3
    const int tid = threadIdx.x;
    const int lane = tid & 63, wav = tid >> 6;
    const int lx = lane & 15, lg = lane >> 4;

    const float cx = px[n * 2], cy = px[n * 2 + 1];
    const float x1 = floorf(fminf(fmaxf(cx - 7.f, 0.f), 63.f));
    const float x2 = floorf(fminf(cx + 7.f, 64.f));
    const float y1 = floorf(fminf(fmaxf(cy - 7.f, 0.f), 63.f));
    const float y2 = floorf(fminf(cy + 7.f, 64.f));
    const float* img = x + (long)(n >> 3) * 4096;

    for (int i = tid; i < 324; i += 256) {
        int row = i / 18, col = i % 18;
        int yy = row - 2, xx = col - 2;
        float val = 0.f;
        if ((unsigned)yy < 14u && (unsigned)xx < 14u) {
            float sx = x1 + (xx + 0.5f) * (x2 - x1) * (1.f / 14.f) - 0.5f;
            sx = fminf(fmaxf(sx, x1), x2 - 1.f);
            float sy = y1 + (yy + 0.5f) * (y2 - y1) * (1.f / 14.f) - 0.5f;
            sy = fminf(fmaxf(sy, y1), y2 - 1.f);
            float ix0f = floorf(sx), iy0f = floorf(sy);
            float wx = sx - ix0f, wy = sy - iy0f;
            int ix0 = (int)ix0f, iy0 = (int)iy0f;
            int ix1 = (int)fminf(ix0f + 1.f, x2 - 1.f);
            int iy1 = (int)fminf(iy0f + 1.f, y2 - 1.f);
            float v00 = img[iy0 * 64 + ix0], v01 = img[iy0 * 64 + ix1];
            float v10 = img[iy1 * 64 + ix0], v11 = img[iy1 * 64 + ix1];
            float top = (1.f - wx) * v00 + wx * v01;
            float bot = (1.f - wx) * v10 + wx * v11;
            val = (1.f - wy) * top + wy * bot;
        }
        slab[row * RS + col] = f2bf(val);
    }

    bf16x8 bfr[2];
    bfr[0] = *(const bf16x8*)&bp1[(long)lane * 8];
    bfr[1] = *(const bf16x8*)&bp1[(long)(64 + lane) * 8];

    int aoff[8];
#pragma unroll
    for (int j = 0; j < 8; ++j) {
        int k = lg * 8 + j;
        int ky = k / 5, kx = k - ky * 5;
        aoff[j] = (k < 25) ? (ky * RS + kx) : 0;
    }

    int bases[4];
#pragma unroll
    for (int i = 0; i < 4; ++i) {
        int mt = wav * 4 + i;
        int pix = mt * 16 + lx; if (pix > 195) pix = 195;
        int py = pix / 14, pxx = pix - py * 14;
        bases[i] = py * RS + pxx;
    }
    __syncthreads();

    f32x4 acc[4][2];
#pragma unroll
    for (int i = 0; i < 4; ++i)
#pragma unroll
        for (int f = 0; f < 2; ++f) acc[i][f] = (f32x4)0.f;

#pragma unroll
    for (int i = 0; i < 4; ++i) {
        if (wav * 4 + i >= 13) break;        // M = 196 -> 13 tiles
        bf16x8 av;
#pragma unroll
        for (int j = 0; j < 8; ++j) av[j] = slab[bases[i] + aoff[j]];
        acc[i][0] = __builtin_amdgcn_mfma_f32_16x16x32_bf16(av, bfr[0], acc[i][0], 0, 0, 0);
        acc[i][1] = __builtin_amdgcn_mfma_f32_16x16x32_bf16(av, bfr[1], acc[i][1], 0, 0, 0);
    }

#pragma unroll
    for (int i = 0; i < 4; ++i) {
        int mt = wav * 4 + i;
        if (mt >= 13) break;
#pragma unroll
        for (int f = 0; f < 2; ++f) {
            int co = f * 16 + lx;
#pragma unroll
            for (int r = 0; r < 4; ++r) {
                int pix = mt * 16 + lg * 4 + r;
                if (pix < 196) cslab[pix * 40 + co] = f2bf(lrelu01(acc[i][f][r]));
            }
        }
    }
    __syncthreads();
    for (int i = tid; i < 784; i += 256) {
        int pix = i >> 2, c8 = i & 3;
        *(bf16x8*)&out[((long)n * 196 + pix) * 32 + c8 * 8]
            = *(const bf16x8*)&cslab[pix * 40 + c8 * 8];
    }
}

// ---------------------------------------------------------------------------
// Global-path MFMA conv, channel-last bf16 in/out (unchanged from round 6).
// ---------------------------------------------------------------------------
template <int Cin, int Cout, int H, int W, bool POOL, int NSPLIT>
__global__ __launch_bounds__(256) void convg_cl(
    const short* __restrict__ in, const short* __restrict__ bp,
    short* __restrict__ out)
{
    constexpr int NFTOT = Cout / 16;
    constexpr int NF    = NFTOT / NSPLIT;
    constexpr int CS    = Cin / 32;
    constexpr int TX    = W / 16, TY = H / 16;
    constexpr int CP    = 40;
    constexpr int Ho    = POOL ? H / 2 : H, Wo = POOL ? W / 2 : W;

    __shared__ __align__(16) short slab[18 * 18 * CP];

    int bid = blockIdx.x;
    const int split = bid % NSPLIT; bid /= NSPLIT;
    const int txt = bid % TX; bid /= TX;
    const int tyt = bid % TY; bid /= TY;
    const int n   = bid;
    const int x0 = txt * 16, y0 = tyt * 16;
    const int nf0 = split * NF;

    const int tid = threadIdx.x;
    const int lane = tid & 63, wav = tid >> 6;
    const int mrow0 = wav * 4;
    const int lx = lane & 15, lg = lane >> 4;

    f32x4 acc[4][NF];
#pragma unroll
    for (int r = 0; r < 4; ++r)
#pragma unroll
        for (int f = 0; f < NF; ++f) acc[r][f] = (f32x4)0.f;

    for (int cs = 0; cs < CS; ++cs) {
        for (int i = tid; i < 324 * 4; i += 256) {
            int pos = i >> 2, c8 = i & 3;
            int yy = pos / 18, xx = pos % 18;
            int gy = y0 - 1 + yy, gx = x0 - 1 + xx;
            bf16x8 v = (bf16x8)(short)0;
            if ((unsigned)gy < (unsigned)H && (unsigned)gx < (unsigned)W)
                v = *(const bf16x8*)&in[(((long)n * H + gy) * W + gx) * Cin + cs * 32 + c8 * 8];
            *(bf16x8*)&slab[pos * CP + c8 * 8] = v;
        }
        __syncthreads();

#pragma unroll
        for (int ky = 0; ky < 3; ++ky)
#pragma unroll
        for (int kx = 0; kx < 3; ++kx) {
            bf16x8 a[4];
#pragma unroll
            for (int r = 0; r < 4; ++r)
                a[r] = *(const bf16x8*)&slab[((mrow0 + r + ky) * 18 + lx + kx) * CP + lg * 8];
            const int kykx = ky * 3 + kx;
#pragma unroll
            for (int f = 0; f < NF; ++f) {
                bf16x8 b = *(const bf16x8*)&bp[(((long)(cs * 9 + kykx) * NFTOT + nf0 + f) * 64 + lane) * 8];
#pragma unroll
                for (int r = 0; r < 4; ++r)
                    acc[r][f] = __builtin_amdgcn_mfma_f32_16x16x32_bf16(a[r], b, acc[r][f], 0, 0, 0);
            }
        }
        __syncthreads();
    }

    if constexpr (!POOL) {
#pragma unroll
        for (int f = 0; f < NF; ++f) {
            int co = (nf0 + f) * 16 + lx;
#pragma unroll
            for (int r = 0; r < 4; ++r) {
                int y = y0 + mrow0 + r;
#pragma unroll
                for (int reg = 0; reg < 4; ++reg) {
                    int x = x0 + lg * 4 + reg;
                    out[((long)n * H * W + y * W + x) * Cout + co] = f2bf(lrelu01(acc[r][f][reg]));
                }
            }
        }
    } else {
#pragma unroll
        for (int f = 0; f < NF; ++f) {
            int co = (nf0 + f) * 16 + lx;
#pragma unroll
            for (int q = 0; q < 2; ++q) {
                int yp = (y0 >> 1) + wav * 2 + q;
                float m0 = fmaxf(fmaxf(lrelu01(acc[2*q][f][0]), lrelu01(acc[2*q][f][1])),
                                 fmaxf(lrelu01(acc[2*q+1][f][0]), lrelu01(acc[2*q+1][f][1])));
                float m1 = fmaxf(fmaxf(lrelu01(acc[2*q][f][2]), lrelu01(acc[2*q][f][3])),
                                 fmaxf(lrelu01(acc[2*q+1][f][2]), lrelu01(acc[2*q+1][f][3])));
                int xp0 = (x0 >> 1) + lg * 2;
                long base = (long)n * Ho * Wo + yp * Wo;
                out[(base + xp0) * Cout + co]     = f2bf(m0);
                out[(base + xp0 + 1) * Cout + co] = f2bf(m1);
            }
        }
    }
}

// ---------------------------------------------------------------------------
// Local conv2: channel-last bf16 [n][196][32] -> pool -> [n][49][32].
// ---------------------------------------------------------------------------
__global__ __launch_bounds__(256) void conv2l_mfma(
    const short* __restrict__ in, const short* __restrict__ bp,
    short* __restrict__ out)
{
    constexpr int CP = 40;
    __shared__ __align__(16) short slab[16 * 16 * CP];
    const int n = blockIdx.x;
    const int tid = threadIdx.x;
    const int lane = tid & 63, wav = tid >> 6;
    const int lx = lane & 15, lg = lane >> 4;

    for (int i = tid; i < 256 * 4; i += 256) {
        int pos = i >> 2, c8 = i & 3;
        int yy = pos >> 4, xx = pos & 15;
        int gy = yy - 1, gx = xx - 1;
        bf16x8 v = (bf16x8)(short)0;
        if ((unsigned)gy < 14u && (unsigned)gx < 14u)
            v = *(const bf16x8*)&in[((long)n * 196 + gy * 14 + gx) * 32 + c8 * 8];
        *(bf16x8*)&slab[pos * CP + c8 * 8] = v;
    }
    __syncthreads();

    f32x4 acc[4][2];
#pragma unroll
    for (int r = 0; r < 4; ++r)
#pragma unroll
        for (int f = 0; f < 2; ++f) acc[r][f] = (f32x4)0.f;

#pragma unroll
    for (int ky = 0; ky < 3; ++ky)
#pragma unroll
    for (int kx = 0; kx < 3; ++kx) {
        bf16x8 a[4];
        int xcl = min(lx + kx, 15);
#pragma unroll
        for (int r = 0; r < 4; ++r) {
            int ycl = min(wav * 4 + r + ky, 15);
            a[r] = *(const bf16x8*)&slab[(ycl * 16 + xcl) * CP + lg * 8];
        }
        const int kykx = ky * 3 + kx;
#pragma unroll
        for (int f = 0; f < 2; ++f) {
            bf16x8 b = *(const bf16x8*)&bp[(((long)kykx * 2 + f) * 64 + lane) * 8];
#pragma unroll
            for (int r = 0; r < 4; ++r)
                acc[r][f] = __builtin_amdgcn_mfma_f32_16x16x32_bf16(a[r], b, acc[r][f], 0, 0, 0);
        }
    }

#pragma unroll
    for (int f = 0; f < 2; ++f) {
        int co = f * 16 + lx;
#pragma unroll
        for (int q = 0; q < 2; ++q) {
            int yp = wav * 2 + q;
            if (yp >= 7) continue;
            float m0 = fmaxf(fmaxf(lrelu01(acc[2*q][f][0]), lrelu01(acc[2*q][f][1])),
                             fmaxf(lrelu01(acc[2*q+1][f][0]), lrelu01(acc[2*q+1][f][1])));
            float m1 = fmaxf(fmaxf(lrelu01(acc[2*q][f][2]), lrelu01(acc[2*q][f][3])),
                             fmaxf(lrelu01(acc[2*q+1][f][2]), lrelu01(acc[2*q+1][f][3])));
            int xp0 = lg * 2;
            out[((long)n * 49 + yp * 7 + xp0) * 32 + co] = f2bf(m0);
            if (xp0 + 1 < 7)
                out[((long)n * 49 + yp * 7 + xp0 + 1) * 32 + co] = f2bf(m1);
        }
    }
}

// ---------------------------------------------------------------------------
// Unified channel-last local conv (conv3l..conv6l), unchanged.
// ---------------------------------------------------------------------------
template <int Cin, int Cout, int S, bool POOL, int G, int NSPLIT>
__global__ __launch_bounds__(256) void convl_cl(
    const short* __restrict__ in, const short* __restrict__ bp,
    short* __restrict__ out)
{
    constexpr int SS    = S * S;
    constexpr int M     = G * SS;
    constexpr int MT    = (M + 15) / 16;
    constexpr int TPW   = (MT + 3) / 4;
    constexpr int CPAD  = Cin + 8;
    constexpr int NFTOT = Cout / 16;
    constexpr int NF    = NFTOT / NSPLIT;
    constexpr int CS    = Cin / 32;
    constexpr int So    = S / 2;

    __shared__ __align__(16) short slab[(1 + M) * CPAD];

    const int bid   = blockIdx.x;
    const int split = bid % NSPLIT;
    const int n0    = (bid / NSPLIT) * G;
    const int nf0   = split * NF;
    const int tid   = threadIdx.x;
    const int lane  = tid & 63, wav = tid >> 6;
    const int lx    = lane & 15, lg = lane >> 4;

    for (int i = tid; i < CPAD / 8; i += 256)
        *(bf16x8*)&slab[i * 8] = (bf16x8)(short)0;
    const short* src = in + (long)n0 * SS * Cin;
    for (int i = tid; i < M * (Cin / 8); i += 256) {
        int gs = i / (Cin / 8), c8 = i % (Cin / 8);
        *(bf16x8*)&slab[(1 + gs) * CPAD + c8 * 8] = *(const bf16x8*)&src[(long)i * 8];
    }
    __syncthreads();

    int aoff[TPW][9];
#pragma unroll
    for (int i = 0; i < TPW; ++i) {
        int mt = wav + i * 4;
        int m = mt * 16 + lx;
        if (mt >= MT || m > M - 1) m = M - 1;
        int g = m / SS, s = m % SS, y = s / S, x = s % S;
#pragma unroll
        for (int ky = 0; ky < 3; ++ky)
#pragma unroll
        for (int kx = 0; kx < 3; ++kx) {
            int iy = y + ky - 1, ix = x + kx - 1;
            bool ok = (unsigned)iy < (unsigned)S && (unsigned)ix < (unsigned)S;
            aoff[i][ky * 3 + kx] = (ok ? (1 + g * SS + iy * S + ix) : 0) * CPAD + lg * 8;
        }
    }

    f32x4 acc[TPW][NF];
#pragma unroll
    for (int i = 0; i < TPW; ++i)
#pragma unroll
        for (int f = 0; f < NF; ++f) acc[i][f] = (f32x4)0.f;

    for (int cs = 0; cs < CS; ++cs) {
#pragma unroll
        for (int kk = 0; kk < 9; ++kk) {
            bf16x8 a[TPW];
#pragma unroll
            for (int i = 0; i < TPW; ++i)
                a[i] = *(const bf16x8*)&slab[aoff[i][kk] + cs * 32];
#pragma unroll
            for (int f = 0; f < NF; ++f) {
                bf16x8 b = *(const bf16x8*)&bp[(((long)(cs * 9 + kk) * NFTOT + nf0 + f) * 64 + lane) * 8];
#pragma unroll
                for (int i = 0; i < TPW; ++i)
                    acc[i][f] = __builtin_amdgcn_mfma_f32_16x16x32_bf16(a[i], b, acc[i][f], 0, 0, 0);
            }
        }
    }

    if constexpr (!POOL) {
#pragma unroll
        for (int i = 0; i < TPW; ++i) {
            int mt = wav + i * 4;
            if (mt >= MT) continue;
#pragma unroll
            for (int f = 0; f < NF; ++f) {
                int co = (nf0 + f) * 16 + lx;
#pragma unroll
                for (int r = 0; r < 4; ++r) {
                    int m = mt * 16 + lg * 4 + r;
                    if (m >= M) continue;
                    int g = m / SS, s = m % SS;
                    out[((long)(n0 + g) * SS + s) * Cout + co] = f2bf(lrelu01(acc[i][f][r]));
                }
            }
        }
    } else {
        constexpr int CPO = Cout + 8;
        static_assert((long)M * CPO <= (long)(1 + M) * CPAD, "pool lds");
        __syncthreads();
#pragma unroll
        for (int i = 0; i < TPW; ++i) {
            int mt = wav + i * 4;
            if (mt >= MT) continue;
#pragma unroll
            for (int f = 0; f < NF; ++f) {
                int co = (nf0 + f) * 16 + lx;
#pragma unroll
                for (int r = 0; r < 4; ++r) {
                    int m = mt * 16 + lg * 4 + r;
                    if (m >= M) continue;
                    slab[m * CPO + co] = f2bf(lrelu01(acc[i][f][r]));
                }
            }
        }
        __syncthreads();
        for (int o = tid; o < G * So * So * Cout; o += 256) {
            int c = o % Cout; int rest = o / Cout;
            int xp = rest % So; rest /= So;
            int yp = rest % So; int g = rest / So;
            int base = (g * SS + 2 * yp * S + 2 * xp) * CPO + c;
            float v0 = bf2f(slab[base]);
            float v1 = bf2f(slab[base + CPO]);
            float v2 = bf2f(slab[base + S * CPO]);
            float v3 = bf2f(slab[base + (S + 1) * CPO]);
            float mv = fmaxf(fmaxf(v0, v1), fmaxf(v2, v3));
            out[((long)(n0 + g) * So * So + yp * So + xp) * Cout + c] = f2bf(mv);
        }
    }
}

// ---------------------------------------------------------------------------
// fc_l as MFMA GEMM, bf16 channel-last input [1920][1152].
// ---------------------------------------------------------------------------
__global__ __launch_bounds__(256) void linear_l_mfma(
    const short* __restrict__ in, const short* __restrict__ wp,
    const float* __restrict__ bias, float* __restrict__ out)
{
    constexpr int KD = 1152, LDK = KD + 8;
    __shared__ __align__(16) short slab[16 * LDK];
    const int m0 = blockIdx.x * 16;
    const int tid = threadIdx.x;
    const int lane = tid & 63, wav = tid >> 6;
    const int lx = lane & 15, lg = lane >> 4;

    for (int i = tid; i < 16 * (KD / 8); i += 256) {
        int r = i / (KD / 8), c8 = i % (KD / 8);
        *(bf16x8*)&slab[r * LDK + c8 * 8] = *(const bf16x8*)&in[(long)(m0 + r) * KD + c8 * 8];
    }
    __syncthreads();

    f32x4 acc[4];
#pragma unroll
    for (int f = 0; f < 4; ++f) acc[f] = (f32x4)0.f;

    for (int kc = 0; kc < KD / 32; ++kc) {
        bf16x8 a = *(const bf16x8*)&slab[lx * LDK + kc * 32 + lg * 8];
#pragma unroll
        for (int f = 0; f < 4; ++f) {
            int nf = wav * 4 + f;
            bf16x8 b = *(const bf16x8*)&wp[(((long)kc * 16 + nf) * 64 + lane) * 8];
            acc[f] = __builtin_amdgcn_mfma_f32_16x16x32_bf16(a, b, acc[f], 0, 0, 0);
        }
    }

#pragma unroll
    for (int f = 0; f < 4; ++f) {
        int co = (wav * 4 + f) * 16 + lx;
        float bv = bias[co];
#pragma unroll
        for (int reg = 0; reg < 4; ++reg) {
            int m = m0 + lg * 4 + reg;
            out[(long)m * 256 + co] = acc[f][reg] + bv;
        }
    }
}

// ---------------------------------------------------------------------------
// max over T, channel-last bf16 -> fp32 in ORIGINAL NCHW order.
// ---------------------------------------------------------------------------
__global__ void max_over_T_cl(const short* __restrict__ in, float* __restrict__ out)
{
    int idx = blockIdx.x * blockDim.x + threadIdx.x;
    if (idx >= 8 * 4096) return;
    int b = idx >> 12, k8 = idx & 4095;
    float m[8];
#pragma unroll
    for (int j = 0; j < 8; ++j) m[j] = -1e30f;
    for (int t = 0; t < 30; ++t) {
        bf16x8 v = *(const bf16x8*)&in[(((long)(b * 30 + t)) << 15) + k8 * 8];
#pragma unroll
        for (int j = 0; j < 8; ++j) m[j] = fmaxf(m[j], bf2f(v[j]));
    }
    int kcl0 = k8 * 8;
    int s = kcl0 >> 7, c0 = kcl0 & 127;
#pragma unroll
    for (int j = 0; j < 8; ++j)
        out[b * 32768 + (c0 + j) * 256 + s] = m[j];
}

// ---------------------------------------------------------------------------
// fc_g: split-K, weights read once, all 8 batch rows per wave, atomicAdd.
// ---------------------------------------------------------------------------
__global__ void init_fcg(const float* __restrict__ bias, float* __restrict__ fcbuf)
{
    int idx = blockIdx.x * blockDim.x + threadIdx.x;
    if (idx >= 8 * 256) return;
    fcbuf[(idx >> 8) * 528 + (idx & 255)] = bias[idx & 255];
}

__global__ __launch_bounds__(256) void fcg_partial(
    const float* __restrict__ in, const float* __restrict__ w,
    float* __restrict__ fcbuf)
{
    const int gid = blockIdx.x * 256 + threadIdx.x;
    const int wid = gid >> 6, lane = gid & 63;
    const int o = wid >> 4, kc = wid & 15;
    const int k0 = kc * 2048;

    float acc[8];
#pragma unroll
    for (int m = 0; m < 8; ++m) acc[m] = 0.f;

    for (int it = 0; it < 8; ++it) {
        int k = k0 + it * 256 + lane * 4;
        float4 wv = *(const float4*)&w[(long)o * 32768 + k];
#pragma unroll
        for (int m = 0; m < 8; ++m) {
            float4 xv = *(const float4*)&in[(long)m * 32768 + k];
            acc[m] = fmaf(xv.x, wv.x, acc[m]);
            acc[m] = fmaf(xv.y, wv.y, acc[m]);
            acc[m] = fmaf(xv.z, wv.z, acc[m]);
            acc[m] = fmaf(xv.w, wv.w, acc[m]);
        }
    }
#pragma unroll
    for (int off = 32; off > 0; off >>= 1)
#pragma unroll
        for (int m = 0; m < 8; ++m)
            acc[m] += __shfl_down(acc[m], off, 64);
    if (lane == 0) {
#pragma unroll
        for (int m = 0; m < 8; ++m)
            atomicAdd(&fcbuf[m * 528 + o], acc[m]);
    }
}

// ---------------- tiny dense matmul ------------------------------------------
__global__ void matmul_small(const float* __restrict__ in, const float* __restrict__ w,
                             float* __restrict__ out, int rows, int Kd, int O)
{
    int idx = blockIdx.x * blockDim.x + threadIdx.x;
    if (idx >= rows * O) return;
    int row = idx / O, o = idx % O;
    float acc = 0.f;
    for (int k = 0; k < Kd; ++k) acc = fmaf(in[(long)row * Kd + k], w[k * O + o], acc);
    out[idx] = acc;
}

// ---------------- GAT attention scalars ---------------------------------------
__global__ void gat_scores(const float* __restrict__ h, const float* __restrict__ a1,
                           const float* __restrict__ a2, float* __restrict__ s1,
                           float* __restrict__ s2, int total, int D)
{
    int idx = blockIdx.x * blockDim.x + threadIdx.x;
    if (idx >= total) return;
    const float* hr = h + (long)idx * D;
    float acc1 = 0.f, acc2 = 0.f;
    for (int k = 0; k < D; ++k) {
        acc1 = fmaf(hr[k], a1[k], acc1);
        acc2 = fmaf(hr[k], a2[k], acc2);
    }
    s1[idx] = acc1; s2[idx] = acc2;
}

// ---------------- GAT masked-softmax aggregate: wave per (b,i) ----------------
template <int D>
__global__ __launch_bounds__(256) void gat_agg2(
    const float* __restrict__ h, const float* __restrict__ s1,
    const float* __restrict__ s2, float* __restrict__ out)
{
    const int wid = (blockIdx.x * 256 + threadIdx.x) >> 6;
    const int lane = threadIdx.x & 63;
    const int b = wid / kN, i = wid % kN;
    const int fri = i / kR, rki = i % kR;
    const float s1i = s1[b * kN + i];

    float ej[4];
    float mx = -1e30f;
#pragma unroll
    for (int t = 0; t < 4; ++t) {
        int j = lane + t * 64;
        if (j < kN) {
            int frj = j / kR, rkj = j % kR;
            int df = fri - frj;
            bool adj = (fri == frj) || ((rki == rkj) && (df == 1 || df == -1));
            float v = s1i + s2[b * kN + j];
            v = v > 0.f ? v : 0.2f * v;
            ej[t] = adj ? v : -9.0e15f;
        } else ej[t] = -1e30f;
        mx = fmaxf(mx, ej[t]);
    }
#pragma unroll
    for (int off = 1; off < 64; off <<= 1)
        mx = fmaxf(mx, __shfl_xor(mx, off, 64));

    float ex[4]; float sum = 0.f;
#pragma unroll
    for (int t = 0; t < 4; ++t) { ex[t] = expf(ej[t] - mx); sum += ex[t]; }
#pragma unroll
    for (int off = 1; off < 64; off <<= 1)
        sum += __shfl_xor(sum, off, 64);

    float part[D];
#pragma unroll
    for (int d = 0; d < D; ++d) part[d] = 0.f;
#pragma unroll
    for (int t = 0; t < 4; ++t) {
        int j = lane + t * 64;
        int jc = j < kN ? j : kN - 1;
        float w = j < kN ? ex[t] : 0.f;
        const float* hr = h + ((long)b * kN + jc) * D;
#pragma unroll
        for (int d = 0; d < D; ++d) part[d] = fmaf(w, hr[d], part[d]);
    }
#pragma unroll
    for (int d = 0; d < D; ++d)
#pragma unroll
        for (int off = 1; off < 64; off <<= 1)
            part[d] += __shfl_xor(part[d], off, 64);

    if (lane < D) {
        float v = part[0];
#pragma unroll
        for (int d = 1; d < D; ++d) v = (lane == d) ? part[d] : v;
        out[((long)b * kN + i) * D + lane] = v / sum;
    }
}

// ---------------- elu + log_softmax (last dim 16) -----------------------------
__global__ void elu_logsoftmax(const float* __restrict__ in, float* __restrict__ out,
                               int rows)
{
    int r = blockIdx.x * blockDim.x + threadIdx.x;
    if (r >= rows) return;
    float v[16];
    float mx = -1e30f;
#pragma unroll
    for (int k = 0; k < 16; ++k) {
        float xv = in[(long)r * 16 + k];
        xv = xv > 0.f ? xv : expm1f(xv);
        v[k] = xv; mx = fmaxf(mx, xv);
    }
    float s = 0.f;
#pragma unroll
    for (int k = 0; k < 16; ++k) s += expf(v[k] - mx);
    float ls = logf(s) + mx;
#pragma unroll
    for (int k = 0; k < 16; ++k) out[(long)r * 16 + k] = v[k] - ls;
}

// ---------------- mean over nodes of concat(l_fc, gat_fc) ---------------------
__global__ void lcat_mean(const float* __restrict__ lfc, const float* __restrict__ gatfc,
                          float* __restrict__ fcbuf)
{
    int idx = blockIdx.x * blockDim.x + threadIdx.x;
    if (idx >= kB * 272) return;
    int b = idx / 272, c = idx % 272;
    float s = 0.f;
    if (c < 256) {
        for (int n2 = 0; n2 < kN; ++n2) s += lfc[((long)b * kN + n2) * 256 + c];
    } else {
        int cc = c - 256;
        for (int n2 = 0; n2 < kN; ++n2) s += gatfc[((long)b * kN + n2) * 16 + cc];
    }
    fcbuf[b * 528 + 256 + c] = s * (1.f / kN);
}

// ---------------- final pyramid ----------------------------------------------
__global__ void final_feats(const float* __restrict__ fcbuf, float* __restrict__ out)
{
    int idx = blockIdx.x * blockDim.x + threadIdx.x;
    if (idx >= kB * 1023) return;
    int b = idx / 1023, m = idx % 1023;
    int nb, seg, off;
    if      (m < 528) { nb = 1;  seg = 528; off = 0;   }
    else if (m < 792) { nb = 2;  seg = 264; off = 528; }
    else if (m < 924) { nb = 4;  seg = 132; off = 792; }
    else if (m < 990) { nb = 8;  seg = 66;  off = 924; }
    else              { nb = 16; seg = 33;  off = 990; }
    int mm = m - off;
    float s = 0.f, mx = -1e30f;
    for (int k2 = 0; k2 < nb; ++k2) {
        float v = fcbuf[b * 528 + k2 * seg + mm];
        s += v; mx = fmaxf(mx, v);
    }
    out[(long)b * 1023 + m] = s / nb + mx;
}

// ---------------------------------------------------------------------------
extern "C" void kernel_launch(void* const* d_in, const int* in_sizes, int n_in,
                              void* d_out, int out_size, void* d_ws, size_t ws_size,
                              hipStream_t stream)
{
    const float* x       = (const float*)d_in[0];
    const float* px      = (const float*)d_in[1];
    const float* cw1     = (const float*)d_in[2];
    const float* cw2     = (const float*)d_in[3];
    const float* cw3     = (const float*)d_in[4];
    const float* cw4     = (const float*)d_in[5];
    const float* cw5     = (const float*)d_in[6];
    const float* cw6     = (const float*)d_in[7];
    const float* fc_g_w  = (const float*)d_in[8];
    const float* fc_g_b  = (const float*)d_in[9];
    const float* fc_l_w  = (const float*)d_in[10];
    const float* fc_l_b  = (const float*)d_in[11];
    const float* gat1_W  = (const float*)d_in[12];
    const float* gat1_a1 = (const float*)d_in[13];
    const float* gat1_a2 = (const float*)d_in[14];
    const float* gat2_W  = (const float*)d_in[15];
    const float* gat2_a1 = (const float*)d_in[16];
    const float* gat2_a2 = (const float*)d_in[17];

    float* ws    = (float*)d_ws;
    float* A     = ws;                      // 31,457,280 floats
    float* Bb    = A + 31457280;            //  7,864,320
    float* crops = Bb + 7864320;            //    376,320 (unused now)
    float* gmaxb = crops + 376320;          //    262,144
    float* lfc   = gmaxb + 262144;          //    491,520
    float* h1    = lfc + 491520;
    float* s1    = h1 + 15360;
    float* s2    = s1 + 1920;
    float* o1    = s2 + 1920;
    float* h2    = o1 + 15360;
    float* s1b   = h2 + 30720;
    float* s2b   = s1b + 1920;
    float* o2    = s2b + 1920;
    float* gatfc = o2 + 30720;
    float* fcbuf = gatfc + 30720;           // 4,224

    short* bp2 = (short*)(fcbuf + 4224);    // 9,216 shorts
    short* bp3 = bp2 + 9216;                // 18,432
    short* bp4 = bp3 + 18432;               // 36,864
    short* bp5 = bp4 + 36864;               // 73,728
    short* bp6 = bp5 + 73728;               // 147,456
    short* wpl = bp6 + 147456;              // 294,912 (fc_l packed, K-permuted)
    short* bp1 = wpl + 294912;              // 1,024 (conv1, K=25 padded to 32)

    auto cdiv = [](long a, long b) { return (int)((a + b - 1) / b); };
    const int TB = 256;

    // ---------------- all weight repacks in one launch ----------------
    repack_all<<<284, 256, 0, stream>>>(cw1, cw2, cw3, cw4, cw5, cw6, fc_l_w,
                                        bp1, bp2, bp3, bp4, bp5, bp6, wpl);

    // ---------------- global path (channel-last bf16 chain) ----------------
    conv1g_mfma<<<3840, 256, 0, stream>>>(x, bp1, (short*)A);
    //        Cin Cout  H   W  POOL NSPLIT        blocks = N*(H/16)*(W/16)*NSPLIT
    convg_cl< 32,  32, 64, 64, true,  1><<<3840, 256, 0, stream>>>((short*)A,  bp2, (short*)Bb);
    convg_cl< 32,  64, 32, 32, false, 1><<< 960, 256, 0, stream>>>((short*)Bb, bp3, (short*)A);
    convg_cl< 64,  64, 32, 32, true,  1><<< 960, 256, 0, stream>>>((short*)A,  bp4, (short*)Bb);
    convg_cl< 64, 128, 16, 16, false, 2><<< 480, 256, 0, stream>>>((short*)Bb, bp5, (short*)A);
    convg_cl<128, 128, 16, 16, false, 2><<< 480, 256, 0, stream>>>((short*)A,  bp6, (short*)Bb);
    max_over_T_cl<<<128, 256, 0, stream>>>((short*)Bb, gmaxb);
    init_fcg<<<cdiv(2048L, TB), TB, 0, stream>>>(fc_g_b, fcbuf);
    fcg_partial<<<1024, 256, 0, stream>>>(gmaxb, fc_g_w, fcbuf);

    // ---------------- local path (ROI fused into conv1) ----------------
    conv1l_fused<<<1920, 256, 0, stream>>>(x, px, bp1, (short*)A);
    conv2l_mfma<<<1920, 256, 0, stream>>>((short*)A, bp2, (short*)Bb);
    //        Cin Cout  S  POOL  G NSPLIT          blocks = (1920/G)*NSPLIT
    convl_cl< 32,  64,  7, false, 2, 1><<< 960, 256, 0, stream>>>((short*)Bb, bp3, (short*)A);
    convl_cl< 64,  64,  7, true,  2, 1><<< 960, 256, 0, stream>>>((short*)A,  bp4, (short*)Bb);
    convl_cl< 64, 128,  3, false, 8, 2><<< 480, 256, 0, stream>>>((short*)Bb, bp5, (short*)A);
    convl_cl<128, 128,  3, false, 8, 2><<< 480, 256, 0, stream>>>((short*)A,  bp6, (short*)Bb);
    linear_l_mfma<<<120, 256, 0, stream>>>((short*)Bb, wpl, fc_l_b, lfc);

    // ---------------- GAT ----------------
    matmul_small<<<cdiv(1920L * 8, TB), TB, 0, stream>>>(lfc, gat1_W, h1, kB * kN, 256, 8);
    gat_scores<<<cdiv(1920L, TB), TB, 0, stream>>>(h1, gat1_a1, gat1_a2, s1, s2, kB * kN, 8);
    gat_agg2<8><<<480, 256, 0, stream>>>(h1, s1, s2, o1);
    matmul_small<<<cdiv(1920L * 16, TB), TB, 0, stream>>>(o1, gat2_W, h2, kB * kN, 8, 16);
    gat_scores<<<cdiv(1920L, TB), TB, 0, stream>>>(h2, gat2_a1, gat2_a2, s1b, s2b, kB * kN, 16);
    gat_agg2<16><<<480, 256, 0, stream>>>(h2, s1b, s2b, o2);
    elu_logsoftmax<<<cdiv(1920L, TB), TB, 0, stream>>>(o2, gatfc, kB * kN);

    // ---------------- head ----------------
    lcat_mean<<<cdiv(8L * 272, TB), TB, 0, stream>>>(lfc, gatfc, fcbuf);
    final_feats<<<cdiv(8L * 1023, TB), TB, 0, stream>>>(fcbuf, (float*)d_out);
}

// Round 9
// 444.760 us; speedup vs baseline: 58.8913x; 1.3816x over previous
//
#include <hip/hip_runtime.h>
#include <hip/hip_bf16.h>

// ---------------------------------------------------------------------------
// RGPNet forward. Round 8 (resubmit): fully-fused local path (ROI+conv1..conv6
// in one kernel, activations in LDS), GAT in 3 dispatches, wider conv5g/6g.
// ---------------------------------------------------------------------------

constexpr int kB = 8, kT = 30, kR = 8;
constexpr int kN = kT * kR;          // 240 nodes per batch

static __device__ __forceinline__ float lrelu01(float v) {
    return v > 0.f ? v : 0.01f * v;
}

typedef __attribute__((ext_vector_type(8))) short bf16x8;
typedef __attribute__((ext_vector_type(4))) float f32x4;

static __device__ __forceinline__ short f2bf(float v) {
    __hip_bfloat16 h = __float2bfloat16(v);
    return *reinterpret_cast<short*>(&h);
}
static __device__ __forceinline__ float bf2f(short s) {
    unsigned u = ((unsigned)(unsigned short)s) << 16;
    return __uint_as_float(u);
}

// ---------------------------------------------------------------------------
// Weight repacks (single launch).
// ---------------------------------------------------------------------------
template <int Cin, int Cout>
static __device__ void repack_w_body(const float* __restrict__ w,
                                     short* __restrict__ bp, int t)
{
    constexpr int NFTOT = Cout / 16;
    int lane = t & 63, rest = t >> 6;
    int nf = rest % NFTOT; rest /= NFTOT;
    int kykx = rest % 9; int cs = rest / 9;
    int co  = nf * 16 + (lane & 15);
    int cib = cs * 32 + (lane >> 4) * 8;
#pragma unroll
    for (int j = 0; j < 8; ++j) {
        float v = w[((long)co * Cin + cib + j) * 9 + kykx];
        bp[(long)t * 8 + j] = f2bf(v);
    }
}

static __device__ void repack_dense_body(const float* __restrict__ w,
                                         short* __restrict__ wp, int t)
{
    constexpr int KD = 1152;
    int lane = t & 63, rest = t >> 6;
    int nf = rest % 16; int kc = rest / 16;
    int co = nf * 16 + (lane & 15);
    int k0 = kc * 32 + (lane >> 4) * 8;
#pragma unroll
    for (int j = 0; j < 8; ++j) {
        int k = k0 + j;
        int korig = (k & 127) * 9 + (k >> 7);
        wp[(long)t * 8 + j] = f2bf(w[(long)co * KD + korig]);
    }
}

static __device__ void repack_w1_body(const float* __restrict__ w,
                                      short* __restrict__ bp, int t)
{
    int lane = t & 63, f = t >> 6;          // t < 128
    int co = f * 16 + (lane & 15);
    int k0 = (lane >> 4) * 8;
#pragma unroll
    for (int j = 0; j < 8; ++j) {
        int k = k0 + j;
        bp[(long)t * 8 + j] = (k < 25) ? f2bf(w[co * 25 + k]) : (short)0;
    }
}

__global__ __launch_bounds__(256) void repack_all(
    const float* cw1, const float* cw2, const float* cw3, const float* cw4,
    const float* cw5, const float* cw6, const float* fclw,
    short* bp1, short* bp2, short* bp3, short* bp4, short* bp5, short* bp6,
    short* wpl)
{
    int t = blockIdx.x * 256 + threadIdx.x;
    if      (t < 1152)                repack_w_body< 32,  32>(cw2, bp2, t);
    else if (t < 1152 + 2304)         repack_w_body< 32,  64>(cw3, bp3, t - 1152);
    else if (t < 3456 + 4608)         repack_w_body< 64,  64>(cw4, bp4, t - 3456);
    else if (t < 8064 + 9216)         repack_w_body< 64, 128>(cw5, bp5, t - 8064);
    else if (t < 17280 + 18432)       repack_w_body<128, 128>(cw6, bp6, t - 17280);
    else if (t < 35712 + 36864)       repack_dense_body(fclw, wpl, t - 35712);
    else if (t < 72576 + 128)         repack_w1_body(cw1, bp1, t - 72576);
}

// ---------------------------------------------------------------------------
// conv1 global.
// ---------------------------------------------------------------------------
__global__ __launch_bounds__(256) void conv1g_mfma(
    const float* __restrict__ x, const short* __restrict__ bp1,
    short* __restrict__ out)
{
    constexpr int RS = 23;
    __shared__ short slab[20 * RS];
    __shared__ __align__(16) short cslab[256 * 40];

    int bid = blockIdx.x;
    const int t16 = bid & 15;
    const int n = bid >> 4;
    const int y0 = (t16 >> 2) * 16, x0 = (t16 & 3) * 16;
    const int tid = threadIdx.x;
    const int lane = tid & 63, wav = tid >> 6;
    const int lx = lane & 15, lg = lane >> 4;

    for (int i = tid; i < 400; i += 256) {
        int yy = i / 20, xx = i % 20;
        int gy = y0 - 2 + yy, gx = x0 - 2 + xx;
        float v = 0.f;
        if ((unsigned)gy < 64u && (unsigned)gx < 64u)
            v = x[(long)n * 4096 + gy * 64 + gx];
        slab[yy * RS + xx] = f2bf(v);
    }

    bf16x8 bfr[2];
    bfr[0] = *(const bf16x8*)&bp1[(long)lane * 8];
    bfr[1] = *(const bf16x8*)&bp1[(long)(64 + lane) * 8];

    int aoff[8];
#pragma unroll
    for (int j = 0; j < 8; ++j) {
        int k = lg * 8 + j;
        int ky = k / 5, kx = k - ky * 5;
        aoff[j] = (k < 25) ? (ky * RS + kx) : 0;
    }
    __syncthreads();

    f32x4 acc[4][2];
#pragma unroll
    for (int i = 0; i < 4; ++i)
#pragma unroll
        for (int f = 0; f < 2; ++f) acc[i][f] = (f32x4)0.f;

#pragma unroll
    for (int i = 0; i < 4; ++i) {
        int mt = wav * 4 + i;
        int base = mt * RS + lx;
        bf16x8 av;
#pragma unroll
        for (int j = 0; j < 8; ++j) av[j] = slab[base + aoff[j]];
        acc[i][0] = __builtin_amdgcn_mfma_f32_16x16x32_bf16(av, bfr[0], acc[i][0], 0, 0, 0);
        acc[i][1] = __builtin_amdgcn_mfma_f32_16x16x32_bf16(av, bfr[1], acc[i][1], 0, 0, 0);
    }

#pragma unroll
    for (int i = 0; i < 4; ++i) {
        int mt = wav * 4 + i;
#pragma unroll
        for (int f = 0; f < 2; ++f) {
            int co = f * 16 + lx;
#pragma unroll
            for (int r = 0; r < 4; ++r) {
                int pix = mt * 16 + lg * 4 + r;
                cslab[pix * 40 + co] = f2bf(lrelu01(acc[i][f][r]));
            }
        }
    }
    __syncthreads();
    for (int i = tid; i < 1024; i += 256) {
        int pix = i >> 2, c8 = i & 3;
        int py = pix >> 4, px = pix & 15;
        *(bf16x8*)&out[((long)n * 4096 + (y0 + py) * 64 + x0 + px) * 32 + c8 * 8]
            = *(const bf16x8*)&cslab[pix * 40 + c8 * 8];
    }
}

// ---------------------------------------------------------------------------
// Global-path MFMA conv, channel-last bf16.
// ---------------------------------------------------------------------------
template <int Cin, int Cout, int H, int W, bool POOL, int NSPLIT>
__global__ __launch_bounds__(256) void convg_cl(
    const short* __restrict__ in, const short* __restrict__ bp,
    short* __restrict__ out)
{
    constexpr int NFTOT = Cout / 16;
    constexpr int NF    = NFTOT / NSPLIT;
    constexpr int CS    = Cin / 32;
    constexpr int TX    = W / 16, TY = H / 16;
    constexpr int CP    = 40;
    constexpr int Ho    = POOL ? H / 2 : H, Wo = POOL ? W / 2 : W;

    __shared__ __align__(16) short slab[18 * 18 * CP];

    int bid = blockIdx.x;
    const int split = bid % NSPLIT; bid /= NSPLIT;
    const int txt = bid % TX; bid /= TX;
    const int tyt = bid % TY; bid /= TY;
    const int n   = bid;
    const int x0 = txt * 16, y0 = tyt * 16;
    const int nf0 = split * NF;

    const int tid = threadIdx.x;
    const int lane = tid & 63, wav = tid >> 6;
    const int mrow0 = wav * 4;
    const int lx = lane & 15, lg = lane >> 4;

    f32x4 acc[4][NF];
#pragma unroll
    for (int r = 0; r < 4; ++r)
#pragma unroll
        for (int f = 0; f < NF; ++f) acc[r][f] = (f32x4)0.f;

    for (int cs = 0; cs < CS; ++cs) {
        for (int i = tid; i < 324 * 4; i += 256) {
            int pos = i >> 2, c8 = i & 3;
            int yy = pos / 18, xx = pos % 18;
            int gy = y0 - 1 + yy, gx = x0 - 1 + xx;
            bf16x8 v = (bf16x8)(short)0;
            if ((unsigned)gy < (unsigned)H && (unsigned)gx < (unsigned)W)
                v = *(const bf16x8*)&in[(((long)n * H + gy) * W + gx) * Cin + cs * 32 + c8 * 8];
            *(bf16x8*)&slab[pos * CP + c8 * 8] = v;
        }
        __syncthreads();

#pragma unroll
        for (int ky = 0; ky < 3; ++ky)
#pragma unroll
        for (int kx = 0; kx < 3; ++kx) {
            bf16x8 a[4];
#pragma unroll
            for (int r = 0; r < 4; ++r)
                a[r] = *(const bf16x8*)&slab[((mrow0 + r + ky) * 18 + lx + kx) * CP + lg * 8];
            const int kykx = ky * 3 + kx;
#pragma unroll
            for (int f = 0; f < NF; ++f) {
                bf16x8 b = *(const bf16x8*)&bp[(((long)(cs * 9 + kykx) * NFTOT + nf0 + f) * 64 + lane) * 8];
#pragma unroll
                for (int r = 0; r < 4; ++r)
                    acc[r][f] = __builtin_amdgcn_mfma_f32_16x16x32_bf16(a[r], b, acc[r][f], 0, 0, 0);
            }
        }
        __syncthreads();
    }

    if constexpr (!POOL) {
#pragma unroll
        for (int f = 0; f < NF; ++f) {
            int co = (nf0 + f) * 16 + lx;
#pragma unroll
            for (int r = 0; r < 4; ++r) {
                int y = y0 + mrow0 + r;
#pragma unroll
                for (int reg = 0; reg < 4; ++reg) {
                    int x = x0 + lg * 4 + reg;
                    out[((long)n * H * W + y * W + x) * Cout + co] = f2bf(lrelu01(acc[r][f][reg]));
                }
            }
        }
    } else {
#pragma unroll
        for (int f = 0; f < NF; ++f) {
            int co = (nf0 + f) * 16 + lx;
#pragma unroll
            for (int q = 0; q < 2; ++q) {
                int yp = (y0 >> 1) + wav * 2 + q;
                float m0 = fmaxf(fmaxf(lrelu01(acc[2*q][f][0]), lrelu01(acc[2*q][f][1])),
                                 fmaxf(lrelu01(acc[2*q+1][f][0]), lrelu01(acc[2*q+1][f][1])));
                float m1 = fmaxf(fmaxf(lrelu01(acc[2*q][f][2]), lrelu01(acc[2*q][f][3])),
                                 fmaxf(lrelu01(acc[2*q+1][f][2]), lrelu01(acc[2*q+1][f][3])));
                int xp0 = (x0 >> 1) + lg * 2;
                long base = (long)n * Ho * Wo + yp * Wo;
                out[(base + xp0) * Cout + co]     = f2bf(m0);
                out[(base + xp0 + 1) * Cout + co] = f2bf(m1);
            }
        }
    }
}

// ---------------------------------------------------------------------------
// FUSED local path: one block = one crop. ROI+conv1..conv6 with activations
// in LDS; writes conv6 output [1920][9][128] bf16 channel-last.
// LDS layout (shorts): inslab 0..342; bufA 352..10592 (slab2 [256][40];
// later act3 @352 [50][72], prepool @3952 [49][72]); act2 @10592 [50][40];
// act4 @12592 [10][72]; act5 @13312 [10][136]. Total 14672 shorts = 29.3 KB.
// ---------------------------------------------------------------------------
__global__ __launch_bounds__(256) void local_fused(
    const float* __restrict__ x, const float* __restrict__ px,
    const short* __restrict__ bp1, const short* __restrict__ bp2,
    const short* __restrict__ bp3, const short* __restrict__ bp4,
    const short* __restrict__ bp5, const short* __restrict__ bp6,
    short* __restrict__ out)
{
    __shared__ __align__(16) short lds[14672];
    short* inslab  = lds;            // 18*19
    short* slab2   = lds + 352;      // [256][40]
    short* act3    = lds + 352;      // [50][72] (aliases slab2, used after)
    short* prepool = lds + 3952;     // [49][72]
    short* act2    = lds + 10592;    // [50][40]
    short* act4    = lds + 12592;    // [10][72]
    short* act5    = lds + 13312;    // [10][136]

    const int n = blockIdx.x;
    const int tid = threadIdx.x;
    const int lane = tid & 63, wav = tid >> 6;
    const int lx = lane & 15, lg = lane >> 4;

    // ---------------- phase 0: ROI stage + zero slab2 + zero act2 slot0 ----
    {
        const float cx = px[n * 2], cy = px[n * 2 + 1];
        const float x1 = floorf(fminf(fmaxf(cx - 7.f, 0.f), 63.f));
        const float x2 = floorf(fminf(cx + 7.f, 64.f));
        const float y1 = floorf(fminf(fmaxf(cy - 7.f, 0.f), 63.f));
        const float y2 = floorf(fminf(cy + 7.f, 64.f));
        const float* img = x + (long)(n >> 3) * 4096;

        for (int i = tid; i < 324; i += 256) {
            int row = i / 18, col = i % 18;
            int yy = row - 2, xx = col - 2;
            float val = 0.f;
            if ((unsigned)yy < 14u && (unsigned)xx < 14u) {
                float sx = x1 + (xx + 0.5f) * (x2 - x1) * (1.f / 14.f) - 0.5f;
                sx = fminf(fmaxf(sx, x1), x2 - 1.f);
                float sy = y1 + (yy + 0.5f) * (y2 - y1) * (1.f / 14.f) - 0.5f;
                sy = fminf(fmaxf(sy, y1), y2 - 1.f);
                float ix0f = floorf(sx), iy0f = floorf(sy);
                float wx = sx - ix0f, wy = sy - iy0f;
                int ix0 = (int)ix0f, iy0 = (int)iy0f;
                int ix1 = (int)fminf(ix0f + 1.f, x2 - 1.f);
                int iy1 = (int)fminf(iy0f + 1.f, y2 - 1.f);
                float v00 = img[iy0 * 64 + ix0], v01 = img[iy0 * 64 + ix1];
                float v10 = img[iy1 * 64 + ix0], v11 = img[iy1 * 64 + ix1];
                float top = (1.f - wx) * v00 + wx * v01;
                float bot = (1.f - wx) * v10 + wx * v11;
                val = (1.f - wy) * top + wy * bot;
            }
            inslab[row * 19 + col] = f2bf(val);
        }
        for (int i = tid; i < 1280; i += 256)
            *(bf16x8*)&slab2[i * 8] = (bf16x8)(short)0;
        if (tid < 5) *(bf16x8*)&act2[tid * 8] = (bf16x8)(short)0;
    }
    __syncthreads();

    // ---------------- phase 1: conv1 (5x5, im2col K=25->32) ----------------
    {
        bf16x8 bfr[2];
        bfr[0] = *(const bf16x8*)&bp1[(long)lane * 8];
        bfr[1] = *(const bf16x8*)&bp1[(long)(64 + lane) * 8];
        int aoff[8];
#pragma unroll
        for (int j = 0; j < 8; ++j) {
            int k = lg * 8 + j;
            int ky = k / 5, kx = k - ky * 5;
            aoff[j] = (k < 25) ? (ky * 19 + kx) : 0;
        }
        f32x4 acc[4][2];
#pragma unroll
        for (int i = 0; i < 4; ++i)
#pragma unroll
            for (int f = 0; f < 2; ++f) acc[i][f] = (f32x4)0.f;

#pragma unroll
        for (int i = 0; i < 4; ++i) {
            int mt = wav * 4 + i;
            if (mt >= 13) break;
            int pix = mt * 16 + lx; if (pix > 195) pix = 195;
            int py = pix / 14, pxx = pix - py * 14;
            int base = py * 19 + pxx;
            bf16x8 av;
#pragma unroll
            for (int j = 0; j < 8; ++j) av[j] = inslab[base + aoff[j]];
            acc[i][0] = __builtin_amdgcn_mfma_f32_16x16x32_bf16(av, bfr[0], acc[i][0], 0, 0, 0);
            acc[i][1] = __builtin_amdgcn_mfma_f32_16x16x32_bf16(av, bfr[1], acc[i][1], 0, 0, 0);
        }
        __syncthreads();     // zeros of slab2 complete before interior writes
#pragma unroll
        for (int i = 0; i < 4; ++i) {
            int mt = wav * 4 + i;
            if (mt >= 13) break;
#pragma unroll
            for (int f = 0; f < 2; ++f) {
                int co = f * 16 + lx;
#pragma unroll
                for (int r = 0; r < 4; ++r) {
                    int pix = mt * 16 + lg * 4 + r;
                    if (pix < 196) {
                        int py = pix / 14, pxx = pix - py * 14;
                        slab2[((py + 1) * 16 + (pxx + 1)) * 40 + co] = f2bf(lrelu01(acc[i][f][r]));
                    }
                }
            }
        }
    }
    __syncthreads();

    // ---------------- phase 2: conv2 (3x3, 32->32, pool) -------------------
    {
        f32x4 acc[4][2];
#pragma unroll
        for (int r = 0; r < 4; ++r)
#pragma unroll
            for (int f = 0; f < 2; ++f) acc[r][f] = (f32x4)0.f;

#pragma unroll
        for (int ky = 0; ky < 3; ++ky)
#pragma unroll
        for (int kx = 0; kx < 3; ++kx) {
            bf16x8 a[4];
            int xcl = min(lx + kx, 15);
#pragma unroll
            for (int r = 0; r < 4; ++r) {
                int ycl = min(wav * 4 + r + ky, 15);
                a[r] = *(const bf16x8*)&slab2[(ycl * 16 + xcl) * 40 + lg * 8];
            }
            const int kykx = ky * 3 + kx;
#pragma unroll
            for (int f = 0; f < 2; ++f) {
                bf16x8 b = *(const bf16x8*)&bp2[(((long)kykx * 2 + f) * 64 + lane) * 8];
#pragma unroll
                for (int r = 0; r < 4; ++r)
                    acc[r][f] = __builtin_amdgcn_mfma_f32_16x16x32_bf16(a[r], b, acc[r][f], 0, 0, 0);
            }
        }
#pragma unroll
        for (int f = 0; f < 2; ++f) {
            int co = f * 16 + lx;
#pragma unroll
            for (int q = 0; q < 2; ++q) {
                int yp = wav * 2 + q;
                if (yp >= 7) continue;
                float m0 = fmaxf(fmaxf(lrelu01(acc[2*q][f][0]), lrelu01(acc[2*q][f][1])),
                                 fmaxf(lrelu01(acc[2*q+1][f][0]), lrelu01(acc[2*q+1][f][1])));
                float m1 = fmaxf(fmaxf(lrelu01(acc[2*q][f][2]), lrelu01(acc[2*q][f][3])),
                                 fmaxf(lrelu01(acc[2*q+1][f][2]), lrelu01(acc[2*q+1][f][3])));
                int xp0 = lg * 2;
                act2[(1 + yp * 7 + xp0) * 40 + co] = f2bf(m0);
                if (xp0 + 1 < 7) act2[(1 + yp * 7 + xp0 + 1) * 40 + co] = f2bf(m1);
            }
        }
    }
    __syncthreads();

    // ---------------- phase 3: conv3 (3x3, 32->64), M=49 -------------------
    {
        int m = wav * 16 + lx; if (m > 48) m = 48;
        int y = m / 7, xx = m % 7;
        int aoff[9];
#pragma unroll
        for (int ky = 0; ky < 3; ++ky)
#pragma unroll
        for (int kx = 0; kx < 3; ++kx) {
            int iy = y + ky - 1, ix = xx + kx - 1;
            bool ok = (unsigned)iy < 7u && (unsigned)ix < 7u;
            aoff[ky * 3 + kx] = (ok ? (1 + iy * 7 + ix) : 0) * 40 + lg * 8;
        }
        f32x4 acc[4];
#pragma unroll
        for (int f = 0; f < 4; ++f) acc[f] = (f32x4)0.f;
#pragma unroll
        for (int kk = 0; kk < 9; ++kk) {
            bf16x8 a = *(const bf16x8*)&act2[aoff[kk]];
#pragma unroll
            for (int f = 0; f < 4; ++f) {
                bf16x8 b = *(const bf16x8*)&bp3[(((long)kk * 4 + f) * 64 + lane) * 8];
                acc[f] = __builtin_amdgcn_mfma_f32_16x16x32_bf16(a, b, acc[f], 0, 0, 0);
            }
        }
        if (tid < 9) *(bf16x8*)&act3[tid * 8] = (bf16x8)(short)0;  // zero slot0
#pragma unroll
        for (int f = 0; f < 4; ++f) {
            int co = f * 16 + lx;
#pragma unroll
            for (int r = 0; r < 4; ++r) {
                int mm = wav * 16 + lg * 4 + r;
                if (mm < 49) act3[(1 + mm) * 72 + co] = f2bf(lrelu01(acc[f][r]));
            }
        }
    }
    __syncthreads();

    // ---------------- phase 4: conv4 (3x3, 64->64), M=49 -> prepool --------
    {
        int m = wav * 16 + lx; if (m > 48) m = 48;
        int y = m / 7, xx = m % 7;
        int aoff[9];
#pragma unroll
        for (int ky = 0; ky < 3; ++ky)
#pragma unroll
        for (int kx = 0; kx < 3; ++kx) {
            int iy = y + ky - 1, ix = xx + kx - 1;
            bool ok = (unsigned)iy < 7u && (unsigned)ix < 7u;
            aoff[ky * 3 + kx] = (ok ? (1 + iy * 7 + ix) : 0) * 72 + lg * 8;
        }
        f32x4 acc[4];
#pragma unroll
        for (int f = 0; f < 4; ++f) acc[f] = (f32x4)0.f;
        for (int cs = 0; cs < 2; ++cs) {
#pragma unroll
            for (int kk = 0; kk < 9; ++kk) {
                bf16x8 a = *(const bf16x8*)&act3[aoff[kk] + cs * 32];
#pragma unroll
                for (int f = 0; f < 4; ++f) {
                    bf16x8 b = *(const bf16x8*)&bp4[(((long)(cs * 9 + kk) * 4 + f) * 64 + lane) * 8];
                    acc[f] = __builtin_amdgcn_mfma_f32_16x16x32_bf16(a, b, acc[f], 0, 0, 0);
                }
            }
        }
#pragma unroll
        for (int f = 0; f < 4; ++f) {
            int co = f * 16 + lx;
#pragma unroll
            for (int r = 0; r < 4; ++r) {
                int mm = wav * 16 + lg * 4 + r;
                if (mm < 49) prepool[mm * 72 + co] = f2bf(lrelu01(acc[f][r]));
            }
        }
    }
    __syncthreads();

    // ---------------- phase 5: pool 7x7 -> 3x3 -----------------------------
    {
        if (tid < 9) *(bf16x8*)&act4[tid * 8] = (bf16x8)(short)0;  // zero slot0
        for (int o = tid; o < 9 * 64; o += 256) {
            int c = o & 63; int rest = o >> 6;
            int xp = rest % 3, yp = rest / 3;
            int base = (2 * yp * 7 + 2 * xp) * 72 + c;
            float v0 = bf2f(prepool[base]);
            float v1 = bf2f(prepool[base + 72]);
            float v2 = bf2f(prepool[base + 7 * 72]);
            float v3 = bf2f(prepool[base + 8 * 72]);
            act4[(1 + yp * 3 + xp) * 72 + c] = f2bf(fmaxf(fmaxf(v0, v1), fmaxf(v2, v3)));
        }
    }
    __syncthreads();

    // ---------------- phase 6: conv5 (3x3, 64->128), M=9, wave=co-split ----
    {
        int m = min(lx, 8);
        int y = m / 3, xx = m % 3;
        int aoff[9];
#pragma unroll
        for (int ky = 0; ky < 3; ++ky)
#pragma unroll
        for (int kx = 0; kx < 3; ++kx) {
            int iy = y + ky - 1, ix = xx + kx - 1;
            bool ok = (unsigned)iy < 3u && (unsigned)ix < 3u;
            aoff[ky * 3 + kx] = (ok ? (1 + iy * 3 + ix) : 0) * 72 + lg * 8;
        }
        f32x4 acc[2];
        acc[0] = (f32x4)0.f; acc[1] = (f32x4)0.f;
        for (int cs = 0; cs < 2; ++cs) {
#pragma unroll
            for (int kk = 0; kk < 9; ++kk) {
                bf16x8 a = *(const bf16x8*)&act4[aoff[kk] + cs * 32];
#pragma unroll
                for (int f = 0; f < 2; ++f) {
                    bf16x8 b = *(const bf16x8*)&bp5[(((long)(cs * 9 + kk) * 8 + wav * 2 + f) * 64 + lane) * 8];
                    acc[f] = __builtin_amdgcn_mfma_f32_16x16x32_bf16(a, b, acc[f], 0, 0, 0);
                }
            }
        }
        if (tid < 17) *(bf16x8*)&act5[tid * 8] = (bf16x8)(short)0;  // zero slot0
#pragma unroll
        for (int f = 0; f < 2; ++f) {
            int co = (wav * 2 + f) * 16 + lx;
#pragma unroll
            for (int r = 0; r < 4; ++r) {
                int s = lg * 4 + r;
                if (s < 9) act5[(1 + s) * 136 + co] = f2bf(lrelu01(acc[f][r]));
            }
        }
    }
    __syncthreads();

    // ---------------- phase 7: conv6 (3x3, 128->128), M=9 -> global --------
    {
        int m = min(lx, 8);
        int y = m / 3, xx = m % 3;
        int aoff[9];
#pragma unroll
        for (int ky = 0; ky < 3; ++ky)
#pragma unroll
        for (int kx = 0; kx < 3; ++kx) {
            int iy = y + ky - 1, ix = xx + kx - 1;
            bool ok = (unsigned)iy < 3u && (unsigned)ix < 3u;
            aoff[ky * 3 + kx] = (ok ? (1 + iy * 3 + ix) : 0) * 136 + lg * 8;
        }
        f32x4 acc[2];
        acc[0] = (f32x4)0.f; acc[1] = (f32x4)0.f;
        for (int cs = 0; cs < 4; ++cs) {
#pragma unroll
            for (int kk = 0; kk < 9; ++kk) {
                bf16x8 a = *(const bf16x8*)&act5[aoff[kk] + cs * 32];
#pragma unroll
                for (int f = 0; f < 2; ++f) {
                    bf16x8 b = *(const bf16x8*)&bp6[(((long)(cs * 9 + kk) * 8 + wav * 2 + f) * 64 + lane) * 8];
                    acc[f] = __builtin_amdgcn_mfma_f32_16x16x32_bf16(a, b, acc[f], 0, 0, 0);
                }
            }
        }
#pragma unroll
        for (int f = 0; f < 2; ++f) {
            int co = (wav * 2 + f) * 16 + lx;
#pragma unroll
            for (int r = 0; r < 4; ++r) {
                int s = lg * 4 + r;
                if (s < 9) out[((long)n * 9 + s) * 128 + co] = f2bf(lrelu01(acc[f][r]));
            }
        }
    }
}

// ---------------------------------------------------------------------------
// fc_l as MFMA GEMM.
// ---------------------------------------------------------------------------
__global__ __launch_bounds__(256) void linear_l_mfma(
    const short* __restrict__ in, const short* __restrict__ wp,
    const float* __restrict__ bias, float* __restrict__ out)
{
    constexpr int KD = 1152, LDK = KD + 8;
    __shared__ __align__(16) short slab[16 * LDK];
    const int m0 = blockIdx.x * 16;
    const int tid = threadIdx.x;
    const int lane = tid & 63, wav = tid >> 6;
    const int lx = lane & 15, lg = lane >> 4;

    for (int i = tid; i < 16 * (KD / 8); i += 256) {
        int r = i / (KD / 8), c8 = i % (KD / 8);
        *(bf16x8*)&slab[r * LDK + c8 * 8] = *(const bf16x8*)&in[(long)(m0 + r) * KD + c8 * 8];
    }
    __syncthreads();

    f32x4 acc[4];
#pragma unroll
    for (int f = 0; f < 4; ++f) acc[f] = (f32x4)0.f;

    for (int kc = 0; kc < KD / 32; ++kc) {
        bf16x8 a = *(const bf16x8*)&slab[lx * LDK + kc * 32 + lg * 8];
#pragma unroll
        for (int f = 0; f < 4; ++f) {
            int nf = wav * 4 + f;
            bf16x8 b = *(const bf16x8*)&wp[(((long)kc * 16 + nf) * 64 + lane) * 8];
            acc[f] = __builtin_amdgcn_mfma_f32_16x16x32_bf16(a, b, acc[f], 0, 0, 0);
        }
    }

#pragma unroll
    for (int f = 0; f < 4; ++f) {
        int co = (wav * 4 + f) * 16 + lx;
        float bv = bias[co];
#pragma unroll
        for (int reg = 0; reg < 4; ++reg) {
            int m = m0 + lg * 4 + reg;
            out[(long)m * 256 + co] = acc[f][reg] + bv;
        }
    }
}

// ---------------------------------------------------------------------------
// max over T.
// ---------------------------------------------------------------------------
__global__ void max_over_T_cl(const short* __restrict__ in, float* __restrict__ out)
{
    int idx = blockIdx.x * blockDim.x + threadIdx.x;
    if (idx >= 8 * 4096) return;
    int b = idx >> 12, k8 = idx & 4095;
    float m[8];
#pragma unroll
    for (int j = 0; j < 8; ++j) m[j] = -1e30f;
    for (int t = 0; t < 30; ++t) {
        bf16x8 v = *(const bf16x8*)&in[(((long)(b * 30 + t)) << 15) + k8 * 8];
#pragma unroll
        for (int j = 0; j < 8; ++j) m[j] = fmaxf(m[j], bf2f(v[j]));
    }
    int kcl0 = k8 * 8;
    int s = kcl0 >> 7, c0 = kcl0 & 127;
#pragma unroll
    for (int j = 0; j < 8; ++j)
        out[b * 32768 + (c0 + j) * 256 + s] = m[j];
}

// ---------------------------------------------------------------------------
// fc_g.
// ---------------------------------------------------------------------------
__global__ void init_fcg(const float* __restrict__ bias, float* __restrict__ fcbuf)
{
    int idx = blockIdx.x * blockDim.x + threadIdx.x;
    if (idx >= 8 * 256) return;
    fcbuf[(idx >> 8) * 528 + (idx & 255)] = bias[idx & 255];
}

__global__ __launch_bounds__(256) void fcg_partial(
    const float* __restrict__ in, const float* __restrict__ w,
    float* __restrict__ fcbuf)
{
    const int gid = blockIdx.x * 256 + threadIdx.x;
    const int wid = gid >> 6, lane = gid & 63;
    const int o = wid >> 4, kc = wid & 15;
    const int k0 = kc * 2048;

    float acc[8];
#pragma unroll
    for (int m = 0; m < 8; ++m) acc[m] = 0.f;

    for (int it = 0; it < 8; ++it) {
        int k = k0 + it * 256 + lane * 4;
        float4 wv = *(const float4*)&w[(long)o * 32768 + k];
#pragma unroll
        for (int m = 0; m < 8; ++m) {
            float4 xv = *(const float4*)&in[(long)m * 32768 + k];
            acc[m] = fmaf(xv.x, wv.x, acc[m]);
            acc[m] = fmaf(xv.y, wv.y, acc[m]);
            acc[m] = fmaf(xv.z, wv.z, acc[m]);
            acc[m] = fmaf(xv.w, wv.w, acc[m]);
        }
    }
#pragma unroll
    for (int off = 32; off > 0; off >>= 1)
#pragma unroll
        for (int m = 0; m < 8; ++m)
            acc[m] += __shfl_down(acc[m], off, 64);
    if (lane == 0) {
#pragma unroll
        for (int m = 0; m < 8; ++m)
            atomicAdd(&fcbuf[m * 528 + o], acc[m]);
    }
}

// ---------------------------------------------------------------------------
// GAT stage 1: wave per row -> h1 row + s1 + s2.
// ---------------------------------------------------------------------------
__global__ __launch_bounds__(256) void gat_stage1(
    const float* __restrict__ lfc, const float* __restrict__ W,
    const float* __restrict__ a1, const float* __restrict__ a2,
    float* __restrict__ h1, float* __restrict__ s1, float* __restrict__ s2)
{
    const int wid = (blockIdx.x * 256 + threadIdx.x) >> 6;   // 0..1919
    const int lane = threadIdx.x & 63;
    const float* row = lfc + (long)wid * 256;

    float hd[8];
#pragma unroll
    for (int d = 0; d < 8; ++d) hd[d] = 0.f;
    float4 xv = *(const float4*)&row[lane * 4];
#pragma unroll
    for (int j = 0; j < 4; ++j) {
        float xj = (j == 0) ? xv.x : (j == 1) ? xv.y : (j == 2) ? xv.z : xv.w;
        const float* wr = W + (lane * 4 + j) * 8;
#pragma unroll
        for (int d = 0; d < 8; ++d) hd[d] = fmaf(xj, wr[d], hd[d]);
    }
#pragma unroll
    for (int d = 0; d < 8; ++d)
#pragma unroll
        for (int off = 1; off < 64; off <<= 1)
            hd[d] += __shfl_xor(hd[d], off, 64);

    float ss1 = 0.f, ss2 = 0.f;
#pragma unroll
    for (int d = 0; d < 8; ++d) { ss1 = fmaf(hd[d], a1[d], ss1); ss2 = fmaf(hd[d], a2[d], ss2); }

    if (lane == 0) {
#pragma unroll
        for (int d = 0; d < 8; ++d) h1[(long)wid * 8 + d] = hd[d];
        s1[wid] = ss1; s2[wid] = ss2;
    }
}

// ---------------------------------------------------------------------------
// GAT mid: agg layer1 + h2 matmul + layer2 scores, wave per node.
// ---------------------------------------------------------------------------
__global__ __launch_bounds__(256) void gat_mid(
    const float* __restrict__ h, const float* __restrict__ s1,
    const float* __restrict__ s2, const float* __restrict__ W2,
    const float* __restrict__ a21, const float* __restrict__ a22,
    float* __restrict__ h2, float* __restrict__ s1b, float* __restrict__ s2b)
{
    const int wid = (blockIdx.x * 256 + threadIdx.x) >> 6;
    const int lane = threadIdx.x & 63;
    const int b = wid / kN, i = wid % kN;
    const int fri = i / kR, rki = i % kR;
    const float s1i = s1[b * kN + i];

    float ej[4], mx = -1e30f;
#pragma unroll
    for (int t = 0; t < 4; ++t) {
        int j = lane + t * 64;
        if (j < kN) {
            int frj = j / kR, rkj = j % kR;
            int df = fri - frj;
            bool adj = (fri == frj) || ((rki == rkj) && (df == 1 || df == -1));
            float v = s1i + s2[b * kN + j];
            v = v > 0.f ? v : 0.2f * v;
            ej[t] = adj ? v : -9.0e15f;
        } else ej[t] = -1e30f;
        mx = fmaxf(mx, ej[t]);
    }
#pragma unroll
    for (int off = 1; off < 64; off <<= 1)
        mx = fmaxf(mx, __shfl_xor(mx, off, 64));

    float ex[4], sum = 0.f;
#pragma unroll
    for (int t = 0; t < 4; ++t) { ex[t] = expf(ej[t] - mx); sum += ex[t]; }
#pragma unroll
    for (int off = 1; off < 64; off <<= 1)
        sum += __shfl_xor(sum, off, 64);

    float part[8];
#pragma unroll
    for (int d = 0; d < 8; ++d) part[d] = 0.f;
#pragma unroll
    for (int t = 0; t < 4; ++t) {
        int j = lane + t * 64;
        int jc = j < kN ? j : kN - 1;
        float w = j < kN ? ex[t] : 0.f;
        const float* hr = h + ((long)b * kN + jc) * 8;
#pragma unroll
        for (int d = 0; d < 8; ++d) part[d] = fmaf(w, hr[d], part[d]);
    }
#pragma unroll
    for (int d = 0; d < 8; ++d)
#pragma unroll
        for (int off = 1; off < 64; off <<= 1)
            part[d] += __shfl_xor(part[d], off, 64);

    float o1v[8];
#pragma unroll
    for (int d = 0; d < 8; ++d) o1v[d] = part[d] / sum;

    float h2v[16];
#pragma unroll
    for (int dd = 0; dd < 16; ++dd) {
        float t = 0.f;
#pragma unroll
        for (int d = 0; d < 8; ++d) t = fmaf(o1v[d], W2[d * 16 + dd], t);
        h2v[dd] = t;
    }
    float t1 = 0.f, t2 = 0.f;
#pragma unroll
    for (int dd = 0; dd < 16; ++dd) { t1 = fmaf(h2v[dd], a21[dd], t1); t2 = fmaf(h2v[dd], a22[dd], t2); }

    if (lane == 0) {
#pragma unroll
        for (int dd = 0; dd < 16; ++dd) h2[(long)wid * 16 + dd] = h2v[dd];
        s1b[wid] = t1; s2b[wid] = t2;
    }
}

// ---------------------------------------------------------------------------
// GAT final: agg layer2 + elu + log_softmax, wave per node.
// ---------------------------------------------------------------------------
__global__ __launch_bounds__(256) void gat_final(
    const float* __restrict__ h2, const float* __restrict__ s1b,
    const float* __restrict__ s2b, float* __restrict__ gatfc)
{
    const int wid = (blockIdx.x * 256 + threadIdx.x) >> 6;
    const int lane = threadIdx.x & 63;
    const int b = wid / kN, i = wid % kN;
    const int fri = i / kR, rki = i % kR;
    const float s1i = s1b[b * kN + i];

    float ej[4], mx = -1e30f;
#pragma unroll
    for (int t = 0; t < 4; ++t) {
        int j = lane + t * 64;
        if (j < kN) {
            int frj = j / kR, rkj = j % kR;
            int df = fri - frj;
            bool adj = (fri == frj) || ((rki == rkj) && (df == 1 || df == -1));
            float v = s1i + s2b[b * kN + j];
            v = v > 0.f ? v : 0.2f * v;
            ej[t] = adj ? v : -9.0e15f;
        } else ej[t] = -1e30f;
        mx = fmaxf(mx, ej[t]);
    }
#pragma unroll
    for (int off = 1; off < 64; off <<= 1)
        mx = fmaxf(mx, __shfl_xor(mx, off, 64));

    float ex[4], sum = 0.f;
#pragma unroll
    for (int t = 0; t < 4; ++t) { ex[t] = expf(ej[t] - mx); sum += ex[t]; }
#pragma unroll
    for (int off = 1; off < 64; off <<= 1)
        sum += __shfl_xor(sum, off, 64);

    float part[16];
#pragma unroll
    for (int d = 0; d < 16; ++d) part[d] = 0.f;
#pragma unroll
    for (int t = 0; t < 4; ++t) {
        int j = lane + t * 64;
        int jc = j < kN ? j : kN - 1;
        float w = j < kN ? ex[t] : 0.f;
        const float* hr = h2 + ((long)b * kN + jc) * 16;
#pragma unroll
        for (int d = 0; d < 16; ++d) part[d] = fmaf(w, hr[d], part[d]);
    }
#pragma unroll
    for (int d = 0; d < 16; ++d)
#pragma unroll
        for (int off = 1; off < 64; off <<= 1)
            part[d] += __shfl_xor(part[d], off, 64);

    float v[16];
#pragma unroll
    for (int d = 0; d < 16; ++d) {
        float o = part[d] / sum;
        v[d] = o > 0.f ? o : expm1f(o);
    }
    float vm = v[0];
#pragma unroll
    for (int d = 1; d < 16; ++d) vm = fmaxf(vm, v[d]);
    float se = 0.f;
#pragma unroll
    for (int d = 0; d < 16; ++d) se += expf(v[d] - vm);
    float ls = logf(se) + vm;

    if (lane == 0) {
#pragma unroll
        for (int d = 0; d < 16; ++d) gatfc[(long)wid * 16 + d] = v[d] - ls;
    }
}

// ---------------- mean over nodes of concat(l_fc, gat_fc) ---------------------
__global__ void lcat_mean(const float* __restrict__ lfc, const float* __restrict__ gatfc,
                          float* __restrict__ fcbuf)
{
    int idx = blockIdx.x * blockDim.x + threadIdx.x;
    if (idx >= kB * 272) return;
    int b = idx / 272, c = idx % 272;
    float s = 0.f;
    if (c < 256) {
        for (int n2 = 0; n2 < kN; ++n2) s += lfc[((long)b * kN + n2) * 256 + c];
    } else {
        int cc = c - 256;
        for (int n2 = 0; n2 < kN; ++n2) s += gatfc[((long)b * kN + n2) * 16 + cc];
    }
    fcbuf[b * 528 + 256 + c] = s * (1.f / kN);
}

// ---------------- final pyramid ----------------------------------------------
__global__ void final_feats(const float* __restrict__ fcbuf, float* __restrict__ out)
{
    int idx = blockIdx.x * blockDim.x + threadIdx.x;
    if (idx >= kB * 1023) return;
    int b = idx / 1023, m = idx % 1023;
    int nb, seg, off;
    if      (m < 528) { nb = 1;  seg = 528; off = 0;   }
    else if (m < 792) { nb = 2;  seg = 264; off = 528; }
    else if (m < 924) { nb = 4;  seg = 132; off = 792; }
    else if (m < 990) { nb = 8;  seg = 66;  off = 924; }
    else              { nb = 16; seg = 33;  off = 990; }
    int mm = m - off;
    float s = 0.f, mx = -1e30f;
    for (int k2 = 0; k2 < nb; ++k2) {
        float v = fcbuf[b * 528 + k2 * seg + mm];
        s += v; mx = fmaxf(mx, v);
    }
    out[(long)b * 1023 + m] = s / nb + mx;
}

// ---------------------------------------------------------------------------
extern "C" void kernel_launch(void* const* d_in, const int* in_sizes, int n_in,
                              void* d_out, int out_size, void* d_ws, size_t ws_size,
                              hipStream_t stream)
{
    const float* x       = (const float*)d_in[0];
    const float* px      = (const float*)d_in[1];
    const float* cw1     = (const float*)d_in[2];
    const float* cw2     = (const float*)d_in[3];
    const float* cw3     = (const float*)d_in[4];
    const float* cw4     = (const float*)d_in[5];
    const float* cw5     = (const float*)d_in[6];
    const float* cw6     = (const float*)d_in[7];
    const float* fc_g_w  = (const float*)d_in[8];
    const float* fc_g_b  = (const float*)d_in[9];
    const float* fc_l_w  = (const float*)d_in[10];
    const float* fc_l_b  = (const float*)d_in[11];
    const float* gat1_W  = (const float*)d_in[12];
    const float* gat1_a1 = (const float*)d_in[13];
    const float* gat1_a2 = (const float*)d_in[14];
    const float* gat2_W  = (const float*)d_in[15];
    const float* gat2_a1 = (const float*)d_in[16];
    const float* gat2_a2 = (const float*)d_in[17];

    float* ws    = (float*)d_ws;
    float* A     = ws;                      // big ping
    float* Bb    = A + 31457280;            // big pong
    float* crops = Bb + 7864320;            // (unused)
    float* gmaxb = crops + 376320;
    float* lfc   = gmaxb + 262144;
    float* h1    = lfc + 491520;            // 15,360
    float* s1    = h1 + 15360;
    float* s2    = s1 + 1920;
    float* o1    = s2 + 1920;               // (unused)
    float* h2    = o1 + 15360;              // 30,720
    float* s1b   = h2 + 30720;
    float* s2b   = s1b + 1920;
    float* o2    = s2b + 1920;              // (unused)
    float* gatfc = o2 + 30720;
    float* fcbuf = gatfc + 30720;

    short* bp2 = (short*)(fcbuf + 4224);
    short* bp3 = bp2 + 9216;
    short* bp4 = bp3 + 18432;
    short* bp5 = bp4 + 36864;
    short* bp6 = bp5 + 73728;
    short* wpl = bp6 + 147456;
    short* bp1 = wpl + 294912;

    auto cdiv = [](long a, long b) { return (int)((a + b - 1) / b); };
    const int TB = 256;

    repack_all<<<284, 256, 0, stream>>>(cw1, cw2, cw3, cw4, cw5, cw6, fc_l_w,
                                        bp1, bp2, bp3, bp4, bp5, bp6, wpl);

    // ---------------- global path ----------------
    conv1g_mfma<<<3840, 256, 0, stream>>>(x, bp1, (short*)A);
    convg_cl< 32,  32, 64, 64, true,  1><<<3840, 256, 0, stream>>>((short*)A,  bp2, (short*)Bb);
    convg_cl< 32,  64, 32, 32, false, 1><<< 960, 256, 0, stream>>>((short*)Bb, bp3, (short*)A);
    convg_cl< 64,  64, 32, 32, true,  1><<< 960, 256, 0, stream>>>((short*)A,  bp4, (short*)Bb);
    convg_cl< 64, 128, 16, 16, false, 4><<< 960, 256, 0, stream>>>((short*)Bb, bp5, (short*)A);
    convg_cl<128, 128, 16, 16, false, 4><<< 960, 256, 0, stream>>>((short*)A,  bp6, (short*)Bb);
    max_over_T_cl<<<128, 256, 0, stream>>>((short*)Bb, gmaxb);
    init_fcg<<<cdiv(2048L, TB), TB, 0, stream>>>(fc_g_b, fcbuf);
    fcg_partial<<<1024, 256, 0, stream>>>(gmaxb, fc_g_w, fcbuf);

    // ---------------- local path: ONE kernel ----------------
    local_fused<<<1920, 256, 0, stream>>>(x, px, bp1, bp2, bp3, bp4, bp5, bp6,
                                          (short*)A);
    linear_l_mfma<<<120, 256, 0, stream>>>((short*)A, wpl, fc_l_b, lfc);

    // ---------------- GAT (3 dispatches) ----------------
    gat_stage1<<<480, 256, 0, stream>>>(lfc, gat1_W, gat1_a1, gat1_a2, h1, s1, s2);
    gat_mid<<<480, 256, 0, stream>>>(h1, s1, s2, gat2_W, gat2_a1, gat2_a2, h2, s1b, s2b);
    gat_final<<<480, 256, 0, stream>>>(h2, s1b, s2b, gatfc);

    // ---------------- head ----------------
    lcat_mean<<<cdiv(8L * 272, TB), TB, 0, stream>>>(lfc, gatfc, fcbuf);
    final_feats<<<cdiv(8L * 1023, TB), TB, 0, stream>>>(fcbuf, (float*)d_out);
}